// Round 3
// baseline (866.233 us; speedup 1.0000x reference)
//
#include <hip/hip_runtime.h>
#include <math.h>

#define NN 16384
#define D  256
#define NB (NN*D)
#define EPSR 1e-15f
#define SQEPS 3.1622776601683794e-8f
#define MXN 0.99999f   /* 1 - 1e-5 */

typedef unsigned short u16;
typedef __bf16 bf16x8 __attribute__((ext_vector_type(8)));
typedef float f32x4 __attribute__((ext_vector_type(4)));
typedef unsigned short u16x8 __attribute__((ext_vector_type(8)));
typedef unsigned short u16x4 __attribute__((ext_vector_type(4)));

__device__ __forceinline__ float b2f(u16 u){
  unsigned int x = ((unsigned int)u) << 16;
  return __builtin_bit_cast(float, x);
}
__device__ __forceinline__ u16 f2b(float f){
  unsigned int u = __builtin_bit_cast(unsigned int, f);
  return (u16)((u + 0x7fffu + ((u >> 16) & 1u)) >> 16);
}
__device__ __forceinline__ float at_c(float x){          // _artanh with clip
  return atanhf(fminf(fmaxf(x, -1.f + 1e-5f), 1.f - 1e-5f));
}
__device__ __forceinline__ float wred(float v){          // 64-lane sum, all lanes get result
#pragma unroll
  for (int m = 32; m; m >>= 1) v += __shfl_xor(v, m);
  return v;
}
// _proj given pre-proj norm: returns scale, sets clipped final norm (as _norm would see it)
__device__ __forceinline__ float sig_proj(float npre, float* nrm){
  float n = fmaxf(npre, SQEPS);
  float s = (n > MXN) ? (MXN / n) : 1.f;
  *nrm = fminf(n, MXN);
  return s;
}
__device__ __forceinline__ void ld4(const u16* p, float v[4]){   // bf16 table load
  u16x4 t = *(const u16x4*)p;
#pragma unroll
  for (int r = 0; r < 4; r++) v[r] = b2f(t[r]);
}
__device__ __forceinline__ void ld4f(const float* p, float v[4]){ // f32 input load
  f32x4 t = *(const f32x4*)p;
#pragma unroll
  for (int r = 0; r < 4; r++) v[r] = t[r];
}

// ---------------- K1: per-node prep: x_ball (f32), norms ----------------
__global__ void __launch_bounds__(256) k_prep(const float* __restrict__ x,
    const float* __restrict__ h1, const float* __restrict__ c1,
    float* __restrict__ xb, float* __restrict__ scal)
{
  int w = threadIdx.x >> 6, lane = threadIdx.x & 63;
  int n = blockIdx.x * 4 + w;
  int base = n * D + lane * 4;
  float xv[4], hv[4], cv[4];
  ld4f(x + base, xv); ld4f(h1 + base, hv); ld4f(c1 + base, cv);
  float un2 = 0, hn2 = 0, prn2 = 0, cn2 = 0;
#pragma unroll
  for (int r = 0; r < 4; r++){
    un2 += xv[r]*xv[r]; hn2 += hv[r]*hv[r];
    float rr = fmaxf(hv[r], 0.f); prn2 += rr*rr;
    cn2 += cv[r]*cv[r];
  }
  un2 = wred(un2); hn2 = wred(hn2); prn2 = wred(prn2); cn2 = wred(cn2);
  float un = sqrtf(fmaxf(un2, EPSR));
  float t  = tanhf(un);
  float sc = t / un;
  float nx = sqrtf(fmaxf(sc*sc*un2, EPSR));       // proj norm (with clip)
  float s  = (nx > MXN) ? (MXN / nx) : 1.f;
  f32x4 o;
#pragma unroll
  for (int r = 0; r < 4; r++) o[r] = s * sc * xv[r];
  *(f32x4*)(xb + base) = o;
  if (lane == 0){
    float* sp = scal + (size_t)n * 16;
    sp[0] = fminf(nx, MXN);                        // xbn = norm of x_ball
    sp[1] = hn2; sp[2] = prn2; sp[3] = cn2;
    float hn = sqrtf(fmaxf(hn2, EPSR));
    sp[9] = at_c(hn); sp[10] = hn;
  }
}

// ------- MFMA GEMM: C[M,Nout](bf16) = A[M,K](f32) @ B[Nout,K]^T(f32), bf16 compute -------
#define TM 128
#define TN 128
#define TK 32
#define LDP 40
__global__ void __launch_bounds__(256) gemm_bt(const float* __restrict__ A,
    const float* __restrict__ Bw, u16* __restrict__ C, int K, int Nout)
{
  __shared__ u16 As[TM*LDP];
  __shared__ u16 Bs[TN*LDP];
  int t = threadIdx.x;
  int m0 = blockIdx.x * TM, n0 = blockIdx.y * TN;
  int w = t >> 6, lane = t & 63;
  int wr = w >> 1, wc = w & 1;
  int q = lane >> 4, l16 = lane & 15;
  f32x4 acc[4][4];
#pragma unroll
  for (int i = 0; i < 4; i++)
#pragma unroll
    for (int j = 0; j < 4; j++) acc[i][j] = (f32x4){0.f,0.f,0.f,0.f};
  for (int k0 = 0; k0 < K; k0 += TK){
    __syncthreads();
#pragma unroll
    for (int c = t; c < 1024; c += 256){
      int row = c >> 3, ko = (c & 7) * 4;
      f32x4 a4 = *(const f32x4*)(A  + (size_t)(m0+row)*K + k0 + ko);
      f32x4 b4 = *(const f32x4*)(Bw + (size_t)(n0+row)*K + k0 + ko);
      u16x4 ua, ub;
#pragma unroll
      for (int r = 0; r < 4; r++){ ua[r] = f2b(a4[r]); ub[r] = f2b(b4[r]); }
      *(u16x4*)(As + row*LDP + ko) = ua;
      *(u16x4*)(Bs + row*LDP + ko) = ub;
    }
    __syncthreads();
    bf16x8 af[4], bfr[4];
#pragma unroll
    for (int rb = 0; rb < 4; rb++)
      af[rb] = *(const bf16x8*)(As + (wr*64 + rb*16 + l16)*LDP + q*8);
#pragma unroll
    for (int cb = 0; cb < 4; cb++)
      bfr[cb] = *(const bf16x8*)(Bs + (wc*64 + cb*16 + l16)*LDP + q*8);
#pragma unroll
    for (int rb = 0; rb < 4; rb++)
#pragma unroll
      for (int cb = 0; cb < 4; cb++)
        acc[rb][cb] = __builtin_amdgcn_mfma_f32_16x16x32_bf16(af[rb], bfr[cb], acc[rb][cb], 0, 0, 0);
  }
#pragma unroll
  for (int rb = 0; rb < 4; rb++)
#pragma unroll
    for (int cb = 0; cb < 4; cb++)
#pragma unroll
      for (int r = 0; r < 4; r++){
        int m  = m0 + wr*64 + rb*16 + q*4 + r;
        int nn = n0 + wc*64 + cb*16 + l16;
        C[(size_t)m*Nout + nn] = f2b(acc[rb][cb][r]);
      }
}

// z = mobius_add(mm_scale(m; xn), b) ; returns clipped norm of z
__device__ __forceinline__ float mm_madd(const float mv[4], const float bv[4], float xn, float z[4]){
  float mn2 = 0.f;
#pragma unroll
  for (int r = 0; r < 4; r++) mn2 += mv[r]*mv[r];
  mn2 = wred(mn2);
  float mnc = sqrtf(fmaxf(mn2, EPSR));
  float t = tanhf(mnc / xn * at_c(xn));
  float npre = t * sqrtf(mn2) / mnc;
  float nf; float sg = sig_proj(npre, &nf);
  float cx = sg * t / mnc;                       // mm result = cx * m
  float x2 = (sg*npre)*(sg*npre);
  float y2 = 0.f, xy = 0.f;
#pragma unroll
  for (int r = 0; r < 4; r++){ y2 += bv[r]*bv[r]; xy += cx*mv[r]*bv[r]; }
  y2 = wred(y2); xy = wred(xy);
  float A = 1.f + 2.f*xy + y2, Bc = 1.f - x2;
  float den = fmaxf(1.f + 2.f*xy + x2*y2, EPSR);
  float zn2 = (A*A*x2 + 2.f*A*Bc*xy + Bc*Bc*y2) / (den*den);
  float zn = sqrtf(fmaxf(zn2, EPSR));
  float sz = (zn > MXN) ? (MXN/zn) : 1.f;
#pragma unroll
  for (int r = 0; r < 4; r++) z[r] = sz * (A*cx*mv[r] + Bc*bv[r]) / den;
  return fminf(zn, MXN);
}

// ---------------- K7: per-node post-GEMM: q, kvec, f, c_sk tables ----------------
__global__ void __launch_bounds__(256) k_post(
    const u16* __restrict__ mq, const u16* __restrict__ mk,
    const u16* __restrict__ mf, const u16* __restrict__ mc,
    const float* __restrict__ c1,
    const float* __restrict__ bq, const float* __restrict__ bk, const float* __restrict__ bc,
    u16* __restrict__ qv, u16* __restrict__ kv,
    u16* __restrict__ fcs, u16* __restrict__ fcm,
    float* __restrict__ scal)
{
  int w = threadIdx.x >> 6, lane = threadIdx.x & 63;
  int n = blockIdx.x * 4 + w;
  int base = n * D + lane * 4, lb = lane * 4;
  float* sp = scal + (size_t)n * 16;
  float xbn = sp[0], hn2 = sp[1], cn2 = sp[3];
  float hnc = sqrtf(fmaxf(hn2, EPSR));
  float cnc = sqrtf(fmaxf(cn2, EPSR));
  float mv[4], bv[4], z[4];
  u16x4 o;
  // q = logmap0(mobius_add(mm(W_q, x_ball), b_q))
  ld4(mq + base, mv); ld4f(bq + lb, bv);
  float znf = mm_madd(mv, bv, xbn, z);
  float cl = at_c(znf) / znf;
#pragma unroll
  for (int r = 0; r < 4; r++) o[r] = f2b(cl * z[r]);
  *(u16x4*)(qv + base) = o;
  // kvec = logmap0(mobius_add(mm(W_k, h1), b_k))
  ld4(mk + base, mv); ld4f(bk + lb, bv);
  znf = mm_madd(mv, bv, hnc, z);
  cl = at_c(znf) / znf;
#pragma unroll
  for (int r = 0; r < 4; r++) o[r] = f2b(cl * z[r]);
  *(u16x4*)(kv + base) = o;
  // f = sigmoid(logmap0(mm(U_f, h1)))
  float fv[4];
  {
    ld4(mf + base, mv);
    float mn2 = 0.f;
#pragma unroll
    for (int r = 0; r < 4; r++) mn2 += mv[r]*mv[r];
    mn2 = wred(mn2);
    float mnc = sqrtf(fmaxf(mn2, EPSR));
    float t = tanhf(mnc / hnc * at_c(hnc));
    float npre = t * sqrtf(mn2) / mnc;
    float nf; float sg = sig_proj(npre, &nf);
    float cx = sg * t / mnc;
    float lcf = at_c(nf) / nf;
#pragma unroll
    for (int r = 0; r < 4; r++) fv[r] = 1.f / (1.f + expf(-lcf * cx * mv[r]));
  }
  // c_sk = expmap0(tanh(logmap0(mobius_add(mm(W_c, c1), b_c))))
  float csk[4];
  {
    ld4(mc + base, mv); ld4f(bc + lb, bv);
    float zn = mm_madd(mv, bv, cnc, z);
    float lc = at_c(zn) / zn;
    float th[4]; float thn2 = 0.f;
#pragma unroll
    for (int r = 0; r < 4; r++){ th[r] = tanhf(lc * z[r]); thn2 += th[r]*th[r]; }
    thn2 = wred(thn2);
    float thn = sqrtf(fmaxf(thn2, EPSR));
    float te = tanhf(thn);
    float se = te / thn;
    float npe = sqrtf(fmaxf(se*se*thn2, EPSR));
    float sge = (npe > MXN) ? (MXN/npe) : 1.f;
#pragma unroll
    for (int r = 0; r < 4; r++) csk[r] = sge * se * th[r];
  }
  float c1v[4]; ld4f(c1 + base, c1v);
  float csn2 = 0, pcc = 0, pfss = 0, pfsm = 0, pfmm = 0;
#pragma unroll
  for (int r = 0; r < 4; r++){
    float f2 = fv[r]*fv[r];
    csn2 += csk[r]*csk[r];
    pcc  += csk[r]*c1v[r];
    pfss += f2*csk[r]*csk[r];
    pfsm += f2*csk[r]*c1v[r];
    pfmm += f2*c1v[r]*c1v[r];
  }
  csn2 = wred(csn2); pcc = wred(pcc); pfss = wred(pfss); pfsm = wred(pfsm); pfmm = wred(pfmm);
  u16x4 oa, ob;
#pragma unroll
  for (int r = 0; r < 4; r++){ oa[r] = f2b(fv[r]*csk[r]); ob[r] = f2b(fv[r]*c1v[r]); }
  *(u16x4*)(fcs + base) = oa;
  *(u16x4*)(fcm + base) = ob;
  if (lane == 0){
    sp[4] = csn2; sp[5] = pcc; sp[6] = pfss; sp[7] = pfsm; sp[8] = pfmm;
    sp[11] = sqrtf(fmaxf(csn2, EPSR));
  }
}

// ---------------- K8: edge kernel (wave per node) ----------------
__global__ void __launch_bounds__(256) k_edge(
    const int* __restrict__ edges, const float* __restrict__ del_t,
    const float* __restrict__ h1,
    const u16* __restrict__ qv, const u16* __restrict__ kvec,
    const u16* __restrict__ fcs, const u16* __restrict__ fcm,
    const float* __restrict__ scal,
    const float* __restrict__ pbh, const float* __restrict__ pah,
    const float* __restrict__ ph1, const float* __restrict__ ph2,
    float* __restrict__ ht, u16* __restrict__ cred, float* __restrict__ htn_arr)
{
  __shared__ int   s_j[4][16];
  __shared__ float s_dt[4][16];
  __shared__ float s_lg[4][16];
  int w = threadIdx.x >> 6, lane = threadIdx.x & 63;
  int n = blockIdx.x * 4 + w;
  float bh = pbh[0], ah = pah[0], hw1 = ph1[0], hw2 = ph2[0];
  float qf[4]; ld4(qv + n*D + lane*4, qf);
  // pass 1: logits
  for (int k = 0; k < 16; k++){
    int j = __builtin_amdgcn_readfirstlane(edges[n*16 + k]);
    float dt = del_t[j];
    u16x4 kt = *(const u16x4*)(kvec + (size_t)j*D + lane*4);
    float d = 0.f;
#pragma unroll
    for (int r = 0; r < 4; r++) d += qf[r] * b2f(kt[r]);
    d = wred(d);
    float g = bh * expf(-ah * dt);
    if (lane == 0){ s_j[w][k] = j; s_dt[w][k] = dt; s_lg[w][k] = d * 0.0625f + g; }
  }
  __syncthreads();
  float mxl = -1e30f;
  for (int k = 0; k < 16; k++) mxl = fmaxf(mxl, s_lg[w][k]);
  float sume = 0.f;
  for (int k = 0; k < 16; k++) sume += expf(s_lg[w][k] - mxl);
  float inv_se = 1.f / sume;
  float numh[4] = {0,0,0,0}, numc[4] = {0,0,0,0};
  float denh = 0.f, denc = 0.f;
  // pass 2: analytic per-edge mobius chain, midpoint accumulation
  for (int k = 0; k < 16; k++){
    int j = __builtin_amdgcn_readfirstlane(s_j[w][k]);
    float dt = s_dt[w][k];
    float sk = expf(s_lg[w][k] - mxl) * inv_se;
    const float* sp2 = scal + (size_t)j * 16;
    float hn2 = sp2[1], prn2 = sp2[2], cn2 = sp2[3], csn2 = sp2[4], pcc = sp2[5],
          pfss = sp2[6], pfsm = sp2[7], pfmm = sp2[8], athn = sp2[9], hn = sp2[10];
    float hx[4]; ld4f(h1 + (size_t)j*D + lane*4, hx);
    u16x4 fs4 = *(const u16x4*)(fcs + (size_t)j*D + lane*4);
    u16x4 fm4 = *(const u16x4*)(fcm + (size_t)j*D + lane*4);
    float g = bh * expf(-ah * dt);
    float decay = expf(-hw2 * dt * (1.f/60.f));
    // h-side: h_scaled = a_h*hx ; h_max = b_h*relu(hx)
    float wxn1 = sqrtf(fmaxf(sk*sk*hn2, EPSR));
    float t1 = tanhf(wxn1 / hn * athn);
    float npre1 = t1 * sk * sqrtf(hn2) / wxn1;
    float nn1 = fmaxf(npre1, SQEPS); float sg1 = (nn1 > MXN) ? MXN/nn1 : 1.f;
    float a_h = sg1 * t1 * sk / wxn1;
    float rn2 = a_h*a_h*prn2;
    float xnd  = sqrtf(fmaxf(decay*decay, EPSR));
    float wxn2 = sqrtf(fmaxf(decay*decay*rn2, EPSR));
    float t2 = tanhf(wxn2 / xnd * at_c(xnd));
    float npre2 = t2 * decay * sqrtf(rn2) / wxn2;
    float nn2 = fmaxf(npre2, SQEPS); float sg2 = (nn2 > MXN) ? MXN/nn2 : 1.f;
    float b_h = sg2 * t2 * decay * a_h / wxn2;
    float bh1 = hw1 * b_h;
    float x2 = a_h*a_h*hn2;
    float y2 = bh1*bh1*prn2;
    float xy = a_h*bh1*prn2;           // hx dot relu(hx) = relu(hx)^2
    float A = 1.f + 2.f*xy + y2, B = 1.f - x2;
    float den = fmaxf(1.f + 2.f*xy + x2*y2, EPSR);
    float nh2 = (A*A*x2 + 2.f*A*B*xy + B*B*y2) / (den*den);
    float nh = sqrtf(fmaxf(nh2, EPSR)); float sg3 = (nh > MXN) ? MXN/nh : 1.f;
    float p  = sg3 * A * a_h / den;
    float rr = sg3 * B * bh1 / den;
    float hhn2 = sg3*sg3*nh2;
    float lam = 2.f / fmaxf(1.f - hhn2, EPSR);
    denh += lam - 1.f;
#pragma unroll
    for (int r = 0; r < 4; r++)
      numh[r] += lam * (p*hx[r] + rr*fmaxf(hx[r], 0.f));
    // c-side: c_k_tilde = u1*csk + u2*cm ; res = v1*(f*csk) + v2*(f*cm)
    float xng  = sqrtf(fmaxf(g*g, EPSR));
    float wxn3 = sqrtf(fmaxf(g*g*csn2, EPSR));
    float t3 = tanhf(wxn3 / xng * at_c(xng));
    float npre3 = t3 * g * sqrtf(csn2) / wxn3;
    float nn3 = fmaxf(npre3, SQEPS); float sgc = (nn3 > MXN) ? MXN/nn3 : 1.f;
    float gam = sgc * t3 * g / wxn3;
    float A1 = 1.f - 2.f*pcc + cn2, B1 = 1.f - csn2;
    float den1 = fmaxf(1.f - 2.f*pcc + csn2*cn2, EPSR);
    float al = -A1/den1, be = B1/den1;
    float n1sq = al*al*csn2 + 2.f*al*be*pcc + be*be*cn2;
    float n1 = sqrtf(fmaxf(n1sq, EPSR)); float s1 = (n1 > MXN) ? MXN/n1 : 1.f;
    al *= s1; be *= s1;
    float z1n2 = s1*s1*n1sq;
    float y2c = gam*gam*csn2;
    float xyc = gam*(al*csn2 + be*pcc);
    float A2 = 1.f + 2.f*xyc + y2c, B2 = 1.f - z1n2;
    float den2 = fmaxf(1.f + 2.f*xyc + z1n2*y2c, EPSR);
    float u1 = (A2*al + B2*gam)/den2, u2 = A2*be/den2;
    float n2sq = u1*u1*csn2 + 2.f*u1*u2*pcc + u2*u2*cn2;
    float n2 = sqrtf(fmaxf(n2sq, EPSR)); float s2 = (n2 > MXN) ? MXN/n2 : 1.f;
    u1 *= s2; u2 *= s2;
    float xnc = fminf(n2, MXN);
    float wx2 = u1*u1*pfss + 2.f*u1*u2*pfsm + u2*u2*pfmm;
    float wxn4 = sqrtf(fmaxf(wx2, EPSR));
    float t4 = tanhf(wxn4 / xnc * at_c(xnc));
    float npre4 = t4 * sqrtf(wx2) / wxn4;
    float nn4 = fmaxf(npre4, SQEPS); float s4 = (nn4 > MXN) ? MXN/nn4 : 1.f;
    float v1 = s4*t4*u1/wxn4, v2 = s4*t4*u2/wxn4;
    float rsn2 = (s4*npre4)*(s4*npre4);
    float lam2 = 2.f / fmaxf(1.f - rsn2, EPSR);
    denc += lam2 - 1.f;
#pragma unroll
    for (int r = 0; r < 4; r++)
      numc[r] += lam2 * (v1*b2f(fs4[r]) + v2*b2f(fm4[r]));
  }
  // epilogue: weighted midpoint -> mobius_scalar_mul(0.5, num/den)
  if (fabsf(denh) < 1e-10f) denh = 1e-10f;
  if (fabsf(denc) < 1e-10f) denc = 1e-10f;
  float vh[4], vc[4]; float vn2h = 0.f, vn2c = 0.f;
#pragma unroll
  for (int r = 0; r < 4; r++){
    vh[r] = numh[r]/denh; vn2h += vh[r]*vh[r];
    vc[r] = numc[r]/denc; vn2c += vc[r]*vc[r];
  }
  vn2h = wred(vn2h); vn2c = wred(vn2c);
  float vnh = sqrtf(fmaxf(vn2h, EPSR));
  float tth = tanhf(0.5f * at_c(vnh));
  float nph = tth * sqrtf(vn2h) / vnh;
  float nfh; float sh = sig_proj(nph, &nfh);
  float chh = sh * tth / vnh;
  f32x4 ho;
#pragma unroll
  for (int r = 0; r < 4; r++) ho[r] = chh * vh[r];
  *(f32x4*)(ht + n*D + lane*4) = ho;
  if (lane == 0) htn_arr[n] = nfh;
  float vnc = sqrtf(fmaxf(vn2c, EPSR));
  float ttc = tanhf(0.5f * at_c(vnc));
  float npc = ttc * sqrtf(vn2c) / vnc;
  float nfc; float scz = sig_proj(npc, &nfc);
  float chc = scz * ttc / vnc;
  u16x4 co;
#pragma unroll
  for (int r = 0; r < 4; r++) co[r] = f2b(chc * vc[r]);
  *(u16x4*)(cred + n*D + lane*4) = co;
}

// ---------------- K10: final iou chain + outputs ----------------
__global__ void __launch_bounds__(256) k_final(
    const u16* __restrict__ miou, const u16* __restrict__ mu,
    const u16* __restrict__ cred, const float* __restrict__ biou,
    const float* __restrict__ scal, const float* __restrict__ htn_arr,
    float* __restrict__ out)
{
  int w = threadIdx.x >> 6, lane = threadIdx.x & 63;
  int n = blockIdx.x * 4 + w;
  float mi[3][4], muv[3][4], bi[3][4];
#pragma unroll
  for (int p = 0; p < 3; p++){
    ld4(miou + (size_t)n*768 + p*256 + lane*4, mi[p]);
    ld4(mu   + (size_t)n*768 + p*256 + lane*4, muv[p]);
    ld4f(biou + p*256 + lane*4, bi[p]);
  }
  float cr[4]; ld4(cred + (size_t)n*D + lane*4, cr);
  float xbn = scal[(size_t)n*16 + 0];
  float htn = htn_arr[n];
  float mn2 = 0.f, un2 = 0.f, dmu = 0.f;
#pragma unroll
  for (int p = 0; p < 3; p++)
#pragma unroll
    for (int r = 0; r < 4; r++){
      mn2 += mi[p][r]*mi[p][r]; un2 += muv[p][r]*muv[p][r]; dmu += mi[p][r]*muv[p][r];
    }
  mn2 = wred(mn2); un2 = wred(un2); dmu = wred(dmu);
  // iou0 = mm(W_iou, x_ball), uo = mm(U_iou, h_tild)
  float mnc = sqrtf(fmaxf(mn2, EPSR));
  float ta = tanhf(mnc / xbn * at_c(xbn));
  float npa = ta * sqrtf(mn2) / mnc;
  float na_; float sa = sig_proj(npa, &na_);
  float ca = sa * ta / mnc; float x2 = (sa*npa)*(sa*npa);
  float unc = sqrtf(fmaxf(un2, EPSR));
  float tb = tanhf(unc / htn * at_c(htn));
  float npb = tb * sqrtf(un2) / unc;
  float nb_; float sb = sig_proj(npb, &nb_);
  float cb = sb * tb / unc; float y2 = (sb*npb)*(sb*npb);
  float xy = ca * cb * dmu;
  float A = 1.f + 2.f*xy + y2, B = 1.f - x2;
  float den = fmaxf(1.f + 2.f*xy + x2*y2, EPSR);
  float c_mi = A*ca/den, c_mu = B*cb/den;
  float n1sq = (A*A*x2 + 2.f*A*B*xy + B*B*y2) / (den*den);
  float n1 = sqrtf(fmaxf(n1sq, EPSR)); float s1 = (n1 > MXN) ? MXN/n1 : 1.f;
  c_mi *= s1; c_mu *= s1;
  float iou1n2 = s1*s1*n1sq;
  // + b_iou
  float io1[3][4]; float bb2 = 0.f, xyb = 0.f;
#pragma unroll
  for (int p = 0; p < 3; p++)
#pragma unroll
    for (int r = 0; r < 4; r++){
      io1[p][r] = c_mi*mi[p][r] + c_mu*muv[p][r];
      bb2 += bi[p][r]*bi[p][r]; xyb += io1[p][r]*bi[p][r];
    }
  bb2 = wred(bb2); xyb = wred(xyb);
  float A2 = 1.f + 2.f*xyb + bb2, B2 = 1.f - iou1n2;
  float den2 = fmaxf(1.f + 2.f*xyb + iou1n2*bb2, EPSR);
  float n2sq = (A2*A2*iou1n2 + 2.f*A2*B2*xyb + B2*B2*bb2) / (den2*den2);
  float n2c = sqrtf(fmaxf(n2sq, EPSR)); float s2 = (n2c > MXN) ? MXN/n2c : 1.f;
  float iou[3][4];
#pragma unroll
  for (int p = 0; p < 3; p++)
#pragma unroll
    for (int r = 0; r < 4; r++) iou[p][r] = s2 * (A2*io1[p][r] + B2*bi[p][r]) / den2;
  // split + gates
  float ni2 = 0.f, no2 = 0.f, nu2 = 0.f;
#pragma unroll
  for (int r = 0; r < 4; r++){ ni2 += iou[0][r]*iou[0][r]; no2 += iou[1][r]*iou[1][r]; nu2 += iou[2][r]*iou[2][r]; }
  ni2 = wred(ni2); no2 = wred(no2); nu2 = wred(nu2);
  float niN = sqrtf(fmaxf(ni2, EPSR)), noN = sqrtf(fmaxf(no2, EPSR)), nuN = sqrtf(fmaxf(nu2, EPSR));
  float ci = at_c(niN)/niN, co = at_c(noN)/noN, cu = at_c(nuN)/nuN;
  float iv[4], ov[4], uv[4];
#pragma unroll
  for (int r = 0; r < 4; r++){
    iv[r] = 1.f / (1.f + expf(-ci*iou[0][r]));
    ov[r] = 1.f / (1.f + expf(-co*iou[1][r]));
    uv[r] = tanhf(cu*iou[2][r]);
  }
  // pm(i, u2)
  float xn2 = 0.f, wn2 = 0.f; float wx[4];
#pragma unroll
  for (int r = 0; r < 4; r++){ xn2 += uv[r]*uv[r]; wx[r] = iv[r]*uv[r]; wn2 += wx[r]*wx[r]; }
  xn2 = wred(xn2); wn2 = wred(wn2);
  float xnc = sqrtf(fmaxf(xn2, EPSR)), wnc = sqrtf(fmaxf(wn2, EPSR));
  float t4 = tanhf(wnc / xnc * at_c(xnc));
  float np4 = t4 * sqrtf(wn2) / wnc;
  float n4_; float s4 = sig_proj(np4, &n4_);
  float cpm = s4*t4/wnc; float pmn2 = (s4*np4)*(s4*np4);
  // c_new = mobius_add(pm, c_red)
  float y2c = 0.f, xyc = 0.f;
#pragma unroll
  for (int r = 0; r < 4; r++){ y2c += cr[r]*cr[r]; xyc += cpm*wx[r]*cr[r]; }
  y2c = wred(y2c); xyc = wred(xyc);
  float A3 = 1.f + 2.f*xyc + y2c, B3 = 1.f - pmn2;
  float den3 = fmaxf(1.f + 2.f*xyc + pmn2*y2c, EPSR);
  float n3sq = (A3*A3*pmn2 + 2.f*A3*B3*xyc + B3*B3*y2c) / (den3*den3);
  float n3 = sqrtf(fmaxf(n3sq, EPSR)); float s3 = (n3 > MXN) ? MXN/n3 : 1.f;
  float cnw[4]; f32x4 oc;
#pragma unroll
  for (int r = 0; r < 4; r++){ cnw[r] = s3*(A3*cpm*wx[r] + B3*cr[r])/den3; oc[r] = cnw[r]; }
  *(f32x4*)(out + NB + (size_t)n*D + lane*4) = oc;
  // h_new = pm(o, tanh(logmap0(c_new)))
  float ncn = fminf(n3, MXN);
  float clg = at_c(ncn)/ncn;
  float th[4]; float xn5 = 0.f, wn5 = 0.f; float wx5[4];
#pragma unroll
  for (int r = 0; r < 4; r++){
    th[r] = tanhf(clg*cnw[r]);
    xn5 += th[r]*th[r]; wx5[r] = ov[r]*th[r]; wn5 += wx5[r]*wx5[r];
  }
  xn5 = wred(xn5); wn5 = wred(wn5);
  float xn5c = sqrtf(fmaxf(xn5, EPSR)), wn5c = sqrtf(fmaxf(wn5, EPSR));
  float t5 = tanhf(wn5c / xn5c * at_c(xn5c));
  float np5 = t5 * sqrtf(wn5) / wn5c;
  float n5_; float s5 = sig_proj(np5, &n5_);
  float ch = s5*t5/wn5c;
  f32x4 oh;
#pragma unroll
  for (int r = 0; r < 4; r++) oh[r] = ch * wx5[r];
  *(f32x4*)(out + (size_t)n*D + lane*4) = oh;
}

extern "C" void kernel_launch(void* const* d_in, const int* in_sizes, int n_in,
                              void* d_out, int out_size, void* d_ws, size_t ws_size,
                              hipStream_t stream)
{
  (void)in_sizes; (void)n_in; (void)out_size; (void)ws_size;
  const float* x     = (const float*)d_in[0];
  const float* h1    = (const float*)d_in[1];
  const float* c1    = (const float*)d_in[2];
  const float* del_t = (const float*)d_in[3];
  const int*   edges = (const int*)d_in[4];
  const float* W_iou = (const float*)d_in[5];
  const float* U_iou = (const float*)d_in[6];
  const float* b_iou = (const float*)d_in[7];
  const float* U_f   = (const float*)d_in[8];
  const float* W_q   = (const float*)d_in[9];
  const float* b_q   = (const float*)d_in[10];
  const float* W_k   = (const float*)d_in[11];
  const float* b_k   = (const float*)d_in[12];
  const float* W_c   = (const float*)d_in[13];
  const float* b_c   = (const float*)d_in[14];
  const float* b_haw = (const float*)d_in[15];
  const float* a_haw = (const float*)d_in[16];
  const float* haw1  = (const float*)d_in[17];
  const float* haw2  = (const float*)d_in[18];

  // workspace layout: xb is f32 (GEMM A operand, reused as ht);
  // mq reused as cred; mk..mc (3*NB u16) reused as mu after k_post.
  float* xb  = (float*)d_ws;                 // NB f32
  u16* mq    = (u16*)(xb + NB);              // NB
  u16* mk    = mq   + NB;                    // NB
  u16* mf    = mk   + NB;                    // NB
  u16* mc    = mf   + NB;                    // NB
  u16* miou  = mc   + NB;                    // 3*NB
  u16* qv    = miou + 3*(size_t)NB;          // NB
  u16* kvec  = qv   + NB;                    // NB
  u16* fcs   = kvec + NB;                    // NB
  u16* fcm   = fcs  + NB;                    // NB
  float* scal    = (float*)(fcm + NB);       // NN*16 f32
  float* htn_arr = scal + (size_t)NN*16;     // NN f32
  float* ht = xb;
  u16* cred = mq;
  u16* mu   = mk;

  k_prep<<<NN/4, 256, 0, stream>>>(x, h1, c1, xb, scal);
  gemm_bt<<<dim3(NN/128, 2), 256, 0, stream>>>(xb, W_q,   mq,   256, 256);
  gemm_bt<<<dim3(NN/128, 6), 256, 0, stream>>>(xb, W_iou, miou, 256, 768);
  gemm_bt<<<dim3(NN/128, 2), 256, 0, stream>>>(h1, W_k,   mk,   256, 256);
  gemm_bt<<<dim3(NN/128, 2), 256, 0, stream>>>(h1, U_f,   mf,   256, 256);
  gemm_bt<<<dim3(NN/128, 2), 256, 0, stream>>>(c1, W_c,   mc,   256, 256);
  k_post<<<NN/4, 256, 0, stream>>>(mq, mk, mf, mc, c1, b_q, b_k, b_c, qv, kvec, fcs, fcm, scal);
  k_edge<<<NN/4, 256, 0, stream>>>(edges, del_t, h1, qv, kvec, fcs, fcm, scal,
                                   b_haw, a_haw, haw1, haw2, ht, cred, htn_arr);
  gemm_bt<<<dim3(NN/128, 6), 256, 0, stream>>>(ht, U_iou, mu, 256, 768);
  k_final<<<NN/4, 256, 0, stream>>>(miou, mu, cred, b_iou, scal, htn_arr, (float*)d_out);
}

// Round 4
// 485.806 us; speedup vs baseline: 1.7831x; 1.7831x over previous
//
#include <hip/hip_runtime.h>
#include <math.h>

#define NN 16384
#define D  256
#define NB (NN*D)
#define EPSR 1e-15f
#define SQEPS 3.1622776601683794e-8f
#define MXN 0.99999f   /* 1 - 1e-5 */

typedef unsigned short u16;
typedef __bf16 bf16x8 __attribute__((ext_vector_type(8)));
typedef float f32x4 __attribute__((ext_vector_type(4)));
typedef unsigned short u16x8 __attribute__((ext_vector_type(8)));
typedef unsigned short u16x4 __attribute__((ext_vector_type(4)));

__device__ __forceinline__ float b2f(u16 u){
  unsigned int x = ((unsigned int)u) << 16;
  return __builtin_bit_cast(float, x);
}
__device__ __forceinline__ u16 f2b(float f){
  unsigned int u = __builtin_bit_cast(unsigned int, f);
  return (u16)((u + 0x7fffu + ((u >> 16) & 1u)) >> 16);
}
__device__ __forceinline__ float at_c(float x){          // _artanh with clip
  return atanhf(fminf(fmaxf(x, -1.f + 1e-5f), 1.f - 1e-5f));
}
__device__ __forceinline__ float wred(float v){          // 64-lane sum
#pragma unroll
  for (int m = 32; m; m >>= 1) v += __shfl_xor(v, m);
  return v;
}
__device__ __forceinline__ float sig_proj(float npre, float* nrm){
  float n = fmaxf(npre, SQEPS);
  float s = (n > MXN) ? (MXN / n) : 1.f;
  *nrm = fminf(n, MXN);
  return s;
}
__device__ __forceinline__ void ld4(const u16* p, float v[4]){   // bf16 table load
  u16x4 t = *(const u16x4*)p;
#pragma unroll
  for (int r = 0; r < 4; r++) v[r] = b2f(t[r]);
}
__device__ __forceinline__ void ld4f(const float* p, float v[4]){ // f32 load
  f32x4 t = *(const f32x4*)p;
#pragma unroll
  for (int r = 0; r < 4; r++) v[r] = t[r];
}

// ---------------- K1: per-node prep: x_ball (f32), norms ----------------
__global__ void __launch_bounds__(256) k_prep(const float* __restrict__ x,
    const float* __restrict__ h1, const float* __restrict__ c1,
    float* __restrict__ xb, float* __restrict__ scal)
{
  int w = threadIdx.x >> 6, lane = threadIdx.x & 63;
  int n = blockIdx.x * 4 + w;
  int base = n * D + lane * 4;
  float xv[4], hv[4], cv[4];
  ld4f(x + base, xv); ld4f(h1 + base, hv); ld4f(c1 + base, cv);
  float un2 = 0, hn2 = 0, prn2 = 0, cn2 = 0;
#pragma unroll
  for (int r = 0; r < 4; r++){
    un2 += xv[r]*xv[r]; hn2 += hv[r]*hv[r];
    float rr = fmaxf(hv[r], 0.f); prn2 += rr*rr;
    cn2 += cv[r]*cv[r];
  }
  un2 = wred(un2); hn2 = wred(hn2); prn2 = wred(prn2); cn2 = wred(cn2);
  float un = sqrtf(fmaxf(un2, EPSR));
  float t  = tanhf(un);
  float sc = t / un;
  float nx = sqrtf(fmaxf(sc*sc*un2, EPSR));
  float s  = (nx > MXN) ? (MXN / nx) : 1.f;
  f32x4 o;
#pragma unroll
  for (int r = 0; r < 4; r++) o[r] = s * sc * xv[r];
  *(f32x4*)(xb + base) = o;
  if (lane == 0){
    float* sp = scal + (size_t)n * 16;
    sp[0] = fminf(nx, MXN);
    sp[1] = hn2; sp[2] = prn2; sp[3] = cn2;
    float hn = sqrtf(fmaxf(hn2, EPSR));
    sp[9] = at_c(hn); sp[10] = hn;
  }
}

// -- MFMA GEMM (dual-B): C[M,Nout](bf16) = A[M,K](f32) @ [B1;B2][Nout,K]^T (f32) --
#define TM 128
#define TN 128
#define TK 32
#define LDP 40
__global__ void __launch_bounds__(256) gemm_bt(const float* __restrict__ A,
    const float* __restrict__ B1, const float* __restrict__ B2, int split,
    u16* __restrict__ C, int K, int Nout)
{
  __shared__ u16 As[TM*LDP];
  __shared__ u16 Bs[TN*LDP];
  int t = threadIdx.x;
  int m0 = blockIdx.x * TM, n0 = blockIdx.y * TN;
  int w = t >> 6, lane = t & 63;
  int wr = w >> 1, wc = w & 1;
  int q = lane >> 4, l16 = lane & 15;
  f32x4 acc[4][4];
#pragma unroll
  for (int i = 0; i < 4; i++)
#pragma unroll
    for (int j = 0; j < 4; j++) acc[i][j] = (f32x4){0.f,0.f,0.f,0.f};
  for (int k0 = 0; k0 < K; k0 += TK){
    __syncthreads();
#pragma unroll
    for (int c = t; c < 1024; c += 256){
      int row = c >> 3, ko = (c & 7) * 4;
      int grow = n0 + row;
      const float* bsrc = (grow < split) ? (B1 + (size_t)grow*K)
                                         : (B2 + (size_t)(grow - split)*K);
      f32x4 a4 = *(const f32x4*)(A + (size_t)(m0+row)*K + k0 + ko);
      f32x4 b4 = *(const f32x4*)(bsrc + k0 + ko);
      u16x4 ua, ub;
#pragma unroll
      for (int r = 0; r < 4; r++){ ua[r] = f2b(a4[r]); ub[r] = f2b(b4[r]); }
      *(u16x4*)(As + row*LDP + ko) = ua;
      *(u16x4*)(Bs + row*LDP + ko) = ub;
    }
    __syncthreads();
    bf16x8 af[4], bfr[4];
#pragma unroll
    for (int rb = 0; rb < 4; rb++)
      af[rb] = *(const bf16x8*)(As + (wr*64 + rb*16 + l16)*LDP + q*8);
#pragma unroll
    for (int cb = 0; cb < 4; cb++)
      bfr[cb] = *(const bf16x8*)(Bs + (wc*64 + cb*16 + l16)*LDP + q*8);
#pragma unroll
    for (int rb = 0; rb < 4; rb++)
#pragma unroll
      for (int cb = 0; cb < 4; cb++)
        acc[rb][cb] = __builtin_amdgcn_mfma_f32_16x16x32_bf16(af[rb], bfr[cb], acc[rb][cb], 0, 0, 0);
  }
#pragma unroll
  for (int rb = 0; rb < 4; rb++)
#pragma unroll
    for (int cb = 0; cb < 4; cb++)
#pragma unroll
      for (int r = 0; r < 4; r++){
        int m  = m0 + wr*64 + rb*16 + q*4 + r;
        int nn = n0 + wc*64 + cb*16 + l16;
        C[(size_t)m*Nout + nn] = f2b(acc[rb][cb][r]);
      }
}

// z = mobius_add(mm_scale(m; xn), b) ; returns clipped norm of z
__device__ __forceinline__ float mm_madd(const float mv[4], const float bv[4], float xn, float z[4]){
  float mn2 = 0.f;
#pragma unroll
  for (int r = 0; r < 4; r++) mn2 += mv[r]*mv[r];
  mn2 = wred(mn2);
  float mnc = sqrtf(fmaxf(mn2, EPSR));
  float t = tanhf(mnc / xn * at_c(xn));
  float npre = t * sqrtf(mn2) / mnc;
  float nf; float sg = sig_proj(npre, &nf);
  float cx = sg * t / mnc;
  float x2 = (sg*npre)*(sg*npre);
  float y2 = 0.f, xy = 0.f;
#pragma unroll
  for (int r = 0; r < 4; r++){ y2 += bv[r]*bv[r]; xy += cx*mv[r]*bv[r]; }
  y2 = wred(y2); xy = wred(xy);
  float A = 1.f + 2.f*xy + y2, Bc = 1.f - x2;
  float den = fmaxf(1.f + 2.f*xy + x2*y2, EPSR);
  float zn2 = (A*A*x2 + 2.f*A*Bc*xy + Bc*Bc*y2) / (den*den);
  float zn = sqrtf(fmaxf(zn2, EPSR));
  float sz = (zn > MXN) ? (MXN/zn) : 1.f;
#pragma unroll
  for (int r = 0; r < 4; r++) z[r] = sz * (A*cx*mv[r] + Bc*bv[r]) / den;
  return fminf(zn, MXN);
}

// ---------------- K7: per-node post-GEMM: q, kvec, f, c_sk tables ----------------
__global__ void __launch_bounds__(256) k_post(
    const u16* __restrict__ mqiou, const u16* __restrict__ mkf,
    const u16* __restrict__ mc,
    const float* __restrict__ c1,
    const float* __restrict__ bq, const float* __restrict__ bk, const float* __restrict__ bc,
    u16* __restrict__ qv, u16* __restrict__ kv,
    u16* __restrict__ fcs, u16* __restrict__ fcm,
    float* __restrict__ scal)
{
  int w = threadIdx.x >> 6, lane = threadIdx.x & 63;
  int n = blockIdx.x * 4 + w;
  int base = n * D + lane * 4, lb = lane * 4;
  float* sp = scal + (size_t)n * 16;
  float xbn = sp[0], hn2 = sp[1], cn2 = sp[3];
  float hnc = sqrtf(fmaxf(hn2, EPSR));
  float cnc = sqrtf(fmaxf(cn2, EPSR));
  float mv[4], bv[4], z[4];
  u16x4 o;
  // q = logmap0(mobius_add(mm(W_q, x_ball), b_q))    [mqiou cols 0:256, stride 1024]
  ld4(mqiou + (size_t)n*1024 + lb, mv); ld4f(bq + lb, bv);
  float znf = mm_madd(mv, bv, xbn, z);
  float cl = at_c(znf) / znf;
#pragma unroll
  for (int r = 0; r < 4; r++) o[r] = f2b(cl * z[r]);
  *(u16x4*)(qv + base) = o;
  // kvec = logmap0(mobius_add(mm(W_k, h1), b_k))     [mkf cols 0:256, stride 512]
  ld4(mkf + (size_t)n*512 + lb, mv); ld4f(bk + lb, bv);
  znf = mm_madd(mv, bv, hnc, z);
  cl = at_c(znf) / znf;
#pragma unroll
  for (int r = 0; r < 4; r++) o[r] = f2b(cl * z[r]);
  *(u16x4*)(kv + base) = o;
  // f = sigmoid(logmap0(mm(U_f, h1)))                [mkf cols 256:512]
  float fv[4];
  {
    ld4(mkf + (size_t)n*512 + 256 + lb, mv);
    float mn2 = 0.f;
#pragma unroll
    for (int r = 0; r < 4; r++) mn2 += mv[r]*mv[r];
    mn2 = wred(mn2);
    float mnc = sqrtf(fmaxf(mn2, EPSR));
    float t = tanhf(mnc / hnc * at_c(hnc));
    float npre = t * sqrtf(mn2) / mnc;
    float nf; float sg = sig_proj(npre, &nf);
    float cx = sg * t / mnc;
    float lcf = at_c(nf) / nf;
#pragma unroll
    for (int r = 0; r < 4; r++) fv[r] = 1.f / (1.f + expf(-lcf * cx * mv[r]));
  }
  // c_sk = expmap0(tanh(logmap0(mobius_add(mm(W_c, c1), b_c))))
  float csk[4];
  {
    ld4(mc + base, mv); ld4f(bc + lb, bv);
    float zn = mm_madd(mv, bv, cnc, z);
    float lc = at_c(zn) / zn;
    float th[4]; float thn2 = 0.f;
#pragma unroll
    for (int r = 0; r < 4; r++){ th[r] = tanhf(lc * z[r]); thn2 += th[r]*th[r]; }
    thn2 = wred(thn2);
    float thn = sqrtf(fmaxf(thn2, EPSR));
    float te = tanhf(thn);
    float se = te / thn;
    float npe = sqrtf(fmaxf(se*se*thn2, EPSR));
    float sge = (npe > MXN) ? (MXN/npe) : 1.f;
#pragma unroll
    for (int r = 0; r < 4; r++) csk[r] = sge * se * th[r];
  }
  float c1v[4]; ld4f(c1 + base, c1v);
  float csn2 = 0, pcc = 0, pfss = 0, pfsm = 0, pfmm = 0;
#pragma unroll
  for (int r = 0; r < 4; r++){
    float f2 = fv[r]*fv[r];
    csn2 += csk[r]*csk[r];
    pcc  += csk[r]*c1v[r];
    pfss += f2*csk[r]*csk[r];
    pfsm += f2*csk[r]*c1v[r];
    pfmm += f2*c1v[r]*c1v[r];
  }
  csn2 = wred(csn2); pcc = wred(pcc); pfss = wred(pfss); pfsm = wred(pfsm); pfmm = wred(pfmm);
  u16x4 oa, ob;
#pragma unroll
  for (int r = 0; r < 4; r++){ oa[r] = f2b(fv[r]*csk[r]); ob[r] = f2b(fv[r]*c1v[r]); }
  *(u16x4*)(fcs + base) = oa;
  *(u16x4*)(fcm + base) = ob;
  if (lane == 0){
    sp[4] = csn2; sp[5] = pcc; sp[6] = pfss; sp[7] = pfsm; sp[8] = pfmm;
  }
}

// ---------------- K8a: logits (wave per node) ----------------
__global__ void __launch_bounds__(256) k_logit(
    const int* __restrict__ edges, const float* __restrict__ del_t,
    const u16* __restrict__ qv, const u16* __restrict__ kvec,
    const float* __restrict__ pbh, const float* __restrict__ pah,
    float* __restrict__ logit)
{
  int w = threadIdx.x >> 6, lane = threadIdx.x & 63;
  int n = blockIdx.x * 4 + w;
  float bh = pbh[0], ah = pah[0];
  float qf[4]; ld4(qv + n*D + lane*4, qf);
  for (int k = 0; k < 16; k++){
    int j = edges[n*16 + k];
    float dt = del_t[j];
    u16x4 kt = *(const u16x4*)(kvec + (size_t)j*D + lane*4);
    float d = 0.f;
#pragma unroll
    for (int r = 0; r < 4; r++) d += qf[r] * b2f(kt[r]);
    d = wred(d);
    if (lane == 0) logit[n*16 + k] = d * 0.0625f + bh * expf(-ah * dt);
  }
}

// ---------------- K8b: per-edge coefficient chain (thread per edge) ----------------
__global__ void __launch_bounds__(256) k_coef(
    const int* __restrict__ edges, const float* __restrict__ del_t,
    const float* __restrict__ logit, const float* __restrict__ scal,
    const float* __restrict__ pbh, const float* __restrict__ pah,
    const float* __restrict__ ph1, const float* __restrict__ ph2,
    float* __restrict__ coef)
{
  int e = blockIdx.x * 256 + threadIdx.x;     // e in [0, NN*16)
  int n = e >> 4;
  int j = edges[e];
  float dt = del_t[j];
  float bh = pbh[0], ah = pah[0], hw1 = ph1[0], hw2 = ph2[0];
  const float* ln = logit + n*16;
  float mxl = -1e30f;
#pragma unroll
  for (int k = 0; k < 16; k++) mxl = fmaxf(mxl, ln[k]);
  float sume = 0.f;
#pragma unroll
  for (int k = 0; k < 16; k++) sume += expf(ln[k] - mxl);
  float sk = expf(ln[e & 15] - mxl) / sume;
  const float* sp2 = scal + (size_t)j * 16;
  float hn2 = sp2[1], prn2 = sp2[2], cn2 = sp2[3], csn2 = sp2[4], pcc = sp2[5],
        pfss = sp2[6], pfsm = sp2[7], pfmm = sp2[8], athn = sp2[9], hn = sp2[10];
  float g = bh * expf(-ah * dt);
  float decay = expf(-hw2 * dt * (1.f/60.f));
  // h-side: h_scaled = a_h*hx ; h_max = b_h*relu(hx)
  float wxn1 = sqrtf(fmaxf(sk*sk*hn2, EPSR));
  float t1 = tanhf(wxn1 / hn * athn);
  float npre1 = t1 * sk * sqrtf(hn2) / wxn1;
  float nn1 = fmaxf(npre1, SQEPS); float sg1 = (nn1 > MXN) ? MXN/nn1 : 1.f;
  float a_h = sg1 * t1 * sk / wxn1;
  float rn2 = a_h*a_h*prn2;
  float xnd  = sqrtf(fmaxf(decay*decay, EPSR));
  float wxn2 = sqrtf(fmaxf(decay*decay*rn2, EPSR));
  float t2 = tanhf(wxn2 / xnd * at_c(xnd));
  float npre2 = t2 * decay * sqrtf(rn2) / wxn2;
  float nn2 = fmaxf(npre2, SQEPS); float sg2 = (nn2 > MXN) ? MXN/nn2 : 1.f;
  float b_h = sg2 * t2 * decay * a_h / wxn2;
  float bh1 = hw1 * b_h;
  float x2 = a_h*a_h*hn2;
  float y2 = bh1*bh1*prn2;
  float xy = a_h*bh1*prn2;            // hx dot relu(hx) = relu(hx)^2
  float A = 1.f + 2.f*xy + y2, B = 1.f - x2;
  float den = fmaxf(1.f + 2.f*xy + x2*y2, EPSR);
  float nh2 = (A*A*x2 + 2.f*A*B*xy + B*B*y2) / (den*den);
  float nh = sqrtf(fmaxf(nh2, EPSR)); float sg3 = (nh > MXN) ? MXN/nh : 1.f;
  float p  = sg3 * A * a_h / den;
  float rr = sg3 * B * bh1 / den;
  float hhn2 = sg3*sg3*nh2;
  float lam = 2.f / fmaxf(1.f - hhn2, EPSR);
  // c-side
  float xng  = sqrtf(fmaxf(g*g, EPSR));
  float wxn3 = sqrtf(fmaxf(g*g*csn2, EPSR));
  float t3 = tanhf(wxn3 / xng * at_c(xng));
  float npre3 = t3 * g * sqrtf(csn2) / wxn3;
  float nn3 = fmaxf(npre3, SQEPS); float sgc = (nn3 > MXN) ? MXN/nn3 : 1.f;
  float gam = sgc * t3 * g / wxn3;
  float A1 = 1.f - 2.f*pcc + cn2, B1 = 1.f - csn2;
  float den1 = fmaxf(1.f - 2.f*pcc + csn2*cn2, EPSR);
  float al = -A1/den1, be = B1/den1;
  float n1sq = al*al*csn2 + 2.f*al*be*pcc + be*be*cn2;
  float n1 = sqrtf(fmaxf(n1sq, EPSR)); float s1 = (n1 > MXN) ? MXN/n1 : 1.f;
  al *= s1; be *= s1;
  float z1n2 = s1*s1*n1sq;
  float y2c = gam*gam*csn2;
  float xyc = gam*(al*csn2 + be*pcc);
  float A2 = 1.f + 2.f*xyc + y2c, B2 = 1.f - z1n2;
  float den2 = fmaxf(1.f + 2.f*xyc + z1n2*y2c, EPSR);
  float u1 = (A2*al + B2*gam)/den2, u2 = A2*be/den2;
  float n2sq = u1*u1*csn2 + 2.f*u1*u2*pcc + u2*u2*cn2;
  float n2 = sqrtf(fmaxf(n2sq, EPSR)); float s2 = (n2 > MXN) ? MXN/n2 : 1.f;
  u1 *= s2; u2 *= s2;
  float xnc = fminf(n2, MXN);
  float wx2 = u1*u1*pfss + 2.f*u1*u2*pfsm + u2*u2*pfmm;
  float wxn4 = sqrtf(fmaxf(wx2, EPSR));
  float t4 = tanhf(wxn4 / xnc * at_c(xnc));
  float npre4 = t4 * sqrtf(wx2) / wxn4;
  float nn4 = fmaxf(npre4, SQEPS); float s4 = (nn4 > MXN) ? MXN/nn4 : 1.f;
  float v1 = s4*t4*u1/wxn4, v2 = s4*t4*u2/wxn4;
  float rsn2 = (s4*npre4)*(s4*npre4);
  float lam2 = 2.f / fmaxf(1.f - rsn2, EPSR);
  float* cf = coef + (size_t)e * 6;
  cf[0] = lam; cf[1] = lam*p; cf[2] = lam*rr;
  cf[3] = lam2; cf[4] = lam2*v1; cf[5] = lam2*v2;
}

// ---------------- K8c: accumulate + midpoint epilogue (wave per node) ----------------
__global__ void __launch_bounds__(256) k_acc(
    const int* __restrict__ edges, const float* __restrict__ h1,
    const u16* __restrict__ fcs, const u16* __restrict__ fcm,
    const float* __restrict__ coef,
    float* __restrict__ ht, u16* __restrict__ cred, float* __restrict__ htn_arr)
{
  int w = threadIdx.x >> 6, lane = threadIdx.x & 63;
  int n = blockIdx.x * 4 + w;
  float numh[4] = {0,0,0,0}, numc[4] = {0,0,0,0};
  float denh = 0.f, denc = 0.f;
  for (int k = 0; k < 16; k++){
    int e = n*16 + k;
    int j = edges[e];
    const float* cf = coef + (size_t)e * 6;
    float lam = cf[0], lamp = cf[1], lamr = cf[2];
    float lam2 = cf[3], lv1 = cf[4], lv2 = cf[5];
    denh += lam - 1.f; denc += lam2 - 1.f;
    float hx[4]; ld4f(h1 + (size_t)j*D + lane*4, hx);
    u16x4 fs4 = *(const u16x4*)(fcs + (size_t)j*D + lane*4);
    u16x4 fm4 = *(const u16x4*)(fcm + (size_t)j*D + lane*4);
#pragma unroll
    for (int r = 0; r < 4; r++){
      numh[r] += lamp*hx[r] + lamr*fmaxf(hx[r], 0.f);
      numc[r] += lv1*b2f(fs4[r]) + lv2*b2f(fm4[r]);
    }
  }
  if (fabsf(denh) < 1e-10f) denh = 1e-10f;
  if (fabsf(denc) < 1e-10f) denc = 1e-10f;
  float vh[4], vc[4]; float vn2h = 0.f, vn2c = 0.f;
#pragma unroll
  for (int r = 0; r < 4; r++){
    vh[r] = numh[r]/denh; vn2h += vh[r]*vh[r];
    vc[r] = numc[r]/denc; vn2c += vc[r]*vc[r];
  }
  vn2h = wred(vn2h); vn2c = wred(vn2c);
  float vnh = sqrtf(fmaxf(vn2h, EPSR));
  float tth = tanhf(0.5f * at_c(vnh));
  float nph = tth * sqrtf(vn2h) / vnh;
  float nfh; float sh = sig_proj(nph, &nfh);
  float chh = sh * tth / vnh;
  f32x4 ho;
#pragma unroll
  for (int r = 0; r < 4; r++) ho[r] = chh * vh[r];
  *(f32x4*)(ht + n*D + lane*4) = ho;
  if (lane == 0) htn_arr[n] = nfh;
  float vnc = sqrtf(fmaxf(vn2c, EPSR));
  float ttc = tanhf(0.5f * at_c(vnc));
  float npc = ttc * sqrtf(vn2c) / vnc;
  float nfc; float scz = sig_proj(npc, &nfc);
  float chc = scz * ttc / vnc;
  u16x4 co;
#pragma unroll
  for (int r = 0; r < 4; r++) co[r] = f2b(chc * vc[r]);
  *(u16x4*)(cred + n*D + lane*4) = co;
}

// ---------------- K10: final iou chain + outputs ----------------
__global__ void __launch_bounds__(256) k_final(
    const u16* __restrict__ mqiou, const u16* __restrict__ mu,
    const u16* __restrict__ cred, const float* __restrict__ biou,
    const float* __restrict__ scal, const float* __restrict__ htn_arr,
    float* __restrict__ out)
{
  int w = threadIdx.x >> 6, lane = threadIdx.x & 63;
  int n = blockIdx.x * 4 + w;
  float mi[3][4], muv[3][4], bi[3][4];
#pragma unroll
  for (int p = 0; p < 3; p++){
    ld4(mqiou + (size_t)n*1024 + 256 + p*256 + lane*4, mi[p]);   // miou cols 256:1024
    ld4(mu   + (size_t)n*768 + p*256 + lane*4, muv[p]);
    ld4f(biou + p*256 + lane*4, bi[p]);
  }
  float cr[4]; ld4(cred + (size_t)n*D + lane*4, cr);
  float xbn = scal[(size_t)n*16 + 0];
  float htn = htn_arr[n];
  float mn2 = 0.f, un2 = 0.f, dmu = 0.f;
#pragma unroll
  for (int p = 0; p < 3; p++)
#pragma unroll
    for (int r = 0; r < 4; r++){
      mn2 += mi[p][r]*mi[p][r]; un2 += muv[p][r]*muv[p][r]; dmu += mi[p][r]*muv[p][r];
    }
  mn2 = wred(mn2); un2 = wred(un2); dmu = wred(dmu);
  float mnc = sqrtf(fmaxf(mn2, EPSR));
  float ta = tanhf(mnc / xbn * at_c(xbn));
  float npa = ta * sqrtf(mn2) / mnc;
  float na_; float sa = sig_proj(npa, &na_);
  float ca = sa * ta / mnc; float x2 = (sa*npa)*(sa*npa);
  float unc = sqrtf(fmaxf(un2, EPSR));
  float tb = tanhf(unc / htn * at_c(htn));
  float npb = tb * sqrtf(un2) / unc;
  float nb_; float sb = sig_proj(npb, &nb_);
  float cb = sb * tb / unc; float y2 = (sb*npb)*(sb*npb);
  float xy = ca * cb * dmu;
  float A = 1.f + 2.f*xy + y2, B = 1.f - x2;
  float den = fmaxf(1.f + 2.f*xy + x2*y2, EPSR);
  float c_mi = A*ca/den, c_mu = B*cb/den;
  float n1sq = (A*A*x2 + 2.f*A*B*xy + B*B*y2) / (den*den);
  float n1 = sqrtf(fmaxf(n1sq, EPSR)); float s1 = (n1 > MXN) ? MXN/n1 : 1.f;
  c_mi *= s1; c_mu *= s1;
  float iou1n2 = s1*s1*n1sq;
  float io1[3][4]; float bb2 = 0.f, xyb = 0.f;
#pragma unroll
  for (int p = 0; p < 3; p++)
#pragma unroll
    for (int r = 0; r < 4; r++){
      io1[p][r] = c_mi*mi[p][r] + c_mu*muv[p][r];
      bb2 += bi[p][r]*bi[p][r]; xyb += io1[p][r]*bi[p][r];
    }
  bb2 = wred(bb2); xyb = wred(xyb);
  float A2 = 1.f + 2.f*xyb + bb2, B2 = 1.f - iou1n2;
  float den2 = fmaxf(1.f + 2.f*xyb + iou1n2*bb2, EPSR);
  float n2sq = (A2*A2*iou1n2 + 2.f*A2*B2*xyb + B2*B2*bb2) / (den2*den2);
  float n2c = sqrtf(fmaxf(n2sq, EPSR)); float s2 = (n2c > MXN) ? MXN/n2c : 1.f;
  float iou[3][4];
#pragma unroll
  for (int p = 0; p < 3; p++)
#pragma unroll
    for (int r = 0; r < 4; r++) iou[p][r] = s2 * (A2*io1[p][r] + B2*bi[p][r]) / den2;
  float ni2 = 0.f, no2 = 0.f, nu2 = 0.f;
#pragma unroll
  for (int r = 0; r < 4; r++){ ni2 += iou[0][r]*iou[0][r]; no2 += iou[1][r]*iou[1][r]; nu2 += iou[2][r]*iou[2][r]; }
  ni2 = wred(ni2); no2 = wred(no2); nu2 = wred(nu2);
  float niN = sqrtf(fmaxf(ni2, EPSR)), noN = sqrtf(fmaxf(no2, EPSR)), nuN = sqrtf(fmaxf(nu2, EPSR));
  float ci = at_c(niN)/niN, co = at_c(noN)/noN, cu = at_c(nuN)/nuN;
  float iv[4], ov[4], uv[4];
#pragma unroll
  for (int r = 0; r < 4; r++){
    iv[r] = 1.f / (1.f + expf(-ci*iou[0][r]));
    ov[r] = 1.f / (1.f + expf(-co*iou[1][r]));
    uv[r] = tanhf(cu*iou[2][r]);
  }
  float xn2 = 0.f, wn2 = 0.f; float wx[4];
#pragma unroll
  for (int r = 0; r < 4; r++){ xn2 += uv[r]*uv[r]; wx[r] = iv[r]*uv[r]; wn2 += wx[r]*wx[r]; }
  xn2 = wred(xn2); wn2 = wred(wn2);
  float xnc = sqrtf(fmaxf(xn2, EPSR)), wnc = sqrtf(fmaxf(wn2, EPSR));
  float t4 = tanhf(wnc / xnc * at_c(xnc));
  float np4 = t4 * sqrtf(wn2) / wnc;
  float n4_; float s4 = sig_proj(np4, &n4_);
  float cpm = s4*t4/wnc; float pmn2 = (s4*np4)*(s4*np4);
  float y2c = 0.f, xyc = 0.f;
#pragma unroll
  for (int r = 0; r < 4; r++){ y2c += cr[r]*cr[r]; xyc += cpm*wx[r]*cr[r]; }
  y2c = wred(y2c); xyc = wred(xyc);
  float A3 = 1.f + 2.f*xyc + y2c, B3 = 1.f - pmn2;
  float den3 = fmaxf(1.f + 2.f*xyc + pmn2*y2c, EPSR);
  float n3sq = (A3*A3*pmn2 + 2.f*A3*B3*xyc + B3*B3*y2c) / (den3*den3);
  float n3 = sqrtf(fmaxf(n3sq, EPSR)); float s3 = (n3 > MXN) ? MXN/n3 : 1.f;
  float cnw[4]; f32x4 oc;
#pragma unroll
  for (int r = 0; r < 4; r++){ cnw[r] = s3*(A3*cpm*wx[r] + B3*cr[r])/den3; oc[r] = cnw[r]; }
  *(f32x4*)(out + NB + (size_t)n*D + lane*4) = oc;
  float ncn = fminf(n3, MXN);
  float clg = at_c(ncn)/ncn;
  float th[4]; float xn5 = 0.f, wn5 = 0.f; float wx5[4];
#pragma unroll
  for (int r = 0; r < 4; r++){
    th[r] = tanhf(clg*cnw[r]);
    xn5 += th[r]*th[r]; wx5[r] = ov[r]*th[r]; wn5 += wx5[r]*wx5[r];
  }
  xn5 = wred(xn5); wn5 = wred(wn5);
  float xn5c = sqrtf(fmaxf(xn5, EPSR)), wn5c = sqrtf(fmaxf(wn5, EPSR));
  float t5 = tanhf(wn5c / xn5c * at_c(xn5c));
  float np5 = t5 * sqrtf(wn5) / wn5c;
  float n5_; float s5 = sig_proj(np5, &n5_);
  float ch = s5*t5/wn5c;
  f32x4 oh;
#pragma unroll
  for (int r = 0; r < 4; r++) oh[r] = ch * wx5[r];
  *(f32x4*)(out + (size_t)n*D + lane*4) = oh;
}

extern "C" void kernel_launch(void* const* d_in, const int* in_sizes, int n_in,
                              void* d_out, int out_size, void* d_ws, size_t ws_size,
                              hipStream_t stream)
{
  (void)in_sizes; (void)n_in; (void)out_size; (void)ws_size;
  const float* x     = (const float*)d_in[0];
  const float* h1    = (const float*)d_in[1];
  const float* c1    = (const float*)d_in[2];
  const float* del_t = (const float*)d_in[3];
  const int*   edges = (const int*)d_in[4];
  const float* W_iou = (const float*)d_in[5];
  const float* U_iou = (const float*)d_in[6];
  const float* b_iou = (const float*)d_in[7];
  const float* U_f   = (const float*)d_in[8];
  const float* W_q   = (const float*)d_in[9];
  const float* b_q   = (const float*)d_in[10];
  const float* W_k   = (const float*)d_in[11];
  const float* b_k   = (const float*)d_in[12];
  const float* W_c   = (const float*)d_in[13];
  const float* b_c   = (const float*)d_in[14];
  const float* b_haw = (const float*)d_in[15];
  const float* a_haw = (const float*)d_in[16];
  const float* haw1  = (const float*)d_in[17];
  const float* haw2  = (const float*)d_in[18];

  // workspace (u16 units): xb(2NB, reused as ht) | mqiou(4NB) | mkf(2NB) |
  // mc(NB) | qv(NB, reused as cred) | kvec(NB, reused as coef 6.3MB) |
  // fcs(NB) | fcm(NB) | scal | logit | htn.  mu(3NB) = mkf..mc region.
  float* xb   = (float*)d_ws;                 // NB f32
  u16* mqiou  = (u16*)(xb + NB);              // 4*NB
  u16* mkf    = mqiou + 4*(size_t)NB;         // 2*NB
  u16* mc     = mkf + 2*(size_t)NB;           // NB
  u16* qv     = mc + NB;                      // NB
  u16* kvec   = qv + NB;                      // NB
  u16* fcs    = kvec + NB;                    // NB
  u16* fcm    = fcs + NB;                     // NB
  float* scal    = (float*)(fcm + NB);        // NN*16 f32
  float* logit   = scal + (size_t)NN*16;      // NN*16 f32
  float* htn_arr = logit + (size_t)NN*16;     // NN f32
  float* ht   = xb;
  u16* cred   = qv;
  float* coef = (float*)kvec;                 // NN*16*6 f32
  u16* mu     = mkf;

  k_prep<<<NN/4, 256, 0, stream>>>(x, h1, c1, xb, scal);
  gemm_bt<<<dim3(NN/128, 8), 256, 0, stream>>>(xb, W_q, W_iou, 256, mqiou, 256, 1024);
  gemm_bt<<<dim3(NN/128, 4), 256, 0, stream>>>(h1, W_k, U_f, 256, mkf, 256, 512);
  gemm_bt<<<dim3(NN/128, 2), 256, 0, stream>>>(c1, W_c, W_c, 256, mc, 256, 256);
  k_post<<<NN/4, 256, 0, stream>>>(mqiou, mkf, mc, c1, b_q, b_k, b_c, qv, kvec, fcs, fcm, scal);
  k_logit<<<NN/4, 256, 0, stream>>>(edges, del_t, qv, kvec, b_haw, a_haw, logit);
  k_coef<<<NN*16/256, 256, 0, stream>>>(edges, del_t, logit, scal, b_haw, a_haw, haw1, haw2, coef);
  k_acc<<<NN/4, 256, 0, stream>>>(edges, h1, fcs, fcm, coef, ht, cred, htn_arr);
  gemm_bt<<<dim3(NN/128, 6), 256, 0, stream>>>(ht, U_iou, U_iou, 768, mu, 256, 768);
  k_final<<<NN/4, 256, 0, stream>>>(mqiou, mu, cred, b_iou, scal, htn_arr, (float*)d_out);
}

// Round 5
// 396.998 us; speedup vs baseline: 2.1820x; 1.2237x over previous
//
#include <hip/hip_runtime.h>
#include <math.h>

#define NN 16384
#define D  256
#define NB (NN*D)
#define EPSR 1e-15f
#define SQEPS 3.1622776601683794e-8f
#define MXN 0.99999f   /* 1 - 1e-5 */

typedef unsigned short u16;
typedef __bf16 bf16x8 __attribute__((ext_vector_type(8)));
typedef float f32x4 __attribute__((ext_vector_type(4)));
typedef unsigned short u16x8 __attribute__((ext_vector_type(8)));
typedef unsigned short u16x4 __attribute__((ext_vector_type(4)));

// ---- fast hw transcendentals (v_exp/v_log/v_rcp/v_sqrt are 1-instr; ~1ulp) ----
__device__ __forceinline__ float fexp(float x){ return __builtin_amdgcn_exp2f(x * 1.4426950408889634f); }
__device__ __forceinline__ float flog(float x){ return __builtin_amdgcn_logf(x) * 0.6931471805599453f; }
__device__ __forceinline__ float frcp(float x){ return __builtin_amdgcn_rcpf(x); }
__device__ __forceinline__ float fsqrt(float x){ return __builtin_amdgcn_sqrtf(x); }
__device__ __forceinline__ float ftanh(float x){
  float xc = fminf(fmaxf(x, -15.f), 15.f);
  float t = fexp(2.f * xc);
  return (t - 1.f) * frcp(t + 1.f);
}
__device__ __forceinline__ float at_c(float x){          // _artanh with clip
  float xc = fminf(fmaxf(x, -1.f + 1e-5f), 1.f - 1e-5f);
  return 0.5f * flog((1.f + xc) * frcp(1.f - xc));
}
__device__ __forceinline__ float fsig(float x){ return frcp(1.f + fexp(-x)); }

__device__ __forceinline__ float b2f(u16 u){
  unsigned int x = ((unsigned int)u) << 16;
  return __builtin_bit_cast(float, x);
}
__device__ __forceinline__ u16 f2b(float f){
  unsigned int u = __builtin_bit_cast(unsigned int, f);
  return (u16)((u + 0x7fffu + ((u >> 16) & 1u)) >> 16);
}
__device__ __forceinline__ float wred(float v){          // 64-lane sum
#pragma unroll
  for (int m = 32; m; m >>= 1) v += __shfl_xor(v, m);
  return v;
}
__device__ __forceinline__ float sig_proj(float npre, float* nrm){
  float n = fmaxf(npre, SQEPS);
  float s = (n > MXN) ? (MXN * frcp(n)) : 1.f;
  *nrm = fminf(n, MXN);
  return s;
}
__device__ __forceinline__ void ld4(const u16* p, float v[4]){   // bf16 table load
  u16x4 t = *(const u16x4*)p;
#pragma unroll
  for (int r = 0; r < 4; r++) v[r] = b2f(t[r]);
}
__device__ __forceinline__ void ld4f(const float* p, float v[4]){ // f32 load
  f32x4 t = *(const f32x4*)p;
#pragma unroll
  for (int r = 0; r < 4; r++) v[r] = t[r];
}

// ---------------- K1: per-node prep: x_ball (f32), norms ----------------
__global__ void __launch_bounds__(256) k_prep(const float* __restrict__ x,
    const float* __restrict__ h1, const float* __restrict__ c1,
    float* __restrict__ xb, float* __restrict__ scal)
{
  int w = threadIdx.x >> 6, lane = threadIdx.x & 63;
  int n = blockIdx.x * 4 + w;
  int base = n * D + lane * 4;
  float xv[4], hv[4], cv[4];
  ld4f(x + base, xv); ld4f(h1 + base, hv); ld4f(c1 + base, cv);
  float un2 = 0, hn2 = 0, prn2 = 0, cn2 = 0;
#pragma unroll
  for (int r = 0; r < 4; r++){
    un2 += xv[r]*xv[r]; hn2 += hv[r]*hv[r];
    float rr = fmaxf(hv[r], 0.f); prn2 += rr*rr;
    cn2 += cv[r]*cv[r];
  }
  un2 = wred(un2); hn2 = wred(hn2); prn2 = wred(prn2); cn2 = wred(cn2);
  float un = fsqrt(fmaxf(un2, EPSR));
  float t  = ftanh(un);
  float sc = t * frcp(un);
  float nx = fsqrt(fmaxf(sc*sc*un2, EPSR));
  float s  = (nx > MXN) ? (MXN * frcp(nx)) : 1.f;
  f32x4 o;
#pragma unroll
  for (int r = 0; r < 4; r++) o[r] = s * sc * xv[r];
  *(f32x4*)(xb + base) = o;
  if (lane == 0){
    float* sp = scal + (size_t)n * 16;
    sp[0] = fminf(nx, MXN);
    sp[1] = hn2; sp[2] = prn2; sp[3] = cn2;
    float hn = fsqrt(fmaxf(hn2, EPSR));
    sp[9] = at_c(hn); sp[10] = hn;
  }
}

// -- MFMA GEMM (dual-B): C[M,Nout](bf16) = A[M,K](f32) @ [B1;B2][Nout,K]^T (f32) --
#define TM 128
#define TN 128
#define TK 32
#define LDP 40
__global__ void __launch_bounds__(256) gemm_bt(const float* __restrict__ A,
    const float* __restrict__ B1, const float* __restrict__ B2, int split,
    u16* __restrict__ C, int K, int Nout)
{
  __shared__ u16 As[TM*LDP];
  __shared__ u16 Bs[TN*LDP];
  int t = threadIdx.x;
  int m0 = blockIdx.x * TM, n0 = blockIdx.y * TN;
  int w = t >> 6, lane = t & 63;
  int wr = w >> 1, wc = w & 1;
  int q = lane >> 4, l16 = lane & 15;
  f32x4 acc[4][4];
#pragma unroll
  for (int i = 0; i < 4; i++)
#pragma unroll
    for (int j = 0; j < 4; j++) acc[i][j] = (f32x4){0.f,0.f,0.f,0.f};
  for (int k0 = 0; k0 < K; k0 += TK){
    __syncthreads();
#pragma unroll
    for (int c = t; c < 1024; c += 256){
      int row = c >> 3, ko = (c & 7) * 4;
      int grow = n0 + row;
      const float* bsrc = (grow < split) ? (B1 + (size_t)grow*K)
                                         : (B2 + (size_t)(grow - split)*K);
      f32x4 a4 = *(const f32x4*)(A + (size_t)(m0+row)*K + k0 + ko);
      f32x4 b4 = *(const f32x4*)(bsrc + k0 + ko);
      u16x4 ua, ub;
#pragma unroll
      for (int r = 0; r < 4; r++){ ua[r] = f2b(a4[r]); ub[r] = f2b(b4[r]); }
      *(u16x4*)(As + row*LDP + ko) = ua;
      *(u16x4*)(Bs + row*LDP + ko) = ub;
    }
    __syncthreads();
    bf16x8 af[4], bfr[4];
#pragma unroll
    for (int rb = 0; rb < 4; rb++)
      af[rb] = *(const bf16x8*)(As + (wr*64 + rb*16 + l16)*LDP + q*8);
#pragma unroll
    for (int cb = 0; cb < 4; cb++)
      bfr[cb] = *(const bf16x8*)(Bs + (wc*64 + cb*16 + l16)*LDP + q*8);
#pragma unroll
    for (int rb = 0; rb < 4; rb++)
#pragma unroll
      for (int cb = 0; cb < 4; cb++)
        acc[rb][cb] = __builtin_amdgcn_mfma_f32_16x16x32_bf16(af[rb], bfr[cb], acc[rb][cb], 0, 0, 0);
  }
#pragma unroll
  for (int rb = 0; rb < 4; rb++)
#pragma unroll
    for (int cb = 0; cb < 4; cb++)
#pragma unroll
      for (int r = 0; r < 4; r++){
        int m  = m0 + wr*64 + rb*16 + q*4 + r;
        int nn = n0 + wc*64 + cb*16 + l16;
        C[(size_t)m*Nout + nn] = f2b(acc[rb][cb][r]);
      }
}

// z = mobius_add(mm_scale(m; xn), b) ; returns clipped norm of z
__device__ __forceinline__ float mm_madd(const float mv[4], const float bv[4], float xn, float z[4]){
  float mn2 = 0.f;
#pragma unroll
  for (int r = 0; r < 4; r++) mn2 += mv[r]*mv[r];
  mn2 = wred(mn2);
  float mnc = fsqrt(fmaxf(mn2, EPSR));
  float imnc = frcp(mnc);
  float t = ftanh(mnc * frcp(xn) * at_c(xn));
  float npre = t * fsqrt(mn2) * imnc;
  float nf; float sg = sig_proj(npre, &nf);
  float cx = sg * t * imnc;
  float x2 = (sg*npre)*(sg*npre);
  float y2 = 0.f, xy = 0.f;
#pragma unroll
  for (int r = 0; r < 4; r++){ y2 += bv[r]*bv[r]; xy += cx*mv[r]*bv[r]; }
  y2 = wred(y2); xy = wred(xy);
  float A = 1.f + 2.f*xy + y2, Bc = 1.f - x2;
  float idn = frcp(fmaxf(1.f + 2.f*xy + x2*y2, EPSR));
  float zn2 = (A*A*x2 + 2.f*A*Bc*xy + Bc*Bc*y2) * idn * idn;
  float zn = fsqrt(fmaxf(zn2, EPSR));
  float sz = (zn > MXN) ? (MXN * frcp(zn)) : 1.f;
  float ca = sz * A * idn * cx, cb = sz * Bc * idn;
#pragma unroll
  for (int r = 0; r < 4; r++) z[r] = ca*mv[r] + cb*bv[r];
  return fminf(zn, MXN);
}

// ---------------- K7: per-node post-GEMM: q, kvec, f, c_sk tables ----------------
__global__ void __launch_bounds__(256) k_post(
    const u16* __restrict__ mqiou, const u16* __restrict__ mkf,
    const u16* __restrict__ mc,
    const float* __restrict__ c1,
    const float* __restrict__ bq, const float* __restrict__ bk, const float* __restrict__ bc,
    u16* __restrict__ qv, u16* __restrict__ kv,
    u16* __restrict__ fcs, u16* __restrict__ fcm,
    float* __restrict__ scal)
{
  int w = threadIdx.x >> 6, lane = threadIdx.x & 63;
  int n = blockIdx.x * 4 + w;
  int base = n * D + lane * 4, lb = lane * 4;
  float* sp = scal + (size_t)n * 16;
  float xbn = sp[0], hn2 = sp[1], cn2 = sp[3];
  float hnc = fsqrt(fmaxf(hn2, EPSR));
  float cnc = fsqrt(fmaxf(cn2, EPSR));
  float mv[4], bv[4], z[4];
  u16x4 o;
  // q = logmap0(mobius_add(mm(W_q, x_ball), b_q))    [mqiou cols 0:256, stride 1024]
  ld4(mqiou + (size_t)n*1024 + lb, mv); ld4f(bq + lb, bv);
  float znf = mm_madd(mv, bv, xbn, z);
  float cl = at_c(znf) * frcp(znf);
#pragma unroll
  for (int r = 0; r < 4; r++) o[r] = f2b(cl * z[r]);
  *(u16x4*)(qv + base) = o;
  // kvec = logmap0(mobius_add(mm(W_k, h1), b_k))     [mkf cols 0:256, stride 512]
  ld4(mkf + (size_t)n*512 + lb, mv); ld4f(bk + lb, bv);
  znf = mm_madd(mv, bv, hnc, z);
  cl = at_c(znf) * frcp(znf);
#pragma unroll
  for (int r = 0; r < 4; r++) o[r] = f2b(cl * z[r]);
  *(u16x4*)(kv + base) = o;
  // f = sigmoid(logmap0(mm(U_f, h1)))                [mkf cols 256:512]
  float fv[4];
  {
    ld4(mkf + (size_t)n*512 + 256 + lb, mv);
    float mn2 = 0.f;
#pragma unroll
    for (int r = 0; r < 4; r++) mn2 += mv[r]*mv[r];
    mn2 = wred(mn2);
    float mnc = fsqrt(fmaxf(mn2, EPSR));
    float imnc = frcp(mnc);
    float t = ftanh(mnc * frcp(hnc) * at_c(hnc));
    float npre = t * fsqrt(mn2) * imnc;
    float nf; float sg = sig_proj(npre, &nf);
    float cx = sg * t * imnc;
    float lcf = at_c(nf) * frcp(nf);
#pragma unroll
    for (int r = 0; r < 4; r++) fv[r] = fsig(lcf * cx * mv[r]);
  }
  // c_sk = expmap0(tanh(logmap0(mobius_add(mm(W_c, c1), b_c))))
  float csk[4];
  {
    ld4(mc + base, mv); ld4f(bc + lb, bv);
    float zn = mm_madd(mv, bv, cnc, z);
    float lc = at_c(zn) * frcp(zn);
    float th[4]; float thn2 = 0.f;
#pragma unroll
    for (int r = 0; r < 4; r++){ th[r] = ftanh(lc * z[r]); thn2 += th[r]*th[r]; }
    thn2 = wred(thn2);
    float thn = fsqrt(fmaxf(thn2, EPSR));
    float te = ftanh(thn);
    float se = te * frcp(thn);
    float npe = fsqrt(fmaxf(se*se*thn2, EPSR));
    float sge = (npe > MXN) ? (MXN * frcp(npe)) : 1.f;
#pragma unroll
    for (int r = 0; r < 4; r++) csk[r] = sge * se * th[r];
  }
  float c1v[4]; ld4f(c1 + base, c1v);
  float csn2 = 0, pcc = 0, pfss = 0, pfsm = 0, pfmm = 0;
#pragma unroll
  for (int r = 0; r < 4; r++){
    float f2 = fv[r]*fv[r];
    csn2 += csk[r]*csk[r];
    pcc  += csk[r]*c1v[r];
    pfss += f2*csk[r]*csk[r];
    pfsm += f2*csk[r]*c1v[r];
    pfmm += f2*c1v[r]*c1v[r];
  }
  csn2 = wred(csn2); pcc = wred(pcc); pfss = wred(pfss); pfsm = wred(pfsm); pfmm = wred(pfmm);
  u16x4 oa, ob;
#pragma unroll
  for (int r = 0; r < 4; r++){ oa[r] = f2b(fv[r]*csk[r]); ob[r] = f2b(fv[r]*c1v[r]); }
  *(u16x4*)(fcs + base) = oa;
  *(u16x4*)(fcm + base) = ob;
  if (lane == 0){
    sp[4] = csn2; sp[5] = pcc; sp[6] = pfss; sp[7] = pfsm; sp[8] = pfmm;
  }
}

// ---------------- K8a: logits (wave per node) ----------------
__global__ void __launch_bounds__(256) k_logit(
    const int* __restrict__ edges, const float* __restrict__ del_t,
    const u16* __restrict__ qv, const u16* __restrict__ kvec,
    const float* __restrict__ pbh, const float* __restrict__ pah,
    float* __restrict__ logit)
{
  int w = threadIdx.x >> 6, lane = threadIdx.x & 63;
  int n = blockIdx.x * 4 + w;
  float bh = pbh[0], ah = pah[0];
  float qf[4]; ld4(qv + n*D + lane*4, qf);
  for (int k = 0; k < 16; k++){
    int j = edges[n*16 + k];
    float dt = del_t[j];
    u16x4 kt = *(const u16x4*)(kvec + (size_t)j*D + lane*4);
    float d = 0.f;
#pragma unroll
    for (int r = 0; r < 4; r++) d += qf[r] * b2f(kt[r]);
    d = wred(d);
    if (lane == 0) logit[n*16 + k] = d * 0.0625f + bh * fexp(-ah * dt);
  }
}

// ---------------- K8b: per-edge coefficient chain (thread per edge) ----------------
__global__ void __launch_bounds__(256) k_coef(
    const int* __restrict__ edges, const float* __restrict__ del_t,
    const float* __restrict__ logit, const float* __restrict__ scal,
    const float* __restrict__ pbh, const float* __restrict__ pah,
    const float* __restrict__ ph1, const float* __restrict__ ph2,
    float* __restrict__ coef)
{
  int e = blockIdx.x * 256 + threadIdx.x;     // e in [0, NN*16)
  int n = e >> 4;
  int j = edges[e];
  float dt = del_t[j];
  float bh = pbh[0], ah = pah[0], hw1 = ph1[0], hw2 = ph2[0];
  const float* ln = logit + n*16;
  float mxl = -1e30f;
#pragma unroll
  for (int k = 0; k < 16; k++) mxl = fmaxf(mxl, ln[k]);
  float sume = 0.f;
#pragma unroll
  for (int k = 0; k < 16; k++) sume += fexp(ln[k] - mxl);
  float sk = fexp(ln[e & 15] - mxl) * frcp(sume);
  const float* sp2 = scal + (size_t)j * 16;
  float hn2 = sp2[1], prn2 = sp2[2], cn2 = sp2[3], csn2 = sp2[4], pcc = sp2[5],
        pfss = sp2[6], pfsm = sp2[7], pfmm = sp2[8], athn = sp2[9], hn = sp2[10];
  float g = bh * fexp(-ah * dt);
  float decay = fexp(-hw2 * dt * (1.f/60.f));
  // h-side: h_scaled = a_h*hx ; h_max = b_h*relu(hx)
  float wxn1 = fsqrt(fmaxf(sk*sk*hn2, EPSR));
  float iwxn1 = frcp(wxn1);
  float t1 = ftanh(wxn1 * frcp(hn) * athn);
  float npre1 = t1 * sk * fsqrt(hn2) * iwxn1;
  float nn1 = fmaxf(npre1, SQEPS); float sg1 = (nn1 > MXN) ? MXN*frcp(nn1) : 1.f;
  float a_h = sg1 * t1 * sk * iwxn1;
  float rn2 = a_h*a_h*prn2;
  float xnd  = fsqrt(fmaxf(decay*decay, EPSR));
  float wxn2 = fsqrt(fmaxf(decay*decay*rn2, EPSR));
  float iwxn2 = frcp(wxn2);
  float t2 = ftanh(wxn2 * frcp(xnd) * at_c(xnd));
  float npre2 = t2 * decay * fsqrt(rn2) * iwxn2;
  float nn2 = fmaxf(npre2, SQEPS); float sg2 = (nn2 > MXN) ? MXN*frcp(nn2) : 1.f;
  float b_h = sg2 * t2 * decay * a_h * iwxn2;
  float bh1 = hw1 * b_h;
  float x2 = a_h*a_h*hn2;
  float y2 = bh1*bh1*prn2;
  float xy = a_h*bh1*prn2;            // hx dot relu(hx) = relu(hx)^2
  float A = 1.f + 2.f*xy + y2, B = 1.f - x2;
  float idn = frcp(fmaxf(1.f + 2.f*xy + x2*y2, EPSR));
  float nh2 = (A*A*x2 + 2.f*A*B*xy + B*B*y2) * idn * idn;
  float nh = fsqrt(fmaxf(nh2, EPSR)); float sg3 = (nh > MXN) ? MXN*frcp(nh) : 1.f;
  float p  = sg3 * A * a_h * idn;
  float rr = sg3 * B * bh1 * idn;
  float hhn2 = sg3*sg3*nh2;
  float lam = 2.f * frcp(fmaxf(1.f - hhn2, EPSR));
  // c-side
  float xng  = fsqrt(fmaxf(g*g, EPSR));
  float wxn3 = fsqrt(fmaxf(g*g*csn2, EPSR));
  float iwxn3 = frcp(wxn3);
  float t3 = ftanh(wxn3 * frcp(xng) * at_c(xng));
  float npre3 = t3 * g * fsqrt(csn2) * iwxn3;
  float nn3 = fmaxf(npre3, SQEPS); float sgc = (nn3 > MXN) ? MXN*frcp(nn3) : 1.f;
  float gam = sgc * t3 * g * iwxn3;
  float A1 = 1.f - 2.f*pcc + cn2, B1 = 1.f - csn2;
  float iden1 = frcp(fmaxf(1.f - 2.f*pcc + csn2*cn2, EPSR));
  float al = -A1*iden1, be = B1*iden1;
  float n1sq = al*al*csn2 + 2.f*al*be*pcc + be*be*cn2;
  float n1 = fsqrt(fmaxf(n1sq, EPSR)); float s1 = (n1 > MXN) ? MXN*frcp(n1) : 1.f;
  al *= s1; be *= s1;
  float z1n2 = s1*s1*n1sq;
  float y2c = gam*gam*csn2;
  float xyc = gam*(al*csn2 + be*pcc);
  float A2 = 1.f + 2.f*xyc + y2c, B2 = 1.f - z1n2;
  float iden2 = frcp(fmaxf(1.f + 2.f*xyc + z1n2*y2c, EPSR));
  float u1 = (A2*al + B2*gam)*iden2, u2 = A2*be*iden2;
  float n2sq = u1*u1*csn2 + 2.f*u1*u2*pcc + u2*u2*cn2;
  float n2 = fsqrt(fmaxf(n2sq, EPSR)); float s2 = (n2 > MXN) ? MXN*frcp(n2) : 1.f;
  u1 *= s2; u2 *= s2;
  float xnc = fminf(n2, MXN);
  float wx2 = u1*u1*pfss + 2.f*u1*u2*pfsm + u2*u2*pfmm;
  float wxn4 = fsqrt(fmaxf(wx2, EPSR));
  float iwxn4 = frcp(wxn4);
  float t4 = ftanh(wxn4 * frcp(xnc) * at_c(xnc));
  float npre4 = t4 * fsqrt(wx2) * iwxn4;
  float nn4 = fmaxf(npre4, SQEPS); float s4 = (nn4 > MXN) ? MXN*frcp(nn4) : 1.f;
  float v1 = s4*t4*u1*iwxn4, v2 = s4*t4*u2*iwxn4;
  float rsn2 = (s4*npre4)*(s4*npre4);
  float lam2 = 2.f * frcp(fmaxf(1.f - rsn2, EPSR));
  float* cf = coef + (size_t)e * 6;
  cf[0] = lam; cf[1] = lam*p; cf[2] = lam*rr;
  cf[3] = lam2; cf[4] = lam2*v1; cf[5] = lam2*v2;
}

// ---------------- K8c: accumulate + midpoint epilogue (wave per node) ----------------
__global__ void __launch_bounds__(256) k_acc(
    const int* __restrict__ edges, const float* __restrict__ h1,
    const u16* __restrict__ fcs, const u16* __restrict__ fcm,
    const float* __restrict__ coef,
    float* __restrict__ ht, u16* __restrict__ cred, float* __restrict__ htn_arr)
{
  int w = threadIdx.x >> 6, lane = threadIdx.x & 63;
  int n = blockIdx.x * 4 + w;
  float numh[4] = {0,0,0,0}, numc[4] = {0,0,0,0};
  float denh = 0.f, denc = 0.f;
  for (int k = 0; k < 16; k++){
    int e = n*16 + k;
    int j = edges[e];
    const float* cf = coef + (size_t)e * 6;
    float lam = cf[0], lamp = cf[1], lamr = cf[2];
    float lam2 = cf[3], lv1 = cf[4], lv2 = cf[5];
    denh += lam - 1.f; denc += lam2 - 1.f;
    float hx[4]; ld4f(h1 + (size_t)j*D + lane*4, hx);
    u16x4 fs4 = *(const u16x4*)(fcs + (size_t)j*D + lane*4);
    u16x4 fm4 = *(const u16x4*)(fcm + (size_t)j*D + lane*4);
#pragma unroll
    for (int r = 0; r < 4; r++){
      numh[r] += lamp*hx[r] + lamr*fmaxf(hx[r], 0.f);
      numc[r] += lv1*b2f(fs4[r]) + lv2*b2f(fm4[r]);
    }
  }
  if (fabsf(denh) < 1e-10f) denh = 1e-10f;
  if (fabsf(denc) < 1e-10f) denc = 1e-10f;
  float idh = frcp(denh), idc = frcp(denc);
  float vh[4], vc[4]; float vn2h = 0.f, vn2c = 0.f;
#pragma unroll
  for (int r = 0; r < 4; r++){
    vh[r] = numh[r]*idh; vn2h += vh[r]*vh[r];
    vc[r] = numc[r]*idc; vn2c += vc[r]*vc[r];
  }
  vn2h = wred(vn2h); vn2c = wred(vn2c);
  float vnh = fsqrt(fmaxf(vn2h, EPSR));
  float tth = ftanh(0.5f * at_c(vnh));
  float nph = tth * fsqrt(vn2h) * frcp(vnh);
  float nfh; float sh = sig_proj(nph, &nfh);
  float chh = sh * tth * frcp(vnh);
  f32x4 ho;
#pragma unroll
  for (int r = 0; r < 4; r++) ho[r] = chh * vh[r];
  *(f32x4*)(ht + n*D + lane*4) = ho;
  if (lane == 0) htn_arr[n] = nfh;
  float vnc = fsqrt(fmaxf(vn2c, EPSR));
  float ttc = ftanh(0.5f * at_c(vnc));
  float npc = ttc * fsqrt(vn2c) * frcp(vnc);
  float nfc; float scz = sig_proj(npc, &nfc);
  float chc = scz * ttc * frcp(vnc);
  u16x4 co;
#pragma unroll
  for (int r = 0; r < 4; r++) co[r] = f2b(chc * vc[r]);
  *(u16x4*)(cred + n*D + lane*4) = co;
}

// ---------------- K10: final iou chain + outputs ----------------
__global__ void __launch_bounds__(256) k_final(
    const u16* __restrict__ mqiou, const u16* __restrict__ mu,
    const u16* __restrict__ cred, const float* __restrict__ biou,
    const float* __restrict__ scal, const float* __restrict__ htn_arr,
    float* __restrict__ out)
{
  int w = threadIdx.x >> 6, lane = threadIdx.x & 63;
  int n = blockIdx.x * 4 + w;
  float mi[3][4], muv[3][4], bi[3][4];
#pragma unroll
  for (int p = 0; p < 3; p++){
    ld4(mqiou + (size_t)n*1024 + 256 + p*256 + lane*4, mi[p]);   // miou cols 256:1024
    ld4(mu   + (size_t)n*768 + p*256 + lane*4, muv[p]);
    ld4f(biou + p*256 + lane*4, bi[p]);
  }
  float cr[4]; ld4(cred + (size_t)n*D + lane*4, cr);
  float xbn = scal[(size_t)n*16 + 0];
  float htn = htn_arr[n];
  float mn2 = 0.f, un2 = 0.f, dmu = 0.f;
#pragma unroll
  for (int p = 0; p < 3; p++)
#pragma unroll
    for (int r = 0; r < 4; r++){
      mn2 += mi[p][r]*mi[p][r]; un2 += muv[p][r]*muv[p][r]; dmu += mi[p][r]*muv[p][r];
    }
  mn2 = wred(mn2); un2 = wred(un2); dmu = wred(dmu);
  float mnc = fsqrt(fmaxf(mn2, EPSR));
  float ta = ftanh(mnc * frcp(xbn) * at_c(xbn));
  float npa = ta * fsqrt(mn2) * frcp(mnc);
  float na_; float sa = sig_proj(npa, &na_);
  float ca = sa * ta * frcp(mnc); float x2 = (sa*npa)*(sa*npa);
  float unc = fsqrt(fmaxf(un2, EPSR));
  float tb = ftanh(unc * frcp(htn) * at_c(htn));
  float npb = tb * fsqrt(un2) * frcp(unc);
  float nb_; float sb = sig_proj(npb, &nb_);
  float cb = sb * tb * frcp(unc); float y2 = (sb*npb)*(sb*npb);
  float xy = ca * cb * dmu;
  float A = 1.f + 2.f*xy + y2, B = 1.f - x2;
  float idn = frcp(fmaxf(1.f + 2.f*xy + x2*y2, EPSR));
  float c_mi = A*ca*idn, c_mu = B*cb*idn;
  float n1sq = (A*A*x2 + 2.f*A*B*xy + B*B*y2) * idn * idn;
  float n1 = fsqrt(fmaxf(n1sq, EPSR)); float s1 = (n1 > MXN) ? MXN*frcp(n1) : 1.f;
  c_mi *= s1; c_mu *= s1;
  float iou1n2 = s1*s1*n1sq;
  float io1[3][4]; float bb2 = 0.f, xyb = 0.f;
#pragma unroll
  for (int p = 0; p < 3; p++)
#pragma unroll
    for (int r = 0; r < 4; r++){
      io1[p][r] = c_mi*mi[p][r] + c_mu*muv[p][r];
      bb2 += bi[p][r]*bi[p][r]; xyb += io1[p][r]*bi[p][r];
    }
  bb2 = wred(bb2); xyb = wred(xyb);
  float A2 = 1.f + 2.f*xyb + bb2, B2 = 1.f - iou1n2;
  float iden2 = frcp(fmaxf(1.f + 2.f*xyb + iou1n2*bb2, EPSR));
  float n2sq = (A2*A2*iou1n2 + 2.f*A2*B2*xyb + B2*B2*bb2) * iden2 * iden2;
  float n2c = fsqrt(fmaxf(n2sq, EPSR)); float s2 = (n2c > MXN) ? MXN*frcp(n2c) : 1.f;
  float cA2 = s2*A2*iden2, cB2 = s2*B2*iden2;
  float iou[3][4];
#pragma unroll
  for (int p = 0; p < 3; p++)
#pragma unroll
    for (int r = 0; r < 4; r++) iou[p][r] = cA2*io1[p][r] + cB2*bi[p][r];
  float ni2 = 0.f, no2 = 0.f, nu2 = 0.f;
#pragma unroll
  for (int r = 0; r < 4; r++){ ni2 += iou[0][r]*iou[0][r]; no2 += iou[1][r]*iou[1][r]; nu2 += iou[2][r]*iou[2][r]; }
  ni2 = wred(ni2); no2 = wred(no2); nu2 = wred(nu2);
  float niN = fsqrt(fmaxf(ni2, EPSR)), noN = fsqrt(fmaxf(no2, EPSR)), nuN = fsqrt(fmaxf(nu2, EPSR));
  float ci = at_c(niN)*frcp(niN), co = at_c(noN)*frcp(noN), cu = at_c(nuN)*frcp(nuN);
  float iv[4], ov[4], uv[4];
#pragma unroll
  for (int r = 0; r < 4; r++){
    iv[r] = fsig(ci*iou[0][r]);
    ov[r] = fsig(co*iou[1][r]);
    uv[r] = ftanh(cu*iou[2][r]);
  }
  float xn2 = 0.f, wn2 = 0.f; float wx[4];
#pragma unroll
  for (int r = 0; r < 4; r++){ xn2 += uv[r]*uv[r]; wx[r] = iv[r]*uv[r]; wn2 += wx[r]*wx[r]; }
  xn2 = wred(xn2); wn2 = wred(wn2);
  float xnc = fsqrt(fmaxf(xn2, EPSR)), wnc = fsqrt(fmaxf(wn2, EPSR));
  float t4 = ftanh(wnc * frcp(xnc) * at_c(xnc));
  float np4 = t4 * fsqrt(wn2) * frcp(wnc);
  float n4_; float s4 = sig_proj(np4, &n4_);
  float cpm = s4*t4*frcp(wnc); float pmn2 = (s4*np4)*(s4*np4);
  float y2c = 0.f, xyc = 0.f;
#pragma unroll
  for (int r = 0; r < 4; r++){ y2c += cr[r]*cr[r]; xyc += cpm*wx[r]*cr[r]; }
  y2c = wred(y2c); xyc = wred(xyc);
  float A3 = 1.f + 2.f*xyc + y2c, B3 = 1.f - pmn2;
  float iden3 = frcp(fmaxf(1.f + 2.f*xyc + pmn2*y2c, EPSR));
  float n3sq = (A3*A3*pmn2 + 2.f*A3*B3*xyc + B3*B3*y2c) * iden3 * iden3;
  float n3 = fsqrt(fmaxf(n3sq, EPSR)); float s3 = (n3 > MXN) ? MXN*frcp(n3) : 1.f;
  float cA3 = s3*A3*cpm*iden3, cB3 = s3*B3*iden3;
  float cnw[4]; f32x4 oc;
#pragma unroll
  for (int r = 0; r < 4; r++){ cnw[r] = cA3*wx[r] + cB3*cr[r]; oc[r] = cnw[r]; }
  *(f32x4*)(out + NB + (size_t)n*D + lane*4) = oc;
  float ncn = fminf(n3, MXN);
  float clg = at_c(ncn)*frcp(ncn);
  float th[4]; float xn5 = 0.f, wn5 = 0.f; float wx5[4];
#pragma unroll
  for (int r = 0; r < 4; r++){
    th[r] = ftanh(clg*cnw[r]);
    xn5 += th[r]*th[r]; wx5[r] = ov[r]*th[r]; wn5 += wx5[r]*wx5[r];
  }
  xn5 = wred(xn5); wn5 = wred(wn5);
  float xn5c = fsqrt(fmaxf(xn5, EPSR)), wn5c = fsqrt(fmaxf(wn5, EPSR));
  float t5 = ftanh(wn5c * frcp(xn5c) * at_c(xn5c));
  float np5 = t5 * fsqrt(wn5) * frcp(wn5c);
  float n5_; float s5 = sig_proj(np5, &n5_);
  float ch = s5*t5*frcp(wn5c);
  f32x4 oh;
#pragma unroll
  for (int r = 0; r < 4; r++) oh[r] = ch * wx5[r];
  *(f32x4*)(out + (size_t)n*D + lane*4) = oh;
}

extern "C" void kernel_launch(void* const* d_in, const int* in_sizes, int n_in,
                              void* d_out, int out_size, void* d_ws, size_t ws_size,
                              hipStream_t stream)
{
  (void)in_sizes; (void)n_in; (void)out_size; (void)ws_size;
  const float* x     = (const float*)d_in[0];
  const float* h1    = (const float*)d_in[1];
  const float* c1    = (const float*)d_in[2];
  const float* del_t = (const float*)d_in[3];
  const int*   edges = (const int*)d_in[4];
  const float* W_iou = (const float*)d_in[5];
  const float* U_iou = (const float*)d_in[6];
  const float* b_iou = (const float*)d_in[7];
  const float* U_f   = (const float*)d_in[8];
  const float* W_q   = (const float*)d_in[9];
  const float* b_q   = (const float*)d_in[10];
  const float* W_k   = (const float*)d_in[11];
  const float* b_k   = (const float*)d_in[12];
  const float* W_c   = (const float*)d_in[13];
  const float* b_c   = (const float*)d_in[14];
  const float* b_haw = (const float*)d_in[15];
  const float* a_haw = (const float*)d_in[16];
  const float* haw1  = (const float*)d_in[17];
  const float* haw2  = (const float*)d_in[18];

  // workspace (u16 units): xb(2NB, reused as ht) | mqiou(4NB) | mkf(2NB) |
  // mc(NB) | qv(NB, reused as cred) | kvec(NB, reused as coef 6.3MB) |
  // fcs(NB) | fcm(NB) | scal | logit | htn.  mu(3NB) = mkf..mc region.
  float* xb   = (float*)d_ws;                 // NB f32
  u16* mqiou  = (u16*)(xb + NB);              // 4*NB
  u16* mkf    = mqiou + 4*(size_t)NB;         // 2*NB
  u16* mc     = mkf + 2*(size_t)NB;           // NB
  u16* qv     = mc + NB;                      // NB
  u16* kvec   = qv + NB;                      // NB
  u16* fcs    = kvec + NB;                    // NB
  u16* fcm    = fcs + NB;                     // NB
  float* scal    = (float*)(fcm + NB);        // NN*16 f32
  float* logit   = scal + (size_t)NN*16;      // NN*16 f32
  float* htn_arr = logit + (size_t)NN*16;     // NN f32
  float* ht   = xb;
  u16* cred   = qv;
  float* coef = (float*)kvec;                 // NN*16*6 f32
  u16* mu     = mkf;

  k_prep<<<NN/4, 256, 0, stream>>>(x, h1, c1, xb, scal);
  gemm_bt<<<dim3(NN/128, 8), 256, 0, stream>>>(xb, W_q, W_iou, 256, mqiou, 256, 1024);
  gemm_bt<<<dim3(NN/128, 4), 256, 0, stream>>>(h1, W_k, U_f, 256, mkf, 256, 512);
  gemm_bt<<<dim3(NN/128, 2), 256, 0, stream>>>(c1, W_c, W_c, 256, mc, 256, 256);
  k_post<<<NN/4, 256, 0, stream>>>(mqiou, mkf, mc, c1, b_q, b_k, b_c, qv, kvec, fcs, fcm, scal);
  k_logit<<<NN/4, 256, 0, stream>>>(edges, del_t, qv, kvec, b_haw, a_haw, logit);
  k_coef<<<NN*16/256, 256, 0, stream>>>(edges, del_t, logit, scal, b_haw, a_haw, haw1, haw2, coef);
  k_acc<<<NN/4, 256, 0, stream>>>(edges, h1, fcs, fcm, coef, ht, cred, htn_arr);
  gemm_bt<<<dim3(NN/128, 6), 256, 0, stream>>>(ht, U_iou, U_iou, 768, mu, 256, 768);
  k_final<<<NN/4, 256, 0, stream>>>(mqiou, mu, cred, b_iou, scal, htn_arr, (float*)d_out);
}

// Round 6
// 338.278 us; speedup vs baseline: 2.5607x; 1.1736x over previous
//
#include <hip/hip_runtime.h>
#include <math.h>

#define NN 16384
#define D  256
#define NB (NN*D)
#define EPSR 1e-15f
#define SQEPS 3.1622776601683794e-8f
#define MXN 0.99999f   /* 1 - 1e-5 */

typedef unsigned short u16;
typedef __bf16 bf16x8 __attribute__((ext_vector_type(8)));
typedef float f32x4 __attribute__((ext_vector_type(4)));
typedef unsigned short u16x8 __attribute__((ext_vector_type(8)));
typedef unsigned short u16x4 __attribute__((ext_vector_type(4)));

// ---- fast hw transcendentals ----
__device__ __forceinline__ float fexp(float x){ return __builtin_amdgcn_exp2f(x * 1.4426950408889634f); }
__device__ __forceinline__ float flog(float x){ return __builtin_amdgcn_logf(x) * 0.6931471805599453f; }
__device__ __forceinline__ float frcp(float x){ return __builtin_amdgcn_rcpf(x); }
__device__ __forceinline__ float fsqrt(float x){ return __builtin_amdgcn_sqrtf(x); }
__device__ __forceinline__ float ftanh(float x){
  float xc = fminf(fmaxf(x, -15.f), 15.f);
  float t = fexp(2.f * xc);
  return (t - 1.f) * frcp(t + 1.f);
}
__device__ __forceinline__ float at_c(float x){          // _artanh with clip
  float xc = fminf(fmaxf(x, -1.f + 1e-5f), 1.f - 1e-5f);
  return 0.5f * flog((1.f + xc) * frcp(1.f - xc));
}
__device__ __forceinline__ float fsig(float x){ return frcp(1.f + fexp(-x)); }

__device__ __forceinline__ float b2f(u16 u){
  unsigned int x = ((unsigned int)u) << 16;
  return __builtin_bit_cast(float, x);
}
__device__ __forceinline__ u16 f2b(float f){
  unsigned int u = __builtin_bit_cast(unsigned int, f);
  return (u16)((u + 0x7fffu + ((u >> 16) & 1u)) >> 16);
}
__device__ __forceinline__ float wred(float v){          // 64-lane sum
#pragma unroll
  for (int m = 32; m; m >>= 1) v += __shfl_xor(v, m);
  return v;
}
__device__ __forceinline__ float sig_proj(float npre, float* nrm){
  float n = fmaxf(npre, SQEPS);
  float s = (n > MXN) ? (MXN * frcp(n)) : 1.f;
  *nrm = fminf(n, MXN);
  return s;
}
__device__ __forceinline__ void ld4(const u16* p, float v[4]){   // bf16 table load
  u16x4 t = *(const u16x4*)p;
#pragma unroll
  for (int r = 0; r < 4; r++) v[r] = b2f(t[r]);
}
__device__ __forceinline__ void ld4f(const float* p, float v[4]){ // f32 load
  f32x4 t = *(const f32x4*)p;
#pragma unroll
  for (int r = 0; r < 4; r++) v[r] = t[r];
}

// ---------------- K0: convert all weights to bf16 arena ----------------
// dst layout (elements): Wq[0,65536) Wiou[65536,262144) Wk[262144,327680)
// Uf[327680,393216) Wc[393216,458752) Uiou[458752,655360)
__global__ void __launch_bounds__(256) k_wcvt(
    const float* __restrict__ Wq, const float* __restrict__ Wiou,
    const float* __restrict__ Wk, const float* __restrict__ Uf,
    const float* __restrict__ Wc, const float* __restrict__ Uiou,
    u16* __restrict__ dst)
{
  size_t base = ((size_t)blockIdx.x * 256 + threadIdx.x) * 4;
  const float* src; size_t off;
  if      (base <  65536){ src = Wq;   off = base; }
  else if (base < 262144){ src = Wiou; off = base - 65536; }
  else if (base < 327680){ src = Wk;   off = base - 262144; }
  else if (base < 393216){ src = Uf;   off = base - 327680; }
  else if (base < 458752){ src = Wc;   off = base - 393216; }
  else                   { src = Uiou; off = base - 458752; }
  f32x4 v = *(const f32x4*)(src + off);
  u16x4 o;
#pragma unroll
  for (int r = 0; r < 4; r++) o[r] = f2b(v[r]);
  *(u16x4*)(dst + base) = o;
}

// ---------------- K1: per-node prep: xbb/cb/pack-hb (bf16), norms ----------------
__global__ void __launch_bounds__(256) k_prep(const float* __restrict__ x,
    const float* __restrict__ h1, const float* __restrict__ c1,
    u16* __restrict__ xbb, u16* __restrict__ cb, u16* __restrict__ pack,
    float* __restrict__ scal)
{
  int w = threadIdx.x >> 6, lane = threadIdx.x & 63;
  int n = blockIdx.x * 4 + w;
  int base = n * D + lane * 4;
  float xv[4], hv[4], cv[4];
  ld4f(x + base, xv); ld4f(h1 + base, hv); ld4f(c1 + base, cv);
  float un2 = 0, hn2 = 0, prn2 = 0, cn2 = 0;
#pragma unroll
  for (int r = 0; r < 4; r++){
    un2 += xv[r]*xv[r]; hn2 += hv[r]*hv[r];
    float rr = fmaxf(hv[r], 0.f); prn2 += rr*rr;
    cn2 += cv[r]*cv[r];
  }
  un2 = wred(un2); hn2 = wred(hn2); prn2 = wred(prn2); cn2 = wred(cn2);
  float un = fsqrt(fmaxf(un2, EPSR));
  float t  = ftanh(un);
  float sc = t * frcp(un);
  float nx = fsqrt(fmaxf(sc*sc*un2, EPSR));
  float s  = (nx > MXN) ? (MXN * frcp(nx)) : 1.f;
  u16x4 ox, oh, oc;
#pragma unroll
  for (int r = 0; r < 4; r++){ ox[r] = f2b(s*sc*xv[r]); oh[r] = f2b(hv[r]); oc[r] = f2b(cv[r]); }
  *(u16x4*)(xbb + base) = ox;
  *(u16x4*)(cb + base) = oc;
  *(u16x4*)(pack + (size_t)n*768 + lane*4) = oh;
  if (lane == 0){
    float* sp = scal + (size_t)n * 16;
    sp[0] = fminf(nx, MXN);
    sp[1] = hn2; sp[2] = prn2; sp[3] = cn2;
    float hn = fsqrt(fmaxf(hn2, EPSR));
    sp[9] = at_c(hn); sp[10] = hn;
  }
}

// -- MFMA GEMM: C[M,Nout](bf16) = A[M,K](bf16, row stride lda) @ B[Nout,K]^T (bf16) --
#define TM 128
#define TN 128
#define TK 32
#define LDP 40
__global__ void __launch_bounds__(256) gemm_bt(const u16* __restrict__ A, int lda,
    const u16* __restrict__ B, u16* __restrict__ C, int K, int Nout)
{
  __shared__ u16 As[TM*LDP];
  __shared__ u16 Bs[TN*LDP];
  int t = threadIdx.x;
  int m0 = blockIdx.x * TM, n0 = blockIdx.y * TN;
  int w = t >> 6, lane = t & 63;
  int wr = w >> 1, wc = w & 1;
  int q = lane >> 4, l16 = lane & 15;
  f32x4 acc[4][4];
#pragma unroll
  for (int i = 0; i < 4; i++)
#pragma unroll
    for (int j = 0; j < 4; j++) acc[i][j] = (f32x4){0.f,0.f,0.f,0.f};
  for (int k0 = 0; k0 < K; k0 += TK){
    __syncthreads();
#pragma unroll
    for (int c = t; c < 512; c += 256){
      int row = c >> 2, ko = (c & 3) * 8;
      *(u16x8*)(As + row*LDP + ko) = *(const u16x8*)(A + (size_t)(m0+row)*lda + k0 + ko);
      *(u16x8*)(Bs + row*LDP + ko) = *(const u16x8*)(B + (size_t)(n0+row)*K + k0 + ko);
    }
    __syncthreads();
    bf16x8 af[4], bfr[4];
#pragma unroll
    for (int rb = 0; rb < 4; rb++)
      af[rb] = *(const bf16x8*)(As + (wr*64 + rb*16 + l16)*LDP + q*8);
#pragma unroll
    for (int cb2 = 0; cb2 < 4; cb2++)
      bfr[cb2] = *(const bf16x8*)(Bs + (wc*64 + cb2*16 + l16)*LDP + q*8);
#pragma unroll
    for (int rb = 0; rb < 4; rb++)
#pragma unroll
      for (int cb2 = 0; cb2 < 4; cb2++)
        acc[rb][cb2] = __builtin_amdgcn_mfma_f32_16x16x32_bf16(af[rb], bfr[cb2], acc[rb][cb2], 0, 0, 0);
  }
#pragma unroll
  for (int rb = 0; rb < 4; rb++)
#pragma unroll
    for (int cb2 = 0; cb2 < 4; cb2++)
#pragma unroll
      for (int r = 0; r < 4; r++){
        int m  = m0 + wr*64 + rb*16 + q*4 + r;
        int nn = n0 + wc*64 + cb2*16 + l16;
        C[(size_t)m*Nout + nn] = f2b(acc[rb][cb2][r]);
      }
}

// z = mobius_add(mm_scale(m; xn), b) ; returns clipped norm of z
__device__ __forceinline__ float mm_madd(const float mv[4], const float bv[4], float xn, float z[4]){
  float mn2 = 0.f;
#pragma unroll
  for (int r = 0; r < 4; r++) mn2 += mv[r]*mv[r];
  mn2 = wred(mn2);
  float mnc = fsqrt(fmaxf(mn2, EPSR));
  float imnc = frcp(mnc);
  float t = ftanh(mnc * frcp(xn) * at_c(xn));
  float npre = t * fsqrt(mn2) * imnc;
  float nf; float sg = sig_proj(npre, &nf);
  float cx = sg * t * imnc;
  float x2 = (sg*npre)*(sg*npre);
  float y2 = 0.f, xy = 0.f;
#pragma unroll
  for (int r = 0; r < 4; r++){ y2 += bv[r]*bv[r]; xy += cx*mv[r]*bv[r]; }
  y2 = wred(y2); xy = wred(xy);
  float A = 1.f + 2.f*xy + y2, Bc = 1.f - x2;
  float idn = frcp(fmaxf(1.f + 2.f*xy + x2*y2, EPSR));
  float zn2 = (A*A*x2 + 2.f*A*Bc*xy + Bc*Bc*y2) * idn * idn;
  float zn = fsqrt(fmaxf(zn2, EPSR));
  float sz = (zn > MXN) ? (MXN * frcp(zn)) : 1.f;
  float ca = sz * A * idn * cx, cb = sz * Bc * idn;
#pragma unroll
  for (int r = 0; r < 4; r++) z[r] = ca*mv[r] + cb*bv[r];
  return fminf(zn, MXN);
}

// ---------------- K7: per-node post-GEMM: q, kvec, f, c_sk tables ----------------
__global__ void __launch_bounds__(256) k_post(
    const u16* __restrict__ mqiou, const u16* __restrict__ mkf,
    const u16* __restrict__ mc,
    const float* __restrict__ c1,
    const float* __restrict__ bq, const float* __restrict__ bk, const float* __restrict__ bc,
    u16* __restrict__ qv, u16* __restrict__ kv,
    u16* __restrict__ pack,
    float* __restrict__ scal)
{
  int w = threadIdx.x >> 6, lane = threadIdx.x & 63;
  int n = blockIdx.x * 4 + w;
  int base = n * D + lane * 4, lb = lane * 4;
  float* sp = scal + (size_t)n * 16;
  float xbn = sp[0], hn2 = sp[1], cn2 = sp[3];
  float hnc = fsqrt(fmaxf(hn2, EPSR));
  float cnc = fsqrt(fmaxf(cn2, EPSR));
  float mv[4], bv[4], z[4];
  u16x4 o;
  // q = logmap0(mobius_add(mm(W_q, x_ball), b_q))    [mqiou cols 0:256, stride 1024]
  ld4(mqiou + (size_t)n*1024 + lb, mv); ld4f(bq + lb, bv);
  float znf = mm_madd(mv, bv, xbn, z);
  float cl = at_c(znf) * frcp(znf);
#pragma unroll
  for (int r = 0; r < 4; r++) o[r] = f2b(cl * z[r]);
  *(u16x4*)(qv + base) = o;
  // kvec = logmap0(mobius_add(mm(W_k, h1), b_k))     [mkf cols 0:256, stride 512]
  ld4(mkf + (size_t)n*512 + lb, mv); ld4f(bk + lb, bv);
  znf = mm_madd(mv, bv, hnc, z);
  cl = at_c(znf) * frcp(znf);
#pragma unroll
  for (int r = 0; r < 4; r++) o[r] = f2b(cl * z[r]);
  *(u16x4*)(kv + base) = o;
  // f = sigmoid(logmap0(mm(U_f, h1)))                [mkf cols 256:512]
  float fv[4];
  {
    ld4(mkf + (size_t)n*512 + 256 + lb, mv);
    float mn2 = 0.f;
#pragma unroll
    for (int r = 0; r < 4; r++) mn2 += mv[r]*mv[r];
    mn2 = wred(mn2);
    float mnc = fsqrt(fmaxf(mn2, EPSR));
    float imnc = frcp(mnc);
    float t = ftanh(mnc * frcp(hnc) * at_c(hnc));
    float npre = t * fsqrt(mn2) * imnc;
    float nf; float sg = sig_proj(npre, &nf);
    float cx = sg * t * imnc;
    float lcf = at_c(nf) * frcp(nf);
#pragma unroll
    for (int r = 0; r < 4; r++) fv[r] = fsig(lcf * cx * mv[r]);
  }
  // c_sk = expmap0(tanh(logmap0(mobius_add(mm(W_c, c1), b_c))))
  float csk[4];
  {
    ld4(mc + base, mv); ld4f(bc + lb, bv);
    float zn = mm_madd(mv, bv, cnc, z);
    float lc = at_c(zn) * frcp(zn);
    float th[4]; float thn2 = 0.f;
#pragma unroll
    for (int r = 0; r < 4; r++){ th[r] = ftanh(lc * z[r]); thn2 += th[r]*th[r]; }
    thn2 = wred(thn2);
    float thn = fsqrt(fmaxf(thn2, EPSR));
    float te = ftanh(thn);
    float se = te * frcp(thn);
    float npe = fsqrt(fmaxf(se*se*thn2, EPSR));
    float sge = (npe > MXN) ? (MXN * frcp(npe)) : 1.f;
#pragma unroll
    for (int r = 0; r < 4; r++) csk[r] = sge * se * th[r];
  }
  float c1v[4]; ld4f(c1 + base, c1v);
  float csn2 = 0, pcc = 0, pfss = 0, pfsm = 0, pfmm = 0;
#pragma unroll
  for (int r = 0; r < 4; r++){
    float f2 = fv[r]*fv[r];
    csn2 += csk[r]*csk[r];
    pcc  += csk[r]*c1v[r];
    pfss += f2*csk[r]*csk[r];
    pfsm += f2*csk[r]*c1v[r];
    pfmm += f2*c1v[r]*c1v[r];
  }
  csn2 = wred(csn2); pcc = wred(pcc); pfss = wred(pfss); pfsm = wred(pfsm); pfmm = wred(pfmm);
  u16x4 oa, ob;
#pragma unroll
  for (int r = 0; r < 4; r++){ oa[r] = f2b(fv[r]*csk[r]); ob[r] = f2b(fv[r]*c1v[r]); }
  *(u16x4*)(pack + (size_t)n*768 + 256 + lb) = oa;   // fcs
  *(u16x4*)(pack + (size_t)n*768 + 512 + lb) = ob;   // fcm
  if (lane == 0){
    sp[4] = csn2; sp[5] = pcc; sp[6] = pfss; sp[7] = pfsm; sp[8] = pfmm;
  }
}

// ---------------- K8a: logits (wave per node) ----------------
__global__ void __launch_bounds__(256) k_logit(
    const int* __restrict__ edges, const float* __restrict__ del_t,
    const u16* __restrict__ qv, const u16* __restrict__ kvec,
    const float* __restrict__ pbh, const float* __restrict__ pah,
    float* __restrict__ logit)
{
  int w = threadIdx.x >> 6, lane = threadIdx.x & 63;
  int n = blockIdx.x * 4 + w;
  float bh = pbh[0], ah = pah[0];
  float qf[4]; ld4(qv + n*D + lane*4, qf);
  for (int k = 0; k < 16; k++){
    int j = edges[n*16 + k];
    float dt = del_t[j];
    u16x4 kt = *(const u16x4*)(kvec + (size_t)j*D + lane*4);
    float d = 0.f;
#pragma unroll
    for (int r = 0; r < 4; r++) d += qf[r] * b2f(kt[r]);
    d = wred(d);
    if (lane == 0) logit[n*16 + k] = d * 0.0625f + bh * fexp(-ah * dt);
  }
}

// ---------------- K8b: per-edge coefficient chain (thread per edge) ----------------
__global__ void __launch_bounds__(256) k_coef(
    const int* __restrict__ edges, const float* __restrict__ del_t,
    const float* __restrict__ logit, const float* __restrict__ scal,
    const float* __restrict__ pbh, const float* __restrict__ pah,
    const float* __restrict__ ph1, const float* __restrict__ ph2,
    float* __restrict__ coef)
{
  int e = blockIdx.x * 256 + threadIdx.x;     // e in [0, NN*16)
  int n = e >> 4;
  int j = edges[e];
  float dt = del_t[j];
  float bh = pbh[0], ah = pah[0], hw1 = ph1[0], hw2 = ph2[0];
  const float* ln = logit + n*16;
  float mxl = -1e30f;
#pragma unroll
  for (int k = 0; k < 16; k++) mxl = fmaxf(mxl, ln[k]);
  float sume = 0.f;
#pragma unroll
  for (int k = 0; k < 16; k++) sume += fexp(ln[k] - mxl);
  float sk = fexp(ln[e & 15] - mxl) * frcp(sume);
  const float* sp2 = scal + (size_t)j * 16;
  float hn2 = sp2[1], prn2 = sp2[2], cn2 = sp2[3], csn2 = sp2[4], pcc = sp2[5],
        pfss = sp2[6], pfsm = sp2[7], pfmm = sp2[8], athn = sp2[9], hn = sp2[10];
  float g = bh * fexp(-ah * dt);
  float decay = fexp(-hw2 * dt * (1.f/60.f));
  // h-side
  float wxn1 = fsqrt(fmaxf(sk*sk*hn2, EPSR));
  float iwxn1 = frcp(wxn1);
  float t1 = ftanh(wxn1 * frcp(hn) * athn);
  float npre1 = t1 * sk * fsqrt(hn2) * iwxn1;
  float nn1 = fmaxf(npre1, SQEPS); float sg1 = (nn1 > MXN) ? MXN*frcp(nn1) : 1.f;
  float a_h = sg1 * t1 * sk * iwxn1;
  float rn2 = a_h*a_h*prn2;
  float xnd  = fsqrt(fmaxf(decay*decay, EPSR));
  float wxn2 = fsqrt(fmaxf(decay*decay*rn2, EPSR));
  float iwxn2 = frcp(wxn2);
  float t2 = ftanh(wxn2 * frcp(xnd) * at_c(xnd));
  float npre2 = t2 * decay * fsqrt(rn2) * iwxn2;
  float nn2 = fmaxf(npre2, SQEPS); float sg2 = (nn2 > MXN) ? MXN*frcp(nn2) : 1.f;
  float b_h = sg2 * t2 * decay * a_h * iwxn2;
  float bh1 = hw1 * b_h;
  float x2 = a_h*a_h*hn2;
  float y2 = bh1*bh1*prn2;
  float xy = a_h*bh1*prn2;            // hx dot relu(hx) = relu(hx)^2
  float A = 1.f + 2.f*xy + y2, B = 1.f - x2;
  float idn = frcp(fmaxf(1.f + 2.f*xy + x2*y2, EPSR));
  float nh2 = (A*A*x2 + 2.f*A*B*xy + B*B*y2) * idn * idn;
  float nh = fsqrt(fmaxf(nh2, EPSR)); float sg3 = (nh > MXN) ? MXN*frcp(nh) : 1.f;
  float p  = sg3 * A * a_h * idn;
  float rr = sg3 * B * bh1 * idn;
  float hhn2 = sg3*sg3*nh2;
  float lam = 2.f * frcp(fmaxf(1.f - hhn2, EPSR));
  // c-side
  float xng  = fsqrt(fmaxf(g*g, EPSR));
  float wxn3 = fsqrt(fmaxf(g*g*csn2, EPSR));
  float iwxn3 = frcp(wxn3);
  float t3 = ftanh(wxn3 * frcp(xng) * at_c(xng));
  float npre3 = t3 * g * fsqrt(csn2) * iwxn3;
  float nn3 = fmaxf(npre3, SQEPS); float sgc = (nn3 > MXN) ? MXN*frcp(nn3) : 1.f;
  float gam = sgc * t3 * g * iwxn3;
  float A1 = 1.f - 2.f*pcc + cn2, B1 = 1.f - csn2;
  float iden1 = frcp(fmaxf(1.f - 2.f*pcc + csn2*cn2, EPSR));
  float al = -A1*iden1, be = B1*iden1;
  float n1sq = al*al*csn2 + 2.f*al*be*pcc + be*be*cn2;
  float n1 = fsqrt(fmaxf(n1sq, EPSR)); float s1 = (n1 > MXN) ? MXN*frcp(n1) : 1.f;
  al *= s1; be *= s1;
  float z1n2 = s1*s1*n1sq;
  float y2c = gam*gam*csn2;
  float xyc = gam*(al*csn2 + be*pcc);
  float A2 = 1.f + 2.f*xyc + y2c, B2 = 1.f - z1n2;
  float iden2 = frcp(fmaxf(1.f + 2.f*xyc + z1n2*y2c, EPSR));
  float u1 = (A2*al + B2*gam)*iden2, u2 = A2*be*iden2;
  float n2sq = u1*u1*csn2 + 2.f*u1*u2*pcc + u2*u2*cn2;
  float n2 = fsqrt(fmaxf(n2sq, EPSR)); float s2 = (n2 > MXN) ? MXN*frcp(n2) : 1.f;
  u1 *= s2; u2 *= s2;
  float xnc = fminf(n2, MXN);
  float wx2 = u1*u1*pfss + 2.f*u1*u2*pfsm + u2*u2*pfmm;
  float wxn4 = fsqrt(fmaxf(wx2, EPSR));
  float iwxn4 = frcp(wxn4);
  float t4 = ftanh(wxn4 * frcp(xnc) * at_c(xnc));
  float npre4 = t4 * fsqrt(wx2) * iwxn4;
  float nn4 = fmaxf(npre4, SQEPS); float s4 = (nn4 > MXN) ? MXN*frcp(nn4) : 1.f;
  float v1 = s4*t4*u1*iwxn4, v2 = s4*t4*u2*iwxn4;
  float rsn2 = (s4*npre4)*(s4*npre4);
  float lam2 = 2.f * frcp(fmaxf(1.f - rsn2, EPSR));
  float* cf = coef + (size_t)e * 6;
  cf[0] = lam; cf[1] = lam*p; cf[2] = lam*rr;
  cf[3] = lam2; cf[4] = lam2*v1; cf[5] = lam2*v2;
}

// ---------------- K8c: accumulate (packed bf16 gather) + midpoint ----------------
__global__ void __launch_bounds__(256) k_acc(
    const int* __restrict__ edges, const u16* __restrict__ pack,
    const float* __restrict__ coef,
    u16* __restrict__ ht, u16* __restrict__ cred, float* __restrict__ htn_arr)
{
  int w = threadIdx.x >> 6, lane = threadIdx.x & 63;
  int n = blockIdx.x * 4 + w;
  float numh[4] = {0,0,0,0}, numc[4] = {0,0,0,0};
  float denh = 0.f, denc = 0.f;
#pragma unroll 4
  for (int k = 0; k < 16; k++){
    int e = n*16 + k;
    int j = edges[e];
    const float* cf = coef + (size_t)e * 6;
    float lam = cf[0], lamp = cf[1], lamr = cf[2];
    float lam2 = cf[3], lv1 = cf[4], lv2 = cf[5];
    denh += lam - 1.f; denc += lam2 - 1.f;
    const u16* pr = pack + (size_t)j*768 + lane*4;
    u16x4 hx4 = *(const u16x4*)(pr);
    u16x4 fs4 = *(const u16x4*)(pr + 256);
    u16x4 fm4 = *(const u16x4*)(pr + 512);
#pragma unroll
    for (int r = 0; r < 4; r++){
      float hxr = b2f(hx4[r]);
      numh[r] += lamp*hxr + lamr*fmaxf(hxr, 0.f);
      numc[r] += lv1*b2f(fs4[r]) + lv2*b2f(fm4[r]);
    }
  }
  if (fabsf(denh) < 1e-10f) denh = 1e-10f;
  if (fabsf(denc) < 1e-10f) denc = 1e-10f;
  float idh = frcp(denh), idc = frcp(denc);
  float vh[4], vc[4]; float vn2h = 0.f, vn2c = 0.f;
#pragma unroll
  for (int r = 0; r < 4; r++){
    vh[r] = numh[r]*idh; vn2h += vh[r]*vh[r];
    vc[r] = numc[r]*idc; vn2c += vc[r]*vc[r];
  }
  vn2h = wred(vn2h); vn2c = wred(vn2c);
  float vnh = fsqrt(fmaxf(vn2h, EPSR));
  float tth = ftanh(0.5f * at_c(vnh));
  float nph = tth * fsqrt(vn2h) * frcp(vnh);
  float nfh; float sh = sig_proj(nph, &nfh);
  float chh = sh * tth * frcp(vnh);
  u16x4 ho;
#pragma unroll
  for (int r = 0; r < 4; r++) ho[r] = f2b(chh * vh[r]);
  *(u16x4*)(ht + (size_t)n*D + lane*4) = ho;
  if (lane == 0) htn_arr[n] = nfh;
  float vnc = fsqrt(fmaxf(vn2c, EPSR));
  float ttc = ftanh(0.5f * at_c(vnc));
  float npc = ttc * fsqrt(vn2c) * frcp(vnc);
  float nfc; float scz = sig_proj(npc, &nfc);
  float chc = scz * ttc * frcp(vnc);
  u16x4 co;
#pragma unroll
  for (int r = 0; r < 4; r++) co[r] = f2b(chc * vc[r]);
  *(u16x4*)(cred + (size_t)n*D + lane*4) = co;
}

// ---------------- K10: final iou chain + outputs ----------------
__global__ void __launch_bounds__(256) k_final(
    const u16* __restrict__ mqiou, const u16* __restrict__ mu,
    const u16* __restrict__ cred, const float* __restrict__ biou,
    const float* __restrict__ scal, const float* __restrict__ htn_arr,
    float* __restrict__ out)
{
  int w = threadIdx.x >> 6, lane = threadIdx.x & 63;
  int n = blockIdx.x * 4 + w;
  float mi[3][4], muv[3][4], bi[3][4];
#pragma unroll
  for (int p = 0; p < 3; p++){
    ld4(mqiou + (size_t)n*1024 + 256 + p*256 + lane*4, mi[p]);   // miou cols 256:1024
    ld4(mu   + (size_t)n*768 + p*256 + lane*4, muv[p]);
    ld4f(biou + p*256 + lane*4, bi[p]);
  }
  float cr[4]; ld4(cred + (size_t)n*D + lane*4, cr);
  float xbn = scal[(size_t)n*16 + 0];
  float htn = htn_arr[n];
  float mn2 = 0.f, un2 = 0.f, dmu = 0.f;
#pragma unroll
  for (int p = 0; p < 3; p++)
#pragma unroll
    for (int r = 0; r < 4; r++){
      mn2 += mi[p][r]*mi[p][r]; un2 += muv[p][r]*muv[p][r]; dmu += mi[p][r]*muv[p][r];
    }
  mn2 = wred(mn2); un2 = wred(un2); dmu = wred(dmu);
  float mnc = fsqrt(fmaxf(mn2, EPSR));
  float ta = ftanh(mnc * frcp(xbn) * at_c(xbn));
  float npa = ta * fsqrt(mn2) * frcp(mnc);
  float na_; float sa = sig_proj(npa, &na_);
  float ca = sa * ta * frcp(mnc); float x2 = (sa*npa)*(sa*npa);
  float unc = fsqrt(fmaxf(un2, EPSR));
  float tb = ftanh(unc * frcp(htn) * at_c(htn));
  float npb = tb * fsqrt(un2) * frcp(unc);
  float nb_; float sb = sig_proj(npb, &nb_);
  float cb = sb * tb * frcp(unc); float y2 = (sb*npb)*(sb*npb);
  float xy = ca * cb * dmu;
  float A = 1.f + 2.f*xy + y2, B = 1.f - x2;
  float idn = frcp(fmaxf(1.f + 2.f*xy + x2*y2, EPSR));
  float c_mi = A*ca*idn, c_mu = B*cb*idn;
  float n1sq = (A*A*x2 + 2.f*A*B*xy + B*B*y2) * idn * idn;
  float n1 = fsqrt(fmaxf(n1sq, EPSR)); float s1 = (n1 > MXN) ? MXN*frcp(n1) : 1.f;
  c_mi *= s1; c_mu *= s1;
  float iou1n2 = s1*s1*n1sq;
  float io1[3][4]; float bb2 = 0.f, xyb = 0.f;
#pragma unroll
  for (int p = 0; p < 3; p++)
#pragma unroll
    for (int r = 0; r < 4; r++){
      io1[p][r] = c_mi*mi[p][r] + c_mu*muv[p][r];
      bb2 += bi[p][r]*bi[p][r]; xyb += io1[p][r]*bi[p][r];
    }
  bb2 = wred(bb2); xyb = wred(xyb);
  float A2 = 1.f + 2.f*xyb + bb2, B2 = 1.f - iou1n2;
  float iden2 = frcp(fmaxf(1.f + 2.f*xyb + iou1n2*bb2, EPSR));
  float n2sq = (A2*A2*iou1n2 + 2.f*A2*B2*xyb + B2*B2*bb2) * iden2 * iden2;
  float n2c = fsqrt(fmaxf(n2sq, EPSR)); float s2 = (n2c > MXN) ? MXN*frcp(n2c) : 1.f;
  float cA2 = s2*A2*iden2, cB2 = s2*B2*iden2;
  float iou[3][4];
#pragma unroll
  for (int p = 0; p < 3; p++)
#pragma unroll
    for (int r = 0; r < 4; r++) iou[p][r] = cA2*io1[p][r] + cB2*bi[p][r];
  float ni2 = 0.f, no2 = 0.f, nu2 = 0.f;
#pragma unroll
  for (int r = 0; r < 4; r++){ ni2 += iou[0][r]*iou[0][r]; no2 += iou[1][r]*iou[1][r]; nu2 += iou[2][r]*iou[2][r]; }
  ni2 = wred(ni2); no2 = wred(no2); nu2 = wred(nu2);
  float niN = fsqrt(fmaxf(ni2, EPSR)), noN = fsqrt(fmaxf(no2, EPSR)), nuN = fsqrt(fmaxf(nu2, EPSR));
  float ci = at_c(niN)*frcp(niN), co = at_c(noN)*frcp(noN), cu = at_c(nuN)*frcp(nuN);
  float iv[4], ov[4], uv[4];
#pragma unroll
  for (int r = 0; r < 4; r++){
    iv[r] = fsig(ci*iou[0][r]);
    ov[r] = fsig(co*iou[1][r]);
    uv[r] = ftanh(cu*iou[2][r]);
  }
  float xn2 = 0.f, wn2 = 0.f; float wx[4];
#pragma unroll
  for (int r = 0; r < 4; r++){ xn2 += uv[r]*uv[r]; wx[r] = iv[r]*uv[r]; wn2 += wx[r]*wx[r]; }
  xn2 = wred(xn2); wn2 = wred(wn2);
  float xnc = fsqrt(fmaxf(xn2, EPSR)), wnc = fsqrt(fmaxf(wn2, EPSR));
  float t4 = ftanh(wnc * frcp(xnc) * at_c(xnc));
  float np4 = t4 * fsqrt(wn2) * frcp(wnc);
  float n4_; float s4 = sig_proj(np4, &n4_);
  float cpm = s4*t4*frcp(wnc); float pmn2 = (s4*np4)*(s4*np4);
  float y2c = 0.f, xyc = 0.f;
#pragma unroll
  for (int r = 0; r < 4; r++){ y2c += cr[r]*cr[r]; xyc += cpm*wx[r]*cr[r]; }
  y2c = wred(y2c); xyc = wred(xyc);
  float A3 = 1.f + 2.f*xyc + y2c, B3 = 1.f - pmn2;
  float iden3 = frcp(fmaxf(1.f + 2.f*xyc + pmn2*y2c, EPSR));
  float n3sq = (A3*A3*pmn2 + 2.f*A3*B3*xyc + B3*B3*y2c) * iden3 * iden3;
  float n3 = fsqrt(fmaxf(n3sq, EPSR)); float s3 = (n3 > MXN) ? MXN*frcp(n3) : 1.f;
  float cA3 = s3*A3*cpm*iden3, cB3 = s3*B3*iden3;
  float cnw[4]; f32x4 oc;
#pragma unroll
  for (int r = 0; r < 4; r++){ cnw[r] = cA3*wx[r] + cB3*cr[r]; oc[r] = cnw[r]; }
  *(f32x4*)(out + NB + (size_t)n*D + lane*4) = oc;
  float ncn = fminf(n3, MXN);
  float clg = at_c(ncn)*frcp(ncn);
  float th[4]; float xn5 = 0.f, wn5 = 0.f; float wx5[4];
#pragma unroll
  for (int r = 0; r < 4; r++){
    th[r] = ftanh(clg*cnw[r]);
    xn5 += th[r]*th[r]; wx5[r] = ov[r]*th[r]; wn5 += wx5[r]*wx5[r];
  }
  xn5 = wred(xn5); wn5 = wred(wn5);
  float xn5c = fsqrt(fmaxf(xn5, EPSR)), wn5c = fsqrt(fmaxf(wn5, EPSR));
  float t5 = ftanh(wn5c * frcp(xn5c) * at_c(xn5c));
  float np5 = t5 * fsqrt(wn5) * frcp(wn5c);
  float n5_; float s5 = sig_proj(np5, &n5_);
  float ch = s5*t5*frcp(wn5c);
  f32x4 oh;
#pragma unroll
  for (int r = 0; r < 4; r++) oh[r] = ch * wx5[r];
  *(f32x4*)(out + (size_t)n*D + lane*4) = oh;
}

extern "C" void kernel_launch(void* const* d_in, const int* in_sizes, int n_in,
                              void* d_out, int out_size, void* d_ws, size_t ws_size,
                              hipStream_t stream)
{
  (void)in_sizes; (void)n_in; (void)out_size; (void)ws_size;
  const float* x     = (const float*)d_in[0];
  const float* h1    = (const float*)d_in[1];
  const float* c1    = (const float*)d_in[2];
  const float* del_t = (const float*)d_in[3];
  const int*   edges = (const int*)d_in[4];
  const float* W_iou = (const float*)d_in[5];
  const float* U_iou = (const float*)d_in[6];
  const float* b_iou = (const float*)d_in[7];
  const float* U_f   = (const float*)d_in[8];
  const float* W_q   = (const float*)d_in[9];
  const float* b_q   = (const float*)d_in[10];
  const float* W_k   = (const float*)d_in[11];
  const float* b_k   = (const float*)d_in[12];
  const float* W_c   = (const float*)d_in[13];
  const float* b_c   = (const float*)d_in[14];
  const float* b_haw = (const float*)d_in[15];
  const float* a_haw = (const float*)d_in[16];
  const float* haw1  = (const float*)d_in[17];
  const float* haw2  = (const float*)d_in[18];

  // workspace (u16 units):
  // wb(655360) | xbb(NB, reused as ht) | cb(NB) | pack(NN*768) | mqiou(4NB) |
  // mkf(2NB) | mc(NB)  [mu(3NB)=mkf..mc] | qv(NB, reused as cred) |
  // kvec(NB, reused as coef) | scal | logit | htn
  u16* wb    = (u16*)d_ws;                   // 655360
  u16* xbb   = wb + 655360;                  // NB
  u16* cb    = xbb + NB;                     // NB
  u16* pack  = cb + NB;                      // NN*768
  u16* mqiou = pack + (size_t)NN*768;        // 4*NB
  u16* mkf   = mqiou + 4*(size_t)NB;         // 2*NB
  u16* mc    = mkf + 2*(size_t)NB;           // NB
  u16* qv    = mc + NB;                      // NB
  u16* kvec  = qv + NB;                      // NB
  float* scal    = (float*)(kvec + NB);      // NN*16 f32
  float* logit   = scal + (size_t)NN*16;     // NN*16 f32
  float* htn_arr = logit + (size_t)NN*16;    // NN f32
  u16* ht   = xbb;
  u16* cred = qv;
  float* coef = (float*)kvec;                // NN*16*6 f32
  u16* mu   = mkf;

  k_wcvt<<<640, 256, 0, stream>>>(W_q, W_iou, W_k, U_f, W_c, U_iou, wb);
  k_prep<<<NN/4, 256, 0, stream>>>(x, h1, c1, xbb, cb, pack, scal);
  gemm_bt<<<dim3(NN/128, 8), 256, 0, stream>>>(xbb, 256, wb,          mqiou, 256, 1024);
  gemm_bt<<<dim3(NN/128, 4), 256, 0, stream>>>(pack, 768, wb+262144,  mkf,   256, 512);
  gemm_bt<<<dim3(NN/128, 2), 256, 0, stream>>>(cb,  256, wb+393216,   mc,    256, 256);
  k_post<<<NN/4, 256, 0, stream>>>(mqiou, mkf, mc, c1, b_q, b_k, b_c, qv, kvec, pack, scal);
  k_logit<<<NN/4, 256, 0, stream>>>(edges, del_t, qv, kvec, b_haw, a_haw, logit);
  k_coef<<<NN*16/256, 256, 0, stream>>>(edges, del_t, logit, scal, b_haw, a_haw, haw1, haw2, coef);
  k_acc<<<NN/4, 256, 0, stream>>>(edges, pack, coef, ht, cred, htn_arr);
  gemm_bt<<<dim3(NN/128, 6), 256, 0, stream>>>(ht, 256, wb+458752, mu, 256, 768);
  k_final<<<NN/4, 256, 0, stream>>>(mqiou, mu, cred, b_iou, scal, htn_arr, (float*)d_out);
}

// Round 7
// 334.609 us; speedup vs baseline: 2.5888x; 1.0110x over previous
//
#include <hip/hip_runtime.h>
#include <math.h>

#define NN 16384
#define D  256
#define NB (NN*D)
#define EPSR 1e-15f
#define SQEPS 3.1622776601683794e-8f
#define MXN 0.99999f   /* 1 - 1e-5 */

typedef unsigned short u16;
typedef __bf16 bf16x8 __attribute__((ext_vector_type(8)));
typedef float f32x4 __attribute__((ext_vector_type(4)));
typedef unsigned short u16x8 __attribute__((ext_vector_type(8)));
typedef unsigned short u16x4 __attribute__((ext_vector_type(4)));

// ---- fast hw transcendentals ----
__device__ __forceinline__ float fexp(float x){ return __builtin_amdgcn_exp2f(x * 1.4426950408889634f); }
__device__ __forceinline__ float flog(float x){ return __builtin_amdgcn_logf(x) * 0.6931471805599453f; }
__device__ __forceinline__ float frcp(float x){ return __builtin_amdgcn_rcpf(x); }
__device__ __forceinline__ float fsqrt(float x){ return __builtin_amdgcn_sqrtf(x); }
__device__ __forceinline__ float ftanh(float x){
  float xc = fminf(fmaxf(x, -15.f), 15.f);
  float t = fexp(2.f * xc);
  return (t - 1.f) * frcp(t + 1.f);
}
__device__ __forceinline__ float at_c(float x){          // _artanh with clip
  float xc = fminf(fmaxf(x, -1.f + 1e-5f), 1.f - 1e-5f);
  return 0.5f * flog((1.f + xc) * frcp(1.f - xc));
}
__device__ __forceinline__ float fsig(float x){ return frcp(1.f + fexp(-x)); }

__device__ __forceinline__ float b2f(u16 u){
  unsigned int x = ((unsigned int)u) << 16;
  return __builtin_bit_cast(float, x);
}
__device__ __forceinline__ u16 f2b(float f){
  unsigned int u = __builtin_bit_cast(unsigned int, f);
  return (u16)((u + 0x7fffu + ((u >> 16) & 1u)) >> 16);
}
__device__ __forceinline__ float wred(float v){          // 64-lane sum
#pragma unroll
  for (int m = 32; m; m >>= 1) v += __shfl_xor(v, m);
  return v;
}
__device__ __forceinline__ float sig_proj(float npre, float* nrm){
  float n = fmaxf(npre, SQEPS);
  float s = (n > MXN) ? (MXN * frcp(n)) : 1.f;
  *nrm = fminf(n, MXN);
  return s;
}
__device__ __forceinline__ void ld4(const u16* p, float v[4]){   // bf16 table load
  u16x4 t = *(const u16x4*)p;
#pragma unroll
  for (int r = 0; r < 4; r++) v[r] = b2f(t[r]);
}
__device__ __forceinline__ void ld4f(const float* p, float v[4]){ // f32 load
  f32x4 t = *(const f32x4*)p;
#pragma unroll
  for (int r = 0; r < 4; r++) v[r] = t[r];
}

// ---------------- K0: convert all weights to bf16 arena ----------------
// dst layout (elements): Wq[0,65536) Wiou[65536,262144) Wk[262144,327680)
// Uf[327680,393216) Wc[393216,458752) Uiou[458752,655360)
__global__ void __launch_bounds__(256) k_wcvt(
    const float* __restrict__ Wq, const float* __restrict__ Wiou,
    const float* __restrict__ Wk, const float* __restrict__ Uf,
    const float* __restrict__ Wc, const float* __restrict__ Uiou,
    u16* __restrict__ dst)
{
  size_t base = ((size_t)blockIdx.x * 256 + threadIdx.x) * 4;
  const float* src; size_t off;
  if      (base <  65536){ src = Wq;   off = base; }
  else if (base < 262144){ src = Wiou; off = base - 65536; }
  else if (base < 327680){ src = Wk;   off = base - 262144; }
  else if (base < 393216){ src = Uf;   off = base - 327680; }
  else if (base < 458752){ src = Wc;   off = base - 393216; }
  else                   { src = Uiou; off = base - 458752; }
  f32x4 v = *(const f32x4*)(src + off);
  u16x4 o;
#pragma unroll
  for (int r = 0; r < 4; r++) o[r] = f2b(v[r]);
  *(u16x4*)(dst + base) = o;
}

// ---------------- K1: per-node prep: xbb/cb/pack-hb (bf16), norms ----------------
__global__ void __launch_bounds__(256) k_prep(const float* __restrict__ x,
    const float* __restrict__ h1, const float* __restrict__ c1,
    u16* __restrict__ xbb, u16* __restrict__ cb, u16* __restrict__ pack,
    float* __restrict__ scal)
{
  int w = threadIdx.x >> 6, lane = threadIdx.x & 63;
  int n = blockIdx.x * 4 + w;
  int base = n * D + lane * 4;
  float xv[4], hv[4], cv[4];
  ld4f(x + base, xv); ld4f(h1 + base, hv); ld4f(c1 + base, cv);
  float un2 = 0, hn2 = 0, prn2 = 0, cn2 = 0;
#pragma unroll
  for (int r = 0; r < 4; r++){
    un2 += xv[r]*xv[r]; hn2 += hv[r]*hv[r];
    float rr = fmaxf(hv[r], 0.f); prn2 += rr*rr;
    cn2 += cv[r]*cv[r];
  }
  un2 = wred(un2); hn2 = wred(hn2); prn2 = wred(prn2); cn2 = wred(cn2);
  float un = fsqrt(fmaxf(un2, EPSR));
  float t  = ftanh(un);
  float sc = t * frcp(un);
  float nx = fsqrt(fmaxf(sc*sc*un2, EPSR));
  float s  = (nx > MXN) ? (MXN * frcp(nx)) : 1.f;
  u16x4 ox, oh, oc;
#pragma unroll
  for (int r = 0; r < 4; r++){ ox[r] = f2b(s*sc*xv[r]); oh[r] = f2b(hv[r]); oc[r] = f2b(cv[r]); }
  *(u16x4*)(xbb + base) = ox;
  *(u16x4*)(cb + base) = oc;
  *(u16x4*)(pack + (size_t)n*768 + lane*4) = oh;
  if (lane == 0){
    float* sp = scal + (size_t)n * 16;
    sp[0] = fminf(nx, MXN);
    sp[1] = hn2; sp[2] = prn2; sp[3] = cn2;
    float hn = fsqrt(fmaxf(hn2, EPSR));
    sp[9] = at_c(hn); sp[10] = hn;
  }
}

// -- MFMA GEMM: C[M,Nout](bf16) = A[M,K](bf16, row stride lda) @ B[Nout,K]^T (bf16) --
#define TM 128
#define TN 128
#define TK 32
#define LDP 40
__global__ void __launch_bounds__(256) gemm_bt(const u16* __restrict__ A, int lda,
    const u16* __restrict__ B, u16* __restrict__ C, int K, int Nout)
{
  __shared__ u16 As[TM*LDP];
  __shared__ u16 Bs[TN*LDP];
  int t = threadIdx.x;
  int m0 = blockIdx.x * TM, n0 = blockIdx.y * TN;
  int w = t >> 6, lane = t & 63;
  int wr = w >> 1, wc = w & 1;
  int q = lane >> 4, l16 = lane & 15;
  f32x4 acc[4][4];
#pragma unroll
  for (int i = 0; i < 4; i++)
#pragma unroll
    for (int j = 0; j < 4; j++) acc[i][j] = (f32x4){0.f,0.f,0.f,0.f};
  for (int k0 = 0; k0 < K; k0 += TK){
    __syncthreads();
#pragma unroll
    for (int c = t; c < 512; c += 256){
      int row = c >> 2, ko = (c & 3) * 8;
      *(u16x8*)(As + row*LDP + ko) = *(const u16x8*)(A + (size_t)(m0+row)*lda + k0 + ko);
      *(u16x8*)(Bs + row*LDP + ko) = *(const u16x8*)(B + (size_t)(n0+row)*K + k0 + ko);
    }
    __syncthreads();
    bf16x8 af[4], bfr[4];
#pragma unroll
    for (int rb = 0; rb < 4; rb++)
      af[rb] = *(const bf16x8*)(As + (wr*64 + rb*16 + l16)*LDP + q*8);
#pragma unroll
    for (int cb2 = 0; cb2 < 4; cb2++)
      bfr[cb2] = *(const bf16x8*)(Bs + (wc*64 + cb2*16 + l16)*LDP + q*8);
#pragma unroll
    for (int rb = 0; rb < 4; rb++)
#pragma unroll
      for (int cb2 = 0; cb2 < 4; cb2++)
        acc[rb][cb2] = __builtin_amdgcn_mfma_f32_16x16x32_bf16(af[rb], bfr[cb2], acc[rb][cb2], 0, 0, 0);
  }
#pragma unroll
  for (int rb = 0; rb < 4; rb++)
#pragma unroll
    for (int cb2 = 0; cb2 < 4; cb2++)
#pragma unroll
      for (int r = 0; r < 4; r++){
        int m  = m0 + wr*64 + rb*16 + q*4 + r;
        int nn = n0 + wc*64 + cb2*16 + l16;
        C[(size_t)m*Nout + nn] = f2b(acc[rb][cb2][r]);
      }
}

// z = mobius_add(mm_scale(m; xn), b) ; returns clipped norm of z
__device__ __forceinline__ float mm_madd(const float mv[4], const float bv[4], float xn, float z[4]){
  float mn2 = 0.f;
#pragma unroll
  for (int r = 0; r < 4; r++) mn2 += mv[r]*mv[r];
  mn2 = wred(mn2);
  float mnc = fsqrt(fmaxf(mn2, EPSR));
  float imnc = frcp(mnc);
  float t = ftanh(mnc * frcp(xn) * at_c(xn));
  float npre = t * fsqrt(mn2) * imnc;
  float nf; float sg = sig_proj(npre, &nf);
  float cx = sg * t * imnc;
  float x2 = (sg*npre)*(sg*npre);
  float y2 = 0.f, xy = 0.f;
#pragma unroll
  for (int r = 0; r < 4; r++){ y2 += bv[r]*bv[r]; xy += cx*mv[r]*bv[r]; }
  y2 = wred(y2); xy = wred(xy);
  float A = 1.f + 2.f*xy + y2, Bc = 1.f - x2;
  float idn = frcp(fmaxf(1.f + 2.f*xy + x2*y2, EPSR));
  float zn2 = (A*A*x2 + 2.f*A*Bc*xy + Bc*Bc*y2) * idn * idn;
  float zn = fsqrt(fmaxf(zn2, EPSR));
  float sz = (zn > MXN) ? (MXN * frcp(zn)) : 1.f;
  float ca = sz * A * idn * cx, cb = sz * Bc * idn;
#pragma unroll
  for (int r = 0; r < 4; r++) z[r] = ca*mv[r] + cb*bv[r];
  return fminf(zn, MXN);
}

// ---------------- K7: per-node post-GEMM: q, kvec, f, c_sk tables ----------------
__global__ void __launch_bounds__(256) k_post(
    const u16* __restrict__ mqiou, const u16* __restrict__ mkf,
    const u16* __restrict__ mc,
    const float* __restrict__ c1,
    const float* __restrict__ bq, const float* __restrict__ bk, const float* __restrict__ bc,
    u16* __restrict__ qv, u16* __restrict__ kv,
    u16* __restrict__ pack,
    float* __restrict__ scal)
{
  int w = threadIdx.x >> 6, lane = threadIdx.x & 63;
  int n = blockIdx.x * 4 + w;
  int base = n * D + lane * 4, lb = lane * 4;
  float* sp = scal + (size_t)n * 16;
  float xbn = sp[0], hn2 = sp[1], cn2 = sp[3];
  float hnc = fsqrt(fmaxf(hn2, EPSR));
  float cnc = fsqrt(fmaxf(cn2, EPSR));
  float mv[4], bv[4], z[4];
  u16x4 o;
  // q = logmap0(mobius_add(mm(W_q, x_ball), b_q))    [mqiou cols 0:256, stride 1024]
  ld4(mqiou + (size_t)n*1024 + lb, mv); ld4f(bq + lb, bv);
  float znf = mm_madd(mv, bv, xbn, z);
  float cl = at_c(znf) * frcp(znf);
#pragma unroll
  for (int r = 0; r < 4; r++) o[r] = f2b(cl * z[r]);
  *(u16x4*)(qv + base) = o;
  // kvec = logmap0(mobius_add(mm(W_k, h1), b_k))     [mkf cols 0:256, stride 512]
  ld4(mkf + (size_t)n*512 + lb, mv); ld4f(bk + lb, bv);
  znf = mm_madd(mv, bv, hnc, z);
  cl = at_c(znf) * frcp(znf);
#pragma unroll
  for (int r = 0; r < 4; r++) o[r] = f2b(cl * z[r]);
  *(u16x4*)(kv + base) = o;
  // f = sigmoid(logmap0(mm(U_f, h1)))                [mkf cols 256:512]
  float fv[4];
  {
    ld4(mkf + (size_t)n*512 + 256 + lb, mv);
    float mn2 = 0.f;
#pragma unroll
    for (int r = 0; r < 4; r++) mn2 += mv[r]*mv[r];
    mn2 = wred(mn2);
    float mnc = fsqrt(fmaxf(mn2, EPSR));
    float imnc = frcp(mnc);
    float t = ftanh(mnc * frcp(hnc) * at_c(hnc));
    float npre = t * fsqrt(mn2) * imnc;
    float nf; float sg = sig_proj(npre, &nf);
    float cx = sg * t * imnc;
    float lcf = at_c(nf) * frcp(nf);
#pragma unroll
    for (int r = 0; r < 4; r++) fv[r] = fsig(lcf * cx * mv[r]);
  }
  // c_sk = expmap0(tanh(logmap0(mobius_add(mm(W_c, c1), b_c))))
  float csk[4];
  {
    ld4(mc + base, mv); ld4f(bc + lb, bv);
    float zn = mm_madd(mv, bv, cnc, z);
    float lc = at_c(zn) * frcp(zn);
    float th[4]; float thn2 = 0.f;
#pragma unroll
    for (int r = 0; r < 4; r++){ th[r] = ftanh(lc * z[r]); thn2 += th[r]*th[r]; }
    thn2 = wred(thn2);
    float thn = fsqrt(fmaxf(thn2, EPSR));
    float te = ftanh(thn);
    float se = te * frcp(thn);
    float npe = fsqrt(fmaxf(se*se*thn2, EPSR));
    float sge = (npe > MXN) ? (MXN * frcp(npe)) : 1.f;
#pragma unroll
    for (int r = 0; r < 4; r++) csk[r] = sge * se * th[r];
  }
  float c1v[4]; ld4f(c1 + base, c1v);
  float csn2 = 0, pcc = 0, pfss = 0, pfsm = 0, pfmm = 0;
#pragma unroll
  for (int r = 0; r < 4; r++){
    float f2 = fv[r]*fv[r];
    csn2 += csk[r]*csk[r];
    pcc  += csk[r]*c1v[r];
    pfss += f2*csk[r]*csk[r];
    pfsm += f2*csk[r]*c1v[r];
    pfmm += f2*c1v[r]*c1v[r];
  }
  csn2 = wred(csn2); pcc = wred(pcc); pfss = wred(pfss); pfsm = wred(pfsm); pfmm = wred(pfmm);
  u16x4 oa, ob;
#pragma unroll
  for (int r = 0; r < 4; r++){ oa[r] = f2b(fv[r]*csk[r]); ob[r] = f2b(fv[r]*c1v[r]); }
  *(u16x4*)(pack + (size_t)n*768 + 256 + lb) = oa;   // fcs
  *(u16x4*)(pack + (size_t)n*768 + 512 + lb) = ob;   // fcm
  if (lane == 0){
    sp[4] = csn2; sp[5] = pcc; sp[6] = pfss; sp[7] = pfsm; sp[8] = pfmm;
  }
}

// ------- K8ab fused: logits (wave/node) + coef chains (lane-parallel) -------
__global__ void __launch_bounds__(256) k_lgc(
    const int* __restrict__ edges, const float* __restrict__ del_t,
    const u16* __restrict__ qv, const u16* __restrict__ kvec,
    const float* __restrict__ scal,
    const float* __restrict__ pbh, const float* __restrict__ pah,
    const float* __restrict__ ph1, const float* __restrict__ ph2,
    float* __restrict__ coef)
{
  __shared__ int   s_j[4][16];
  __shared__ float s_dt[4][16];
  __shared__ float s_lg[4][16];
  int w = threadIdx.x >> 6, lane = threadIdx.x & 63;
  int n = blockIdx.x * 4 + w;
  float bh = pbh[0], ah = pah[0], hw1 = ph1[0], hw2 = ph2[0];
  float qf[4]; ld4(qv + n*D + lane*4, qf);
#pragma unroll
  for (int k = 0; k < 16; k++){
    int j = edges[n*16 + k];
    float dt = del_t[j];
    u16x4 kt = *(const u16x4*)(kvec + (size_t)j*D + lane*4);
    float d = 0.f;
#pragma unroll
    for (int r = 0; r < 4; r++) d += qf[r] * b2f(kt[r]);
    d = wred(d);
    if (lane == 0){ s_j[w][k] = j; s_dt[w][k] = dt; s_lg[w][k] = d * 0.0625f + bh * fexp(-ah * dt); }
  }
  __syncthreads();
  if (lane >= 16) return;
  int e = n*16 + lane;
  int j = s_j[w][lane];
  float dt = s_dt[w][lane];
  const float* ln = s_lg[w];
  float mxl = -1e30f;
#pragma unroll
  for (int k = 0; k < 16; k++) mxl = fmaxf(mxl, ln[k]);
  float sume = 0.f;
#pragma unroll
  for (int k = 0; k < 16; k++) sume += fexp(ln[k] - mxl);
  float sk = fexp(ln[lane] - mxl) * frcp(sume);
  const float* sp2 = scal + (size_t)j * 16;
  float hn2 = sp2[1], prn2 = sp2[2], cn2 = sp2[3], csn2 = sp2[4], pcc = sp2[5],
        pfss = sp2[6], pfsm = sp2[7], pfmm = sp2[8], athn = sp2[9], hn = sp2[10];
  float g = bh * fexp(-ah * dt);
  float decay = fexp(-hw2 * dt * (1.f/60.f));
  // h-side
  float wxn1 = fsqrt(fmaxf(sk*sk*hn2, EPSR));
  float iwxn1 = frcp(wxn1);
  float t1 = ftanh(wxn1 * frcp(hn) * athn);
  float npre1 = t1 * sk * fsqrt(hn2) * iwxn1;
  float nn1 = fmaxf(npre1, SQEPS); float sg1 = (nn1 > MXN) ? MXN*frcp(nn1) : 1.f;
  float a_h = sg1 * t1 * sk * iwxn1;
  float rn2 = a_h*a_h*prn2;
  float xnd  = fsqrt(fmaxf(decay*decay, EPSR));
  float wxn2 = fsqrt(fmaxf(decay*decay*rn2, EPSR));
  float iwxn2 = frcp(wxn2);
  float t2 = ftanh(wxn2 * frcp(xnd) * at_c(xnd));
  float npre2 = t2 * decay * fsqrt(rn2) * iwxn2;
  float nn2 = fmaxf(npre2, SQEPS); float sg2 = (nn2 > MXN) ? MXN*frcp(nn2) : 1.f;
  float b_h = sg2 * t2 * decay * a_h * iwxn2;
  float bh1 = hw1 * b_h;
  float x2 = a_h*a_h*hn2;
  float y2 = bh1*bh1*prn2;
  float xy = a_h*bh1*prn2;            // hx dot relu(hx) = relu(hx)^2
  float A = 1.f + 2.f*xy + y2, B = 1.f - x2;
  float idn = frcp(fmaxf(1.f + 2.f*xy + x2*y2, EPSR));
  float nh2 = (A*A*x2 + 2.f*A*B*xy + B*B*y2) * idn * idn;
  float nh = fsqrt(fmaxf(nh2, EPSR)); float sg3 = (nh > MXN) ? MXN*frcp(nh) : 1.f;
  float p  = sg3 * A * a_h * idn;
  float rr = sg3 * B * bh1 * idn;
  float hhn2 = sg3*sg3*nh2;
  float lam = 2.f * frcp(fmaxf(1.f - hhn2, EPSR));
  // c-side
  float xng  = fsqrt(fmaxf(g*g, EPSR));
  float wxn3 = fsqrt(fmaxf(g*g*csn2, EPSR));
  float iwxn3 = frcp(wxn3);
  float t3 = ftanh(wxn3 * frcp(xng) * at_c(xng));
  float npre3 = t3 * g * fsqrt(csn2) * iwxn3;
  float nn3 = fmaxf(npre3, SQEPS); float sgc = (nn3 > MXN) ? MXN*frcp(nn3) : 1.f;
  float gam = sgc * t3 * g * iwxn3;
  float A1 = 1.f - 2.f*pcc + cn2, B1 = 1.f - csn2;
  float iden1 = frcp(fmaxf(1.f - 2.f*pcc + csn2*cn2, EPSR));
  float al = -A1*iden1, be = B1*iden1;
  float n1sq = al*al*csn2 + 2.f*al*be*pcc + be*be*cn2;
  float n1 = fsqrt(fmaxf(n1sq, EPSR)); float s1 = (n1 > MXN) ? MXN*frcp(n1) : 1.f;
  al *= s1; be *= s1;
  float z1n2 = s1*s1*n1sq;
  float y2c = gam*gam*csn2;
  float xyc = gam*(al*csn2 + be*pcc);
  float A2 = 1.f + 2.f*xyc + y2c, B2 = 1.f - z1n2;
  float iden2 = frcp(fmaxf(1.f + 2.f*xyc + z1n2*y2c, EPSR));
  float u1 = (A2*al + B2*gam)*iden2, u2 = A2*be*iden2;
  float n2sq = u1*u1*csn2 + 2.f*u1*u2*pcc + u2*u2*cn2;
  float n2 = fsqrt(fmaxf(n2sq, EPSR)); float s2 = (n2 > MXN) ? MXN*frcp(n2) : 1.f;
  u1 *= s2; u2 *= s2;
  float xnc = fminf(n2, MXN);
  float wx2 = u1*u1*pfss + 2.f*u1*u2*pfsm + u2*u2*pfmm;
  float wxn4 = fsqrt(fmaxf(wx2, EPSR));
  float iwxn4 = frcp(wxn4);
  float t4 = ftanh(wxn4 * frcp(xnc) * at_c(xnc));
  float npre4 = t4 * fsqrt(wx2) * iwxn4;
  float nn4 = fmaxf(npre4, SQEPS); float s4 = (nn4 > MXN) ? MXN*frcp(nn4) : 1.f;
  float v1 = s4*t4*u1*iwxn4, v2 = s4*t4*u2*iwxn4;
  float rsn2 = (s4*npre4)*(s4*npre4);
  float lam2 = 2.f * frcp(fmaxf(1.f - rsn2, EPSR));
  float* cf = coef + (size_t)e * 6;
  cf[0] = lam; cf[1] = lam*p; cf[2] = lam*rr;
  cf[3] = lam2; cf[4] = lam2*v1; cf[5] = lam2*v2;
}

// ------- K8c: accumulate, 2 waves/node (8 edges each) + LDS combine -------
__global__ void __launch_bounds__(256) k_acc(
    const int* __restrict__ edges, const u16* __restrict__ pack,
    const float* __restrict__ coef,
    u16* __restrict__ ht, u16* __restrict__ cred, float* __restrict__ htn_arr)
{
  __shared__ f32x4 s_nh[2][64];
  __shared__ f32x4 s_nc[2][64];
  __shared__ float s_d[2][2];
  int w = threadIdx.x >> 6, lane = threadIdx.x & 63;
  int nb = w >> 1, half = w & 1;
  int n = blockIdx.x * 2 + nb;
  float numh[4] = {0,0,0,0}, numc[4] = {0,0,0,0};
  float denh = 0.f, denc = 0.f;
#pragma unroll
  for (int kk = 0; kk < 8; kk++){
    int k = half*8 + kk;
    int e = n*16 + k;
    int j = edges[e];
    const float* cf = coef + (size_t)e * 6;
    float lam = cf[0], lamp = cf[1], lamr = cf[2];
    float lam2 = cf[3], lv1 = cf[4], lv2 = cf[5];
    denh += lam - 1.f; denc += lam2 - 1.f;
    const u16* pr = pack + (size_t)j*768 + lane*4;
    u16x4 hx4 = *(const u16x4*)(pr);
    u16x4 fs4 = *(const u16x4*)(pr + 256);
    u16x4 fm4 = *(const u16x4*)(pr + 512);
#pragma unroll
    for (int r = 0; r < 4; r++){
      float hxr = b2f(hx4[r]);
      numh[r] += lamp*hxr + lamr*fmaxf(hxr, 0.f);
      numc[r] += lv1*b2f(fs4[r]) + lv2*b2f(fm4[r]);
    }
  }
  if (half == 1){
    f32x4 a, b;
#pragma unroll
    for (int r = 0; r < 4; r++){ a[r] = numh[r]; b[r] = numc[r]; }
    s_nh[nb][lane] = a; s_nc[nb][lane] = b;
    if (lane == 0){ s_d[nb][0] = denh; s_d[nb][1] = denc; }
  }
  __syncthreads();
  if (half == 1) return;
  {
    f32x4 a = s_nh[nb][lane], b = s_nc[nb][lane];
#pragma unroll
    for (int r = 0; r < 4; r++){ numh[r] += a[r]; numc[r] += b[r]; }
    denh += s_d[nb][0]; denc += s_d[nb][1];
  }
  if (fabsf(denh) < 1e-10f) denh = 1e-10f;
  if (fabsf(denc) < 1e-10f) denc = 1e-10f;
  float idh = frcp(denh), idc = frcp(denc);
  float vh[4], vc[4]; float vn2h = 0.f, vn2c = 0.f;
#pragma unroll
  for (int r = 0; r < 4; r++){
    vh[r] = numh[r]*idh; vn2h += vh[r]*vh[r];
    vc[r] = numc[r]*idc; vn2c += vc[r]*vc[r];
  }
  vn2h = wred(vn2h); vn2c = wred(vn2c);
  float vnh = fsqrt(fmaxf(vn2h, EPSR));
  float tth = ftanh(0.5f * at_c(vnh));
  float nph = tth * fsqrt(vn2h) * frcp(vnh);
  float nfh; float sh = sig_proj(nph, &nfh);
  float chh = sh * tth * frcp(vnh);
  u16x4 ho;
#pragma unroll
  for (int r = 0; r < 4; r++) ho[r] = f2b(chh * vh[r]);
  *(u16x4*)(ht + (size_t)n*D + lane*4) = ho;
  if (lane == 0) htn_arr[n] = nfh;
  float vnc = fsqrt(fmaxf(vn2c, EPSR));
  float ttc = ftanh(0.5f * at_c(vnc));
  float npc = ttc * fsqrt(vn2c) * frcp(vnc);
  float nfc; float scz = sig_proj(npc, &nfc);
  float chc = scz * ttc * frcp(vnc);
  u16x4 co;
#pragma unroll
  for (int r = 0; r < 4; r++) co[r] = f2b(chc * vc[r]);
  *(u16x4*)(cred + (size_t)n*D + lane*4) = co;
}

// ---------------- K10: final iou chain + outputs ----------------
__global__ void __launch_bounds__(256) k_final(
    const u16* __restrict__ mqiou, const u16* __restrict__ mu,
    const u16* __restrict__ cred, const float* __restrict__ biou,
    const float* __restrict__ scal, const float* __restrict__ htn_arr,
    float* __restrict__ out)
{
  int w = threadIdx.x >> 6, lane = threadIdx.x & 63;
  int n = blockIdx.x * 4 + w;
  float mi[3][4], muv[3][4], bi[3][4];
#pragma unroll
  for (int p = 0; p < 3; p++){
    ld4(mqiou + (size_t)n*1024 + 256 + p*256 + lane*4, mi[p]);   // miou cols 256:1024
    ld4(mu   + (size_t)n*768 + p*256 + lane*4, muv[p]);
    ld4f(biou + p*256 + lane*4, bi[p]);
  }
  float cr[4]; ld4(cred + (size_t)n*D + lane*4, cr);
  float xbn = scal[(size_t)n*16 + 0];
  float htn = htn_arr[n];
  float mn2 = 0.f, un2 = 0.f, dmu = 0.f;
#pragma unroll
  for (int p = 0; p < 3; p++)
#pragma unroll
    for (int r = 0; r < 4; r++){
      mn2 += mi[p][r]*mi[p][r]; un2 += muv[p][r]*muv[p][r]; dmu += mi[p][r]*muv[p][r];
    }
  mn2 = wred(mn2); un2 = wred(un2); dmu = wred(dmu);
  float mnc = fsqrt(fmaxf(mn2, EPSR));
  float ta = ftanh(mnc * frcp(xbn) * at_c(xbn));
  float npa = ta * fsqrt(mn2) * frcp(mnc);
  float na_; float sa = sig_proj(npa, &na_);
  float ca = sa * ta * frcp(mnc); float x2 = (sa*npa)*(sa*npa);
  float unc = fsqrt(fmaxf(un2, EPSR));
  float tb = ftanh(unc * frcp(htn) * at_c(htn));
  float npb = tb * fsqrt(un2) * frcp(unc);
  float nb_; float sb = sig_proj(npb, &nb_);
  float cb = sb * tb * frcp(unc); float y2 = (sb*npb)*(sb*npb);
  float xy = ca * cb * dmu;
  float A = 1.f + 2.f*xy + y2, B = 1.f - x2;
  float idn = frcp(fmaxf(1.f + 2.f*xy + x2*y2, EPSR));
  float c_mi = A*ca*idn, c_mu = B*cb*idn;
  float n1sq = (A*A*x2 + 2.f*A*B*xy + B*B*y2) * idn * idn;
  float n1 = fsqrt(fmaxf(n1sq, EPSR)); float s1 = (n1 > MXN) ? MXN*frcp(n1) : 1.f;
  c_mi *= s1; c_mu *= s1;
  float iou1n2 = s1*s1*n1sq;
  float io1[3][4]; float bb2 = 0.f, xyb = 0.f;
#pragma unroll
  for (int p = 0; p < 3; p++)
#pragma unroll
    for (int r = 0; r < 4; r++){
      io1[p][r] = c_mi*mi[p][r] + c_mu*muv[p][r];
      bb2 += bi[p][r]*bi[p][r]; xyb += io1[p][r]*bi[p][r];
    }
  bb2 = wred(bb2); xyb = wred(xyb);
  float A2 = 1.f + 2.f*xyb + bb2, B2 = 1.f - iou1n2;
  float iden2 = frcp(fmaxf(1.f + 2.f*xyb + iou1n2*bb2, EPSR));
  float n2sq = (A2*A2*iou1n2 + 2.f*A2*B2*xyb + B2*B2*bb2) * iden2 * iden2;
  float n2c = fsqrt(fmaxf(n2sq, EPSR)); float s2 = (n2c > MXN) ? MXN*frcp(n2c) : 1.f;
  float cA2 = s2*A2*iden2, cB2 = s2*B2*iden2;
  float iou[3][4];
#pragma unroll
  for (int p = 0; p < 3; p++)
#pragma unroll
    for (int r = 0; r < 4; r++) iou[p][r] = cA2*io1[p][r] + cB2*bi[p][r];
  float ni2 = 0.f, no2 = 0.f, nu2 = 0.f;
#pragma unroll
  for (int r = 0; r < 4; r++){ ni2 += iou[0][r]*iou[0][r]; no2 += iou[1][r]*iou[1][r]; nu2 += iou[2][r]*iou[2][r]; }
  ni2 = wred(ni2); no2 = wred(no2); nu2 = wred(nu2);
  float niN = fsqrt(fmaxf(ni2, EPSR)), noN = fsqrt(fmaxf(no2, EPSR)), nuN = fsqrt(fmaxf(nu2, EPSR));
  float ci = at_c(niN)*frcp(niN), co = at_c(noN)*frcp(noN), cu = at_c(nuN)*frcp(nuN);
  float iv[4], ov[4], uv[4];
#pragma unroll
  for (int r = 0; r < 4; r++){
    iv[r] = fsig(ci*iou[0][r]);
    ov[r] = fsig(co*iou[1][r]);
    uv[r] = ftanh(cu*iou[2][r]);
  }
  float xn2 = 0.f, wn2 = 0.f; float wx[4];
#pragma unroll
  for (int r = 0; r < 4; r++){ xn2 += uv[r]*uv[r]; wx[r] = iv[r]*uv[r]; wn2 += wx[r]*wx[r]; }
  xn2 = wred(xn2); wn2 = wred(wn2);
  float xnc = fsqrt(fmaxf(xn2, EPSR)), wnc = fsqrt(fmaxf(wn2, EPSR));
  float t4 = ftanh(wnc * frcp(xnc) * at_c(xnc));
  float np4 = t4 * fsqrt(wn2) * frcp(wnc);
  float n4_; float s4 = sig_proj(np4, &n4_);
  float cpm = s4*t4*frcp(wnc); float pmn2 = (s4*np4)*(s4*np4);
  float y2c = 0.f, xyc = 0.f;
#pragma unroll
  for (int r = 0; r < 4; r++){ y2c += cr[r]*cr[r]; xyc += cpm*wx[r]*cr[r]; }
  y2c = wred(y2c); xyc = wred(xyc);
  float A3 = 1.f + 2.f*xyc + y2c, B3 = 1.f - pmn2;
  float iden3 = frcp(fmaxf(1.f + 2.f*xyc + pmn2*y2c, EPSR));
  float n3sq = (A3*A3*pmn2 + 2.f*A3*B3*xyc + B3*B3*y2c) * iden3 * iden3;
  float n3 = fsqrt(fmaxf(n3sq, EPSR)); float s3 = (n3 > MXN) ? MXN*frcp(n3) : 1.f;
  float cA3 = s3*A3*cpm*iden3, cB3 = s3*B3*iden3;
  float cnw[4]; f32x4 oc;
#pragma unroll
  for (int r = 0; r < 4; r++){ cnw[r] = cA3*wx[r] + cB3*cr[r]; oc[r] = cnw[r]; }
  *(f32x4*)(out + NB + (size_t)n*D + lane*4) = oc;
  float ncn = fminf(n3, MXN);
  float clg = at_c(ncn)*frcp(ncn);
  float th[4]; float xn5 = 0.f, wn5 = 0.f; float wx5[4];
#pragma unroll
  for (int r = 0; r < 4; r++){
    th[r] = ftanh(clg*cnw[r]);
    xn5 += th[r]*th[r]; wx5[r] = ov[r]*th[r]; wn5 += wx5[r]*wx5[r];
  }
  xn5 = wred(xn5); wn5 = wred(wn5);
  float xn5c = fsqrt(fmaxf(xn5, EPSR)), wn5c = fsqrt(fmaxf(wn5, EPSR));
  float t5 = ftanh(wn5c * frcp(xn5c) * at_c(xn5c));
  float np5 = t5 * fsqrt(wn5) * frcp(wn5c);
  float n5_; float s5 = sig_proj(np5, &n5_);
  float ch = s5*t5*frcp(wn5c);
  f32x4 oh;
#pragma unroll
  for (int r = 0; r < 4; r++) oh[r] = ch * wx5[r];
  *(f32x4*)(out + (size_t)n*D + lane*4) = oh;
}

extern "C" void kernel_launch(void* const* d_in, const int* in_sizes, int n_in,
                              void* d_out, int out_size, void* d_ws, size_t ws_size,
                              hipStream_t stream)
{
  (void)in_sizes; (void)n_in; (void)out_size; (void)ws_size;
  const float* x     = (const float*)d_in[0];
  const float* h1    = (const float*)d_in[1];
  const float* c1    = (const float*)d_in[2];
  const float* del_t = (const float*)d_in[3];
  const int*   edges = (const int*)d_in[4];
  const float* W_iou = (const float*)d_in[5];
  const float* U_iou = (const float*)d_in[6];
  const float* b_iou = (const float*)d_in[7];
  const float* U_f   = (const float*)d_in[8];
  const float* W_q   = (const float*)d_in[9];
  const float* b_q   = (const float*)d_in[10];
  const float* W_k   = (const float*)d_in[11];
  const float* b_k   = (const float*)d_in[12];
  const float* W_c   = (const float*)d_in[13];
  const float* b_c   = (const float*)d_in[14];
  const float* b_haw = (const float*)d_in[15];
  const float* a_haw = (const float*)d_in[16];
  const float* haw1  = (const float*)d_in[17];
  const float* haw2  = (const float*)d_in[18];

  // workspace (u16 units):
  // wb(655360) | xbb(NB, reused as ht) | cb(NB) | pack(NN*768) | mqiou(4NB) |
  // mkf(2NB) | mc(NB)  [mu(3NB)=mkf..mc] | qv(NB, reused as cred) |
  // kvec(NB, reused as coef) | scal | htn
  u16* wb    = (u16*)d_ws;                   // 655360
  u16* xbb   = wb + 655360;                  // NB
  u16* cb    = xbb + NB;                     // NB
  u16* pack  = cb + NB;                      // NN*768
  u16* mqiou = pack + (size_t)NN*768;        // 4*NB
  u16* mkf   = mqiou + 4*(size_t)NB;         // 2*NB
  u16* mc    = mkf + 2*(size_t)NB;           // NB
  u16* qv    = mc + NB;                      // NB
  u16* kvec  = qv + NB;                      // NB
  float* scal    = (float*)(kvec + NB);      // NN*16 f32
  float* coefbuf = scal + (size_t)NN*16;     // NN*16*6 f32
  float* htn_arr = coefbuf + (size_t)NN*96;  // NN f32
  u16* ht   = xbb;
  u16* cred = qv;
  u16* mu   = mkf;

  k_wcvt<<<640, 256, 0, stream>>>(W_q, W_iou, W_k, U_f, W_c, U_iou, wb);
  k_prep<<<NN/4, 256, 0, stream>>>(x, h1, c1, xbb, cb, pack, scal);
  gemm_bt<<<dim3(NN/128, 8), 256, 0, stream>>>(xbb, 256, wb,          mqiou, 256, 1024);
  gemm_bt<<<dim3(NN/128, 4), 256, 0, stream>>>(pack, 768, wb+262144,  mkf,   256, 512);
  gemm_bt<<<dim3(NN/128, 2), 256, 0, stream>>>(cb,  256, wb+393216,   mc,    256, 256);
  k_post<<<NN/4, 256, 0, stream>>>(mqiou, mkf, mc, c1, b_q, b_k, b_c, qv, kvec, pack, scal);
  k_lgc<<<NN/4, 256, 0, stream>>>(edges, del_t, qv, kvec, scal, b_haw, a_haw, haw1, haw2, coefbuf);
  k_acc<<<NN/2, 256, 0, stream>>>(edges, pack, coefbuf, ht, cred, htn_arr);
  gemm_bt<<<dim3(NN/128, 6), 256, 0, stream>>>(ht, 256, wb+458752, mu, 256, 768);
  k_final<<<NN/4, 256, 0, stream>>>(mqiou, mu, cred, b_iou, scal, htn_arr, (float*)d_out);
}

// Round 8
// 314.963 us; speedup vs baseline: 2.7503x; 1.0624x over previous
//
#include <hip/hip_runtime.h>
#include <math.h>

#define NN 16384
#define D  256
#define NB (NN*D)
#define EPSR 1e-15f
#define SQEPS 3.1622776601683794e-8f
#define MXN 0.99999f   /* 1 - 1e-5 */

typedef unsigned short u16;
typedef __bf16 bf16x8 __attribute__((ext_vector_type(8)));
typedef float f32x4 __attribute__((ext_vector_type(4)));
typedef unsigned short u16x8 __attribute__((ext_vector_type(8)));
typedef unsigned short u16x4 __attribute__((ext_vector_type(4)));

// ---- fast hw transcendentals ----
__device__ __forceinline__ float fexp(float x){ return __builtin_amdgcn_exp2f(x * 1.4426950408889634f); }
__device__ __forceinline__ float flog(float x){ return __builtin_amdgcn_logf(x) * 0.6931471805599453f; }
__device__ __forceinline__ float frcp(float x){ return __builtin_amdgcn_rcpf(x); }
__device__ __forceinline__ float fsqrt(float x){ return __builtin_amdgcn_sqrtf(x); }
__device__ __forceinline__ float ftanh(float x){
  float xc = fminf(fmaxf(x, -15.f), 15.f);
  float t = fexp(2.f * xc);
  return (t - 1.f) * frcp(t + 1.f);
}
__device__ __forceinline__ float at_c(float x){          // _artanh with clip
  float xc = fminf(fmaxf(x, -1.f + 1e-5f), 1.f - 1e-5f);
  return 0.5f * flog((1.f + xc) * frcp(1.f - xc));
}
__device__ __forceinline__ float fsig(float x){ return frcp(1.f + fexp(-x)); }

__device__ __forceinline__ float b2f(u16 u){
  unsigned int x = ((unsigned int)u) << 16;
  return __builtin_bit_cast(float, x);
}
__device__ __forceinline__ u16 f2b(float f){
  unsigned int u = __builtin_bit_cast(unsigned int, f);
  return (u16)((u + 0x7fffu + ((u >> 16) & 1u)) >> 16);
}
__device__ __forceinline__ float wred(float v){          // 64-lane sum
#pragma unroll
  for (int m = 32; m; m >>= 1) v += __shfl_xor(v, m);
  return v;
}
__device__ __forceinline__ float sig_proj(float npre, float* nrm){
  float n = fmaxf(npre, SQEPS);
  float s = (n > MXN) ? (MXN * frcp(n)) : 1.f;
  *nrm = fminf(n, MXN);
  return s;
}
__device__ __forceinline__ void ld4(const u16* p, float v[4]){   // bf16 table load
  u16x4 t = *(const u16x4*)p;
#pragma unroll
  for (int r = 0; r < 4; r++) v[r] = b2f(t[r]);
}
__device__ __forceinline__ void ld4f(const float* p, float v[4]){ // f32 load
  f32x4 t = *(const f32x4*)p;
#pragma unroll
  for (int r = 0; r < 4; r++) v[r] = t[r];
}
// async global->LDS, 16 B per lane; LDS dest = uniform base + lane*16
__device__ __forceinline__ void glds16(const u16* g, u16* l){
  typedef __attribute__((address_space(1))) const unsigned int gu32;
  typedef __attribute__((address_space(3))) unsigned int lu32;
  __builtin_amdgcn_global_load_lds((gu32*)g, (lu32*)l, 16, 0, 0);
}

// ---------------- K0: convert all weights to bf16 arena ----------------
// dst layout (elements): Wq[0,65536) Wiou[65536,262144) Wk[262144,327680)
// Uf[327680,393216) Wc[393216,458752) Uiou[458752,655360)
__global__ void __launch_bounds__(256) k_wcvt(
    const float* __restrict__ Wq, const float* __restrict__ Wiou,
    const float* __restrict__ Wk, const float* __restrict__ Uf,
    const float* __restrict__ Wc, const float* __restrict__ Uiou,
    u16* __restrict__ dst)
{
  size_t base = ((size_t)blockIdx.x * 256 + threadIdx.x) * 4;
  const float* src; size_t off;
  if      (base <  65536){ src = Wq;   off = base; }
  else if (base < 262144){ src = Wiou; off = base - 65536; }
  else if (base < 327680){ src = Wk;   off = base - 262144; }
  else if (base < 393216){ src = Uf;   off = base - 327680; }
  else if (base < 458752){ src = Wc;   off = base - 393216; }
  else                   { src = Uiou; off = base - 458752; }
  f32x4 v = *(const f32x4*)(src + off);
  u16x4 o;
#pragma unroll
  for (int r = 0; r < 4; r++) o[r] = f2b(v[r]);
  *(u16x4*)(dst + base) = o;
}

// ---------------- K1: per-node prep: xbb/cb/pack-hb (bf16), norms ----------------
__global__ void __launch_bounds__(256) k_prep(const float* __restrict__ x,
    const float* __restrict__ h1, const float* __restrict__ c1,
    u16* __restrict__ xbb, u16* __restrict__ cb, u16* __restrict__ pack,
    float* __restrict__ scal)
{
  int w = threadIdx.x >> 6, lane = threadIdx.x & 63;
  int n = blockIdx.x * 4 + w;
  int base = n * D + lane * 4;
  float xv[4], hv[4], cv[4];
  ld4f(x + base, xv); ld4f(h1 + base, hv); ld4f(c1 + base, cv);
  float un2 = 0, hn2 = 0, prn2 = 0, cn2 = 0;
#pragma unroll
  for (int r = 0; r < 4; r++){
    un2 += xv[r]*xv[r]; hn2 += hv[r]*hv[r];
    float rr = fmaxf(hv[r], 0.f); prn2 += rr*rr;
    cn2 += cv[r]*cv[r];
  }
  un2 = wred(un2); hn2 = wred(hn2); prn2 = wred(prn2); cn2 = wred(cn2);
  float un = fsqrt(fmaxf(un2, EPSR));
  float t  = ftanh(un);
  float sc = t * frcp(un);
  float nx = fsqrt(fmaxf(sc*sc*un2, EPSR));
  float s  = (nx > MXN) ? (MXN * frcp(nx)) : 1.f;
  u16x4 ox, oh, oc;
#pragma unroll
  for (int r = 0; r < 4; r++){ ox[r] = f2b(s*sc*xv[r]); oh[r] = f2b(hv[r]); oc[r] = f2b(cv[r]); }
  *(u16x4*)(xbb + base) = ox;
  *(u16x4*)(cb + base) = oc;
  *(u16x4*)(pack + (size_t)n*768 + lane*4) = oh;
  if (lane == 0){
    float* sp = scal + (size_t)n * 16;
    sp[0] = fminf(nx, MXN);
    sp[1] = hn2; sp[2] = prn2; sp[3] = cn2;
    float hn = fsqrt(fmaxf(hn2, EPSR));
    sp[9] = at_c(hn); sp[10] = hn;
  }
}

// -- MFMA GEMM core: C[*,Nout](bf16) = A[M,256](bf16, stride lda) @ B[Nout,256]^T --
// glds staging into unpadded LDS (row = 32 u16 = 64 B) with XOR chunk swizzle
// c' = c ^ (row&3) ^ ((row>>2)&3): quarter-wave b128 reads are 2-way = free.
#define TM 128
#define TN 128
#define TK 32
__device__ __forceinline__ void gemm_core(const u16* __restrict__ A, int lda,
    const u16* __restrict__ B, u16* __restrict__ C, int Nout,
    int m0, int n0, u16* As, u16* Bs)
{
  int t = threadIdx.x;
  int w = t >> 6, lane = t & 63;
  int wr = w >> 1, wc = w & 1;
  int q = lane >> 4, l16 = lane & 15;
  int lrow = lane >> 2, lc = lane & 3;
  // staging rows for this wave (2 sub-tiles of 16 rows)
  int r0 = w*32 + lrow, r1 = r0 + 16;
  int cg0 = lc ^ (r0 & 3) ^ ((r0 >> 2) & 3);
  int cg1 = lc ^ (r1 & 3) ^ ((r1 >> 2) & 3);
  const u16* a0 = A + (size_t)(m0 + r0)*lda + cg0*8;
  const u16* a1 = A + (size_t)(m0 + r1)*lda + cg1*8;
  const u16* b0 = B + (size_t)(n0 + r0)*256 + cg0*8;
  const u16* b1 = B + (size_t)(n0 + r1)*256 + cg1*8;
  u16* lA0 = As + (w*32)*32;      u16* lA1 = As + (w*32 + 16)*32;
  u16* lB0 = Bs + (w*32)*32;      u16* lB1 = Bs + (w*32 + 16)*32;
  f32x4 acc[4][4];
#pragma unroll
  for (int i = 0; i < 4; i++)
#pragma unroll
    for (int j = 0; j < 4; j++) acc[i][j] = (f32x4){0.f,0.f,0.f,0.f};
  for (int k0 = 0; k0 < 256; k0 += TK){
    __syncthreads();
    glds16(a0 + k0, lA0);
    glds16(a1 + k0, lA1);
    glds16(b0 + k0, lB0);
    glds16(b1 + k0, lB1);
    __syncthreads();
    bf16x8 af[4], bfr[4];
#pragma unroll
    for (int rb = 0; rb < 4; rb++){
      int ra = wr*64 + rb*16 + l16;
      int ca = q ^ (ra & 3) ^ ((ra >> 2) & 3);
      af[rb] = *(const bf16x8*)(As + ra*32 + ca*8);
    }
#pragma unroll
    for (int cb2 = 0; cb2 < 4; cb2++){
      int rb2 = wc*64 + cb2*16 + l16;
      int cbk = q ^ (rb2 & 3) ^ ((rb2 >> 2) & 3);
      bfr[cb2] = *(const bf16x8*)(Bs + rb2*32 + cbk*8);
    }
#pragma unroll
    for (int rb = 0; rb < 4; rb++)
#pragma unroll
      for (int cb2 = 0; cb2 < 4; cb2++)
        acc[rb][cb2] = __builtin_amdgcn_mfma_f32_16x16x32_bf16(af[rb], bfr[cb2], acc[rb][cb2], 0, 0, 0);
  }
#pragma unroll
  for (int rb = 0; rb < 4; rb++)
#pragma unroll
    for (int cb2 = 0; cb2 < 4; cb2++)
#pragma unroll
      for (int r = 0; r < 4; r++){
        int m  = m0 + wr*64 + rb*16 + q*4 + r;
        int nn = n0 + wc*64 + cb2*16 + l16;
        C[(size_t)m*Nout + nn] = f2b(acc[rb][cb2][r]);
      }
}

// fused front GEMMs: y<8 -> mqiou(1024); y<12 -> mkf(512); else mc(256)
__global__ void __launch_bounds__(256) k_mm3(
    const u16* __restrict__ xbb, const u16* __restrict__ pack,
    const u16* __restrict__ cbp, const u16* __restrict__ wb,
    u16* __restrict__ mqiou, u16* __restrict__ mkf, u16* __restrict__ mc)
{
  __shared__ u16 As[TM*32];
  __shared__ u16 Bs[TN*32];
  int by = blockIdx.y;
  const u16* A; int lda; const u16* B; u16* C; int Nout; int n0;
  if (by < 8)      { A = xbb;  lda = 256; B = wb;          C = mqiou; Nout = 1024; n0 = by*128; }
  else if (by < 12){ A = pack; lda = 768; B = wb + 262144; C = mkf;   Nout = 512;  n0 = (by-8)*128; }
  else             { A = cbp;  lda = 256; B = wb + 393216; C = mc;    Nout = 256;  n0 = (by-12)*128; }
  gemm_core(A, lda, B, C, Nout, blockIdx.x*TM, n0, As, Bs);
}

__global__ void __launch_bounds__(256) gemm_bt(const u16* __restrict__ A, int lda,
    const u16* __restrict__ B, u16* __restrict__ C, int Nout)
{
  __shared__ u16 As[TM*32];
  __shared__ u16 Bs[TN*32];
  gemm_core(A, lda, B, C, Nout, blockIdx.x*TM, blockIdx.y*TN, As, Bs);
}

// z = mobius_add(mm_scale(m; xn), b) ; returns clipped norm of z
__device__ __forceinline__ float mm_madd(const float mv[4], const float bv[4], float xn, float z[4]){
  float mn2 = 0.f;
#pragma unroll
  for (int r = 0; r < 4; r++) mn2 += mv[r]*mv[r];
  mn2 = wred(mn2);
  float mnc = fsqrt(fmaxf(mn2, EPSR));
  float imnc = frcp(mnc);
  float t = ftanh(mnc * frcp(xn) * at_c(xn));
  float npre = t * fsqrt(mn2) * imnc;
  float nf; float sg = sig_proj(npre, &nf);
  float cx = sg * t * imnc;
  float x2 = (sg*npre)*(sg*npre);
  float y2 = 0.f, xy = 0.f;
#pragma unroll
  for (int r = 0; r < 4; r++){ y2 += bv[r]*bv[r]; xy += cx*mv[r]*bv[r]; }
  y2 = wred(y2); xy = wred(xy);
  float A = 1.f + 2.f*xy + y2, Bc = 1.f - x2;
  float idn = frcp(fmaxf(1.f + 2.f*xy + x2*y2, EPSR));
  float zn2 = (A*A*x2 + 2.f*A*Bc*xy + Bc*Bc*y2) * idn * idn;
  float zn = fsqrt(fmaxf(zn2, EPSR));
  float sz = (zn > MXN) ? (MXN * frcp(zn)) : 1.f;
  float ca = sz * A * idn * cx, cb = sz * Bc * idn;
#pragma unroll
  for (int r = 0; r < 4; r++) z[r] = ca*mv[r] + cb*bv[r];
  return fminf(zn, MXN);
}

// ---------------- K7: per-node post-GEMM: q, kvec, f, c_sk tables ----------------
__global__ void __launch_bounds__(256) k_post(
    const u16* __restrict__ mqiou, const u16* __restrict__ mkf,
    const u16* __restrict__ mc,
    const float* __restrict__ c1,
    const float* __restrict__ bq, const float* __restrict__ bk, const float* __restrict__ bc,
    u16* __restrict__ qv, u16* __restrict__ kv,
    u16* __restrict__ pack,
    float* __restrict__ scal)
{
  int w = threadIdx.x >> 6, lane = threadIdx.x & 63;
  int n = blockIdx.x * 4 + w;
  int base = n * D + lane * 4, lb = lane * 4;
  float* sp = scal + (size_t)n * 16;
  float xbn = sp[0], hn2 = sp[1], cn2 = sp[3];
  float hnc = fsqrt(fmaxf(hn2, EPSR));
  float cnc = fsqrt(fmaxf(cn2, EPSR));
  float mv[4], bv[4], z[4];
  u16x4 o;
  // q = logmap0(mobius_add(mm(W_q, x_ball), b_q))    [mqiou cols 0:256, stride 1024]
  ld4(mqiou + (size_t)n*1024 + lb, mv); ld4f(bq + lb, bv);
  float znf = mm_madd(mv, bv, xbn, z);
  float cl = at_c(znf) * frcp(znf);
#pragma unroll
  for (int r = 0; r < 4; r++) o[r] = f2b(cl * z[r]);
  *(u16x4*)(qv + base) = o;
  // kvec = logmap0(mobius_add(mm(W_k, h1), b_k))     [mkf cols 0:256, stride 512]
  ld4(mkf + (size_t)n*512 + lb, mv); ld4f(bk + lb, bv);
  znf = mm_madd(mv, bv, hnc, z);
  cl = at_c(znf) * frcp(znf);
#pragma unroll
  for (int r = 0; r < 4; r++) o[r] = f2b(cl * z[r]);
  *(u16x4*)(kv + base) = o;
  // f = sigmoid(logmap0(mm(U_f, h1)))                [mkf cols 256:512]
  float fv[4];
  {
    ld4(mkf + (size_t)n*512 + 256 + lb, mv);
    float mn2 = 0.f;
#pragma unroll
    for (int r = 0; r < 4; r++) mn2 += mv[r]*mv[r];
    mn2 = wred(mn2);
    float mnc = fsqrt(fmaxf(mn2, EPSR));
    float imnc = frcp(mnc);
    float t = ftanh(mnc * frcp(hnc) * at_c(hnc));
    float npre = t * fsqrt(mn2) * imnc;
    float nf; float sg = sig_proj(npre, &nf);
    float cx = sg * t * imnc;
    float lcf = at_c(nf) * frcp(nf);
#pragma unroll
    for (int r = 0; r < 4; r++) fv[r] = fsig(lcf * cx * mv[r]);
  }
  // c_sk = expmap0(tanh(logmap0(mobius_add(mm(W_c, c1), b_c))))
  float csk[4];
  {
    ld4(mc + base, mv); ld4f(bc + lb, bv);
    float zn = mm_madd(mv, bv, cnc, z);
    float lc = at_c(zn) * frcp(zn);
    float th[4]; float thn2 = 0.f;
#pragma unroll
    for (int r = 0; r < 4; r++){ th[r] = ftanh(lc * z[r]); thn2 += th[r]*th[r]; }
    thn2 = wred(thn2);
    float thn = fsqrt(fmaxf(thn2, EPSR));
    float te = ftanh(thn);
    float se = te * frcp(thn);
    float npe = fsqrt(fmaxf(se*se*thn2, EPSR));
    float sge = (npe > MXN) ? (MXN * frcp(npe)) : 1.f;
#pragma unroll
    for (int r = 0; r < 4; r++) csk[r] = sge * se * th[r];
  }
  float c1v[4]; ld4f(c1 + base, c1v);
  float csn2 = 0, pcc = 0, pfss = 0, pfsm = 0, pfmm = 0;
#pragma unroll
  for (int r = 0; r < 4; r++){
    float f2 = fv[r]*fv[r];
    csn2 += csk[r]*csk[r];
    pcc  += csk[r]*c1v[r];
    pfss += f2*csk[r]*csk[r];
    pfsm += f2*csk[r]*c1v[r];
    pfmm += f2*c1v[r]*c1v[r];
  }
  csn2 = wred(csn2); pcc = wred(pcc); pfss = wred(pfss); pfsm = wred(pfsm); pfmm = wred(pfmm);
  u16x4 oa, ob;
#pragma unroll
  for (int r = 0; r < 4; r++){ oa[r] = f2b(fv[r]*csk[r]); ob[r] = f2b(fv[r]*c1v[r]); }
  *(u16x4*)(pack + (size_t)n*768 + 256 + lb) = oa;   // fcs
  *(u16x4*)(pack + (size_t)n*768 + 512 + lb) = ob;   // fcm
  if (lane == 0){
    sp[4] = csn2; sp[5] = pcc; sp[6] = pfss; sp[7] = pfsm; sp[8] = pfmm;
  }
}

// ------- K8ab fused: logits (wave/node) + coef chains (lane-parallel) -------
__global__ void __launch_bounds__(256) k_lgc(
    const int* __restrict__ edges, const float* __restrict__ del_t,
    const u16* __restrict__ qv, const u16* __restrict__ kvec,
    const float* __restrict__ scal,
    const float* __restrict__ pbh, const float* __restrict__ pah,
    const float* __restrict__ ph1, const float* __restrict__ ph2,
    float* __restrict__ coef)
{
  __shared__ int   s_j[4][16];
  __shared__ float s_dt[4][16];
  __shared__ float s_lg[4][16];
  int w = threadIdx.x >> 6, lane = threadIdx.x & 63;
  int n = blockIdx.x * 4 + w;
  float bh = pbh[0], ah = pah[0], hw1 = ph1[0], hw2 = ph2[0];
  float qf[4]; ld4(qv + n*D + lane*4, qf);
#pragma unroll
  for (int k = 0; k < 16; k++){
    int j = edges[n*16 + k];
    float dt = del_t[j];
    u16x4 kt = *(const u16x4*)(kvec + (size_t)j*D + lane*4);
    float d = 0.f;
#pragma unroll
    for (int r = 0; r < 4; r++) d += qf[r] * b2f(kt[r]);
    d = wred(d);
    if (lane == 0){ s_j[w][k] = j; s_dt[w][k] = dt; s_lg[w][k] = d * 0.0625f + bh * fexp(-ah * dt); }
  }
  __syncthreads();
  if (lane >= 16) return;
  int e = n*16 + lane;
  int j = s_j[w][lane];
  float dt = s_dt[w][lane];
  const float* ln = s_lg[w];
  float mxl = -1e30f;
#pragma unroll
  for (int k = 0; k < 16; k++) mxl = fmaxf(mxl, ln[k]);
  float sume = 0.f;
#pragma unroll
  for (int k = 0; k < 16; k++) sume += fexp(ln[k] - mxl);
  float sk = fexp(ln[lane] - mxl) * frcp(sume);
  const float* sp2 = scal + (size_t)j * 16;
  float hn2 = sp2[1], prn2 = sp2[2], cn2 = sp2[3], csn2 = sp2[4], pcc = sp2[5],
        pfss = sp2[6], pfsm = sp2[7], pfmm = sp2[8], athn = sp2[9], hn = sp2[10];
  float g = bh * fexp(-ah * dt);
  float decay = fexp(-hw2 * dt * (1.f/60.f));
  // h-side
  float wxn1 = fsqrt(fmaxf(sk*sk*hn2, EPSR));
  float iwxn1 = frcp(wxn1);
  float t1 = ftanh(wxn1 * frcp(hn) * athn);
  float npre1 = t1 * sk * fsqrt(hn2) * iwxn1;
  float nn1 = fmaxf(npre1, SQEPS); float sg1 = (nn1 > MXN) ? MXN*frcp(nn1) : 1.f;
  float a_h = sg1 * t1 * sk * iwxn1;
  float rn2 = a_h*a_h*prn2;
  float xnd  = fsqrt(fmaxf(decay*decay, EPSR));
  float wxn2 = fsqrt(fmaxf(decay*decay*rn2, EPSR));
  float iwxn2 = frcp(wxn2);
  float t2 = ftanh(wxn2 * frcp(xnd) * at_c(xnd));
  float npre2 = t2 * decay * fsqrt(rn2) * iwxn2;
  float nn2 = fmaxf(npre2, SQEPS); float sg2 = (nn2 > MXN) ? MXN*frcp(nn2) : 1.f;
  float b_h = sg2 * t2 * decay * a_h * iwxn2;
  float bh1 = hw1 * b_h;
  float x2 = a_h*a_h*hn2;
  float y2 = bh1*bh1*prn2;
  float xy = a_h*bh1*prn2;            // hx dot relu(hx) = relu(hx)^2
  float A = 1.f + 2.f*xy + y2, B = 1.f - x2;
  float idn = frcp(fmaxf(1.f + 2.f*xy + x2*y2, EPSR));
  float nh2 = (A*A*x2 + 2.f*A*B*xy + B*B*y2) * idn * idn;
  float nh = fsqrt(fmaxf(nh2, EPSR)); float sg3 = (nh > MXN) ? MXN*frcp(nh) : 1.f;
  float p  = sg3 * A * a_h * idn;
  float rr = sg3 * B * bh1 * idn;
  float hhn2 = sg3*sg3*nh2;
  float lam = 2.f * frcp(fmaxf(1.f - hhn2, EPSR));
  // c-side
  float xng  = fsqrt(fmaxf(g*g, EPSR));
  float wxn3 = fsqrt(fmaxf(g*g*csn2, EPSR));
  float iwxn3 = frcp(wxn3);
  float t3 = ftanh(wxn3 * frcp(xng) * at_c(xng));
  float npre3 = t3 * g * fsqrt(csn2) * iwxn3;
  float nn3 = fmaxf(npre3, SQEPS); float sgc = (nn3 > MXN) ? MXN*frcp(nn3) : 1.f;
  float gam = sgc * t3 * g * iwxn3;
  float A1 = 1.f - 2.f*pcc + cn2, B1 = 1.f - csn2;
  float iden1 = frcp(fmaxf(1.f - 2.f*pcc + csn2*cn2, EPSR));
  float al = -A1*iden1, be = B1*iden1;
  float n1sq = al*al*csn2 + 2.f*al*be*pcc + be*be*cn2;
  float n1 = fsqrt(fmaxf(n1sq, EPSR)); float s1 = (n1 > MXN) ? MXN*frcp(n1) : 1.f;
  al *= s1; be *= s1;
  float z1n2 = s1*s1*n1sq;
  float y2c = gam*gam*csn2;
  float xyc = gam*(al*csn2 + be*pcc);
  float A2 = 1.f + 2.f*xyc + y2c, B2 = 1.f - z1n2;
  float iden2 = frcp(fmaxf(1.f + 2.f*xyc + z1n2*y2c, EPSR));
  float u1 = (A2*al + B2*gam)*iden2, u2 = A2*be*iden2;
  float n2sq = u1*u1*csn2 + 2.f*u1*u2*pcc + u2*u2*cn2;
  float n2 = fsqrt(fmaxf(n2sq, EPSR)); float s2 = (n2 > MXN) ? MXN*frcp(n2) : 1.f;
  u1 *= s2; u2 *= s2;
  float xnc = fminf(n2, MXN);
  float wx2 = u1*u1*pfss + 2.f*u1*u2*pfsm + u2*u2*pfmm;
  float wxn4 = fsqrt(fmaxf(wx2, EPSR));
  float iwxn4 = frcp(wxn4);
  float t4 = ftanh(wxn4 * frcp(xnc) * at_c(xnc));
  float npre4 = t4 * fsqrt(wx2) * iwxn4;
  float nn4 = fmaxf(npre4, SQEPS); float s4 = (nn4 > MXN) ? MXN*frcp(nn4) : 1.f;
  float v1 = s4*t4*u1*iwxn4, v2 = s4*t4*u2*iwxn4;
  float rsn2 = (s4*npre4)*(s4*npre4);
  float lam2 = 2.f * frcp(fmaxf(1.f - rsn2, EPSR));
  float* cf = coef + (size_t)e * 6;
  cf[0] = lam; cf[1] = lam*p; cf[2] = lam*rr;
  cf[3] = lam2; cf[4] = lam2*v1; cf[5] = lam2*v2;
}

// ------- K8c: accumulate, 2 waves/node (8 edges each) + LDS combine -------
__global__ void __launch_bounds__(256) k_acc(
    const int* __restrict__ edges, const u16* __restrict__ pack,
    const float* __restrict__ coef,
    u16* __restrict__ ht, u16* __restrict__ cred, float* __restrict__ htn_arr)
{
  __shared__ f32x4 s_nh[2][64];
  __shared__ f32x4 s_nc[2][64];
  __shared__ float s_d[2][2];
  int w = threadIdx.x >> 6, lane = threadIdx.x & 63;
  int nb = w >> 1, half = w & 1;
  int n = blockIdx.x * 2 + nb;
  float numh[4] = {0,0,0,0}, numc[4] = {0,0,0,0};
  float denh = 0.f, denc = 0.f;
#pragma unroll
  for (int kk = 0; kk < 8; kk++){
    int k = half*8 + kk;
    int e = n*16 + k;
    int j = edges[e];
    const float* cf = coef + (size_t)e * 6;
    float lam = cf[0], lamp = cf[1], lamr = cf[2];
    float lam2 = cf[3], lv1 = cf[4], lv2 = cf[5];
    denh += lam - 1.f; denc += lam2 - 1.f;
    const u16* pr = pack + (size_t)j*768 + lane*4;
    u16x4 hx4 = *(const u16x4*)(pr);
    u16x4 fs4 = *(const u16x4*)(pr + 256);
    u16x4 fm4 = *(const u16x4*)(pr + 512);
#pragma unroll
    for (int r = 0; r < 4; r++){
      float hxr = b2f(hx4[r]);
      numh[r] += lamp*hxr + lamr*fmaxf(hxr, 0.f);
      numc[r] += lv1*b2f(fs4[r]) + lv2*b2f(fm4[r]);
    }
  }
  if (half == 1){
    f32x4 a, b;
#pragma unroll
    for (int r = 0; r < 4; r++){ a[r] = numh[r]; b[r] = numc[r]; }
    s_nh[nb][lane] = a; s_nc[nb][lane] = b;
    if (lane == 0){ s_d[nb][0] = denh; s_d[nb][1] = denc; }
  }
  __syncthreads();
  if (half == 1) return;
  {
    f32x4 a = s_nh[nb][lane], b = s_nc[nb][lane];
#pragma unroll
    for (int r = 0; r < 4; r++){ numh[r] += a[r]; numc[r] += b[r]; }
    denh += s_d[nb][0]; denc += s_d[nb][1];
  }
  if (fabsf(denh) < 1e-10f) denh = 1e-10f;
  if (fabsf(denc) < 1e-10f) denc = 1e-10f;
  float idh = frcp(denh), idc = frcp(denc);
  float vh[4], vc[4]; float vn2h = 0.f, vn2c = 0.f;
#pragma unroll
  for (int r = 0; r < 4; r++){
    vh[r] = numh[r]*idh; vn2h += vh[r]*vh[r];
    vc[r] = numc[r]*idc; vn2c += vc[r]*vc[r];
  }
  vn2h = wred(vn2h); vn2c = wred(vn2c);
  float vnh = fsqrt(fmaxf(vn2h, EPSR));
  float tth = ftanh(0.5f * at_c(vnh));
  float nph = tth * fsqrt(vn2h) * frcp(vnh);
  float nfh; float sh = sig_proj(nph, &nfh);
  float chh = sh * tth * frcp(vnh);
  u16x4 ho;
#pragma unroll
  for (int r = 0; r < 4; r++) ho[r] = f2b(chh * vh[r]);
  *(u16x4*)(ht + (size_t)n*D + lane*4) = ho;
  if (lane == 0) htn_arr[n] = nfh;
  float vnc = fsqrt(fmaxf(vn2c, EPSR));
  float ttc = ftanh(0.5f * at_c(vnc));
  float npc = ttc * fsqrt(vn2c) * frcp(vnc);
  float nfc; float scz = sig_proj(npc, &nfc);
  float chc = scz * ttc * frcp(vnc);
  u16x4 co;
#pragma unroll
  for (int r = 0; r < 4; r++) co[r] = f2b(chc * vc[r]);
  *(u16x4*)(cred + (size_t)n*D + lane*4) = co;
}

// ---------------- K10: final iou chain + outputs ----------------
__global__ void __launch_bounds__(256) k_final(
    const u16* __restrict__ mqiou, const u16* __restrict__ mu,
    const u16* __restrict__ cred, const float* __restrict__ biou,
    const float* __restrict__ scal, const float* __restrict__ htn_arr,
    float* __restrict__ out)
{
  int w = threadIdx.x >> 6, lane = threadIdx.x & 63;
  int n = blockIdx.x * 4 + w;
  float mi[3][4], muv[3][4], bi[3][4];
#pragma unroll
  for (int p = 0; p < 3; p++){
    ld4(mqiou + (size_t)n*1024 + 256 + p*256 + lane*4, mi[p]);   // miou cols 256:1024
    ld4(mu   + (size_t)n*768 + p*256 + lane*4, muv[p]);
    ld4f(biou + p*256 + lane*4, bi[p]);
  }
  float cr[4]; ld4(cred + (size_t)n*D + lane*4, cr);
  float xbn = scal[(size_t)n*16 + 0];
  float htn = htn_arr[n];
  float mn2 = 0.f, un2 = 0.f, dmu = 0.f;
#pragma unroll
  for (int p = 0; p < 3; p++)
#pragma unroll
    for (int r = 0; r < 4; r++){
      mn2 += mi[p][r]*mi[p][r]; un2 += muv[p][r]*muv[p][r]; dmu += mi[p][r]*muv[p][r];
    }
  mn2 = wred(mn2); un2 = wred(un2); dmu = wred(dmu);
  float mnc = fsqrt(fmaxf(mn2, EPSR));
  float ta = ftanh(mnc * frcp(xbn) * at_c(xbn));
  float npa = ta * fsqrt(mn2) * frcp(mnc);
  float na_; float sa = sig_proj(npa, &na_);
  float ca = sa * ta * frcp(mnc); float x2 = (sa*npa)*(sa*npa);
  float unc = fsqrt(fmaxf(un2, EPSR));
  float tb = ftanh(unc * frcp(htn) * at_c(htn));
  float npb = tb * fsqrt(un2) * frcp(unc);
  float nb_; float sb = sig_proj(npb, &nb_);
  float cb = sb * tb * frcp(unc); float y2 = (sb*npb)*(sb*npb);
  float xy = ca * cb * dmu;
  float A = 1.f + 2.f*xy + y2, B = 1.f - x2;
  float idn = frcp(fmaxf(1.f + 2.f*xy + x2*y2, EPSR));
  float c_mi = A*ca*idn, c_mu = B*cb*idn;
  float n1sq = (A*A*x2 + 2.f*A*B*xy + B*B*y2) * idn * idn;
  float n1 = fsqrt(fmaxf(n1sq, EPSR)); float s1 = (n1 > MXN) ? MXN*frcp(n1) : 1.f;
  c_mi *= s1; c_mu *= s1;
  float iou1n2 = s1*s1*n1sq;
  float io1[3][4]; float bb2 = 0.f, xyb = 0.f;
#pragma unroll
  for (int p = 0; p < 3; p++)
#pragma unroll
    for (int r = 0; r < 4; r++){
      io1[p][r] = c_mi*mi[p][r] + c_mu*muv[p][r];
      bb2 += bi[p][r]*bi[p][r]; xyb += io1[p][r]*bi[p][r];
    }
  bb2 = wred(bb2); xyb = wred(xyb);
  float A2 = 1.f + 2.f*xyb + bb2, B2 = 1.f - iou1n2;
  float iden2 = frcp(fmaxf(1.f + 2.f*xyb + iou1n2*bb2, EPSR));
  float n2sq = (A2*A2*iou1n2 + 2.f*A2*B2*xyb + B2*B2*bb2) * iden2 * iden2;
  float n2c = fsqrt(fmaxf(n2sq, EPSR)); float s2 = (n2c > MXN) ? MXN*frcp(n2c) : 1.f;
  float cA2 = s2*A2*iden2, cB2 = s2*B2*iden2;
  float iou[3][4];
#pragma unroll
  for (int p = 0; p < 3; p++)
#pragma unroll
    for (int r = 0; r < 4; r++) iou[p][r] = cA2*io1[p][r] + cB2*bi[p][r];
  float ni2 = 0.f, no2 = 0.f, nu2 = 0.f;
#pragma unroll
  for (int r = 0; r < 4; r++){ ni2 += iou[0][r]*iou[0][r]; no2 += iou[1][r]*iou[1][r]; nu2 += iou[2][r]*iou[2][r]; }
  ni2 = wred(ni2); no2 = wred(no2); nu2 = wred(nu2);
  float niN = fsqrt(fmaxf(ni2, EPSR)), noN = fsqrt(fmaxf(no2, EPSR)), nuN = fsqrt(fmaxf(nu2, EPSR));
  float ci = at_c(niN)*frcp(niN), co = at_c(noN)*frcp(noN), cu = at_c(nuN)*frcp(nuN);
  float iv[4], ov[4], uv[4];
#pragma unroll
  for (int r = 0; r < 4; r++){
    iv[r] = fsig(ci*iou[0][r]);
    ov[r] = fsig(co*iou[1][r]);
    uv[r] = ftanh(cu*iou[2][r]);
  }
  float xn2 = 0.f, wn2 = 0.f; float wx[4];
#pragma unroll
  for (int r = 0; r < 4; r++){ xn2 += uv[r]*uv[r]; wx[r] = iv[r]*uv[r]; wn2 += wx[r]*wx[r]; }
  xn2 = wred(xn2); wn2 = wred(wn2);
  float xnc = fsqrt(fmaxf(xn2, EPSR)), wnc = fsqrt(fmaxf(wn2, EPSR));
  float t4 = ftanh(wnc * frcp(xnc) * at_c(xnc));
  float np4 = t4 * fsqrt(wn2) * frcp(wnc);
  float n4_; float s4 = sig_proj(np4, &n4_);
  float cpm = s4*t4*frcp(wnc); float pmn2 = (s4*np4)*(s4*np4);
  float y2c = 0.f, xyc = 0.f;
#pragma unroll
  for (int r = 0; r < 4; r++){ y2c += cr[r]*cr[r]; xyc += cpm*wx[r]*cr[r]; }
  y2c = wred(y2c); xyc = wred(xyc);
  float A3 = 1.f + 2.f*xyc + y2c, B3 = 1.f - pmn2;
  float iden3 = frcp(fmaxf(1.f + 2.f*xyc + pmn2*y2c, EPSR));
  float n3sq = (A3*A3*pmn2 + 2.f*A3*B3*xyc + B3*B3*y2c) * iden3 * iden3;
  float n3 = fsqrt(fmaxf(n3sq, EPSR)); float s3 = (n3 > MXN) ? MXN*frcp(n3) : 1.f;
  float cA3 = s3*A3*cpm*iden3, cB3 = s3*B3*iden3;
  float cnw[4]; f32x4 oc;
#pragma unroll
  for (int r = 0; r < 4; r++){ cnw[r] = cA3*wx[r] + cB3*cr[r]; oc[r] = cnw[r]; }
  *(f32x4*)(out + NB + (size_t)n*D + lane*4) = oc;
  float ncn = fminf(n3, MXN);
  float clg = at_c(ncn)*frcp(ncn);
  float th[4]; float xn5 = 0.f, wn5 = 0.f; float wx5[4];
#pragma unroll
  for (int r = 0; r < 4; r++){
    th[r] = ftanh(clg*cnw[r]);
    xn5 += th[r]*th[r]; wx5[r] = ov[r]*th[r]; wn5 += wx5[r]*wx5[r];
  }
  xn5 = wred(xn5); wn5 = wred(wn5);
  float xn5c = fsqrt(fmaxf(xn5, EPSR)), wn5c = fsqrt(fmaxf(wn5, EPSR));
  float t5 = ftanh(wn5c * frcp(xn5c) * at_c(xn5c));
  float np5 = t5 * fsqrt(wn5) * frcp(wn5c);
  float n5_; float s5 = sig_proj(np5, &n5_);
  float ch = s5*t5*frcp(wn5c);
  f32x4 oh;
#pragma unroll
  for (int r = 0; r < 4; r++) oh[r] = ch * wx5[r];
  *(f32x4*)(out + (size_t)n*D + lane*4) = oh;
}

extern "C" void kernel_launch(void* const* d_in, const int* in_sizes, int n_in,
                              void* d_out, int out_size, void* d_ws, size_t ws_size,
                              hipStream_t stream)
{
  (void)in_sizes; (void)n_in; (void)out_size; (void)ws_size;
  const float* x     = (const float*)d_in[0];
  const float* h1    = (const float*)d_in[1];
  const float* c1    = (const float*)d_in[2];
  const float* del_t = (const float*)d_in[3];
  const int*   edges = (const int*)d_in[4];
  const float* W_iou = (const float*)d_in[5];
  const float* U_iou = (const float*)d_in[6];
  const float* b_iou = (const float*)d_in[7];
  const float* U_f   = (const float*)d_in[8];
  const float* W_q   = (const float*)d_in[9];
  const float* b_q   = (const float*)d_in[10];
  const float* W_k   = (const float*)d_in[11];
  const float* b_k   = (const float*)d_in[12];
  const float* W_c   = (const float*)d_in[13];
  const float* b_c   = (const float*)d_in[14];
  const float* b_haw = (const float*)d_in[15];
  const float* a_haw = (const float*)d_in[16];
  const float* haw1  = (const float*)d_in[17];
  const float* haw2  = (const float*)d_in[18];

  // workspace (u16 units):
  // wb(655360) | xbb(NB, reused as ht) | cb(NB) | pack(NN*768) | mqiou(4NB) |
  // mkf(2NB) | mc(NB)  [mu(3NB)=mkf..mc] | qv(NB, reused as cred) |
  // kvec(NB) | scal | coef | htn
  u16* wb    = (u16*)d_ws;                   // 655360
  u16* xbb   = wb + 655360;                  // NB
  u16* cb    = xbb + NB;                     // NB
  u16* pack  = cb + NB;                      // NN*768
  u16* mqiou = pack + (size_t)NN*768;        // 4*NB
  u16* mkf   = mqiou + 4*(size_t)NB;         // 2*NB
  u16* mc    = mkf + 2*(size_t)NB;           // NB
  u16* qv    = mc + NB;                      // NB
  u16* kvec  = qv + NB;                      // NB
  float* scal    = (float*)(kvec + NB);      // NN*16 f32
  float* coefbuf = scal + (size_t)NN*16;     // NN*16*6 f32
  float* htn_arr = coefbuf + (size_t)NN*96;  // NN f32
  u16* ht   = xbb;
  u16* cred = qv;
  u16* mu   = mkf;

  k_wcvt<<<640, 256, 0, stream>>>(W_q, W_iou, W_k, U_f, W_c, U_iou, wb);
  k_prep<<<NN/4, 256, 0, stream>>>(x, h1, c1, xbb, cb, pack, scal);
  k_mm3<<<dim3(NN/128, 14), 256, 0, stream>>>(xbb, pack, cb, wb, mqiou, mkf, mc);
  k_post<<<NN/4, 256, 0, stream>>>(mqiou, mkf, mc, c1, b_q, b_k, b_c, qv, kvec, pack, scal);
  k_lgc<<<NN/4, 256, 0, stream>>>(edges, del_t, qv, kvec, scal, b_haw, a_haw, haw1, haw2, coefbuf);
  k_acc<<<NN/2, 256, 0, stream>>>(edges, pack, coefbuf, ht, cred, htn_arr);
  gemm_bt<<<dim3(NN/128, 6), 256, 0, stream>>>(ht, 256, wb + 458752, mu, 768);
  k_final<<<NN/4, 256, 0, stream>>>(mqiou, mu, cred, b_iou, scal, htn_arr, (float*)d_out);
}